// Round 8
// baseline (1023.463 us; speedup 1.0000x reference)
//
#include <hip/hip_runtime.h>
#include <math.h>

#define D_MODEL 1024
#define D_INNER 2048
#define D_STATE 16
#define D_CONV  4
#define DT_RANK 64
#define NB      2
#define LSEQ    1024
#define NROWS   (NB * LSEQ)   // 2048
#define LN_EPS  1e-5f
#define N_LAYER 4
#define NCHUNK  32
#define TCH     (LSEQ / NCHUNK)   // 32 steps per chunk

__device__ inline unsigned bfbits(float f) {
    unsigned u = __float_as_uint(f);
    return (u + 0x7fffu + ((u >> 16) & 1u)) >> 16;  // RNE
}

// ---------------------------------------------------------------------------
// Fused residual-add + LayerNorm. bf16out=1: emit bf16; 0: fp32.
// ---------------------------------------------------------------------------
__device__ inline float wave_sum(float s) {
    #pragma unroll
    for (int m = 1; m < 64; m <<= 1) s += __shfl_xor(s, m, 64);
    return s;
}

__global__ __launch_bounds__(256)
void add_ln_kernel(const float* __restrict__ add, float* __restrict__ residual,
                   const float* __restrict__ w, const float* __restrict__ b,
                   void* __restrict__ out, int first, int bf16out)
{
    int row = blockIdx.x;
    int tid = threadIdx.x;
    size_t base = (size_t)row * D_MODEL + tid * 4;

    float4 v = *(const float4*)(add + base);
    if (!first) {
        float4 r = *(const float4*)(residual + base);
        v.x += r.x; v.y += r.y; v.z += r.z; v.w += r.w;
    }
    *(float4*)(residual + base) = v;

    __shared__ float red[8];
    float s = v.x + v.y + v.z + v.w;
    s = wave_sum(s);
    if ((tid & 63) == 0) red[tid >> 6] = s;
    __syncthreads();
    float mu = (red[0] + red[1] + red[2] + red[3]) * (1.0f / D_MODEL);

    float dx = v.x - mu, dy = v.y - mu, dz = v.z - mu, dw2 = v.w - mu;
    float s2 = dx*dx + dy*dy + dz*dz + dw2*dw2;
    s2 = wave_sum(s2);
    if ((tid & 63) == 0) red[4 + (tid >> 6)] = s2;
    __syncthreads();
    float var = (red[4] + red[5] + red[6] + red[7]) * (1.0f / D_MODEL);
    float rs = rsqrtf(var + LN_EPS);

    float4 wv = *(const float4*)(w + tid * 4);
    float4 bv = *(const float4*)(b + tid * 4);
    float4 o;
    o.x = dx  * rs * wv.x + bv.x;
    o.y = dy  * rs * wv.y + bv.y;
    o.z = dz  * rs * wv.z + bv.z;
    o.w = dw2 * rs * wv.w + bv.w;
    if (bf16out) {
        ushort4 ov;
        ov.x = (unsigned short)bfbits(o.x);
        ov.y = (unsigned short)bfbits(o.y);
        ov.z = (unsigned short)bfbits(o.z);
        ov.w = (unsigned short)bfbits(o.w);
        *(ushort4*)((unsigned short*)out + base) = ov;
    } else {
        *(float4*)((float*)out + base) = o;
    }
}

// ---------------------------------------------------------------------------
// fp32 -> bf16 bulk convert (weights). grid*256*4 must equal element count.
// ---------------------------------------------------------------------------
__global__ __launch_bounds__(256)
void f32_to_bf16_kernel(const float* __restrict__ src, unsigned short* __restrict__ dst)
{
    int i = blockIdx.x * 256 + threadIdx.x;
    float4 v = *(const float4*)(src + (size_t)i * 4);
    ushort4 o;
    o.x = (unsigned short)bfbits(v.x);
    o.y = (unsigned short)bfbits(v.y);
    o.z = (unsigned short)bfbits(v.z);
    o.w = (unsigned short)bfbits(v.w);
    *(ushort4*)(dst + (size_t)i * 4) = o;
}

// ---------------------------------------------------------------------------
// fp32 -> hi/lo bf16 split convert (a = hi + lo, each bf16; ~fp32 accuracy
// when used as ah*bh + ah*bl + al*bh). grid*1024 elements.
// ---------------------------------------------------------------------------
__global__ __launch_bounds__(256)
void f32_to_hl_kernel(const float* __restrict__ src, unsigned short* __restrict__ hi,
                      unsigned short* __restrict__ lo)
{
    int i = blockIdx.x * 256 + threadIdx.x;
    float4 v = *(const float4*)(src + (size_t)i * 4);
    ushort4 h, l;
    float f;
    h.x = (unsigned short)bfbits(v.x); f = __uint_as_float((unsigned)h.x << 16); l.x = (unsigned short)bfbits(v.x - f);
    h.y = (unsigned short)bfbits(v.y); f = __uint_as_float((unsigned)h.y << 16); l.y = (unsigned short)bfbits(v.y - f);
    h.z = (unsigned short)bfbits(v.z); f = __uint_as_float((unsigned)h.z << 16); l.z = (unsigned short)bfbits(v.z - f);
    h.w = (unsigned short)bfbits(v.w); f = __uint_as_float((unsigned)h.w << 16); l.w = (unsigned short)bfbits(v.w - f);
    *(ushort4*)(hi + (size_t)i * 4) = h;
    *(ushort4*)(lo + (size_t)i * 4) = l;
}

// ---------------------------------------------------------------------------
// Extract dt-low columns (0..63) of dbl [2048][96] -> compact hi/lo bf16
// [2048][64]. 32768 threads (128 blocks), float4 per thread.
// ---------------------------------------------------------------------------
__global__ __launch_bounds__(256)
void dtlow_hl_kernel(const float* __restrict__ dbl, unsigned short* __restrict__ hi,
                     unsigned short* __restrict__ lo)
{
    int idx = blockIdx.x * 256 + threadIdx.x;   // 2048*16
    int m = idx >> 4, k4 = (idx & 15) * 4;
    float4 v = *(const float4*)(dbl + (size_t)m * 96 + k4);
    ushort4 h, l;
    float f;
    h.x = (unsigned short)bfbits(v.x); f = __uint_as_float((unsigned)h.x << 16); l.x = (unsigned short)bfbits(v.x - f);
    h.y = (unsigned short)bfbits(v.y); f = __uint_as_float((unsigned)h.y << 16); l.y = (unsigned short)bfbits(v.y - f);
    h.z = (unsigned short)bfbits(v.z); f = __uint_as_float((unsigned)h.z << 16); l.z = (unsigned short)bfbits(v.z - f);
    h.w = (unsigned short)bfbits(v.w); f = __uint_as_float((unsigned)h.w << 16); l.w = (unsigned short)bfbits(v.w - f);
    *(ushort4*)(hi + (size_t)m * 64 + k4) = h;
    *(ushort4*)(lo + (size_t)m * 64 + k4) = l;
}

// ---------------------------------------------------------------------------
// bf16 MFMA NT GEMM — both operands pre-converted bf16 (uint4 passthrough
// staging). 128x128 tile, BK=64, 4 waves, mfma_f32_16x16x32_bf16, LDS_S=72.
// ---------------------------------------------------------------------------
using bf16x8 = __attribute__((ext_vector_type(8))) short;
using f32x4  = __attribute__((ext_vector_type(4))) float;

#define BBM 128
#define BBN 128
#define BBK 64
#define LDS_S (BBK + 8)   // 72 bf16 -> 144B row stride

__global__ __launch_bounds__(256)
void gemm_bf16_nt(const unsigned short* __restrict__ A, const unsigned short* __restrict__ Bw,
                  float* __restrict__ C, int M, int N, int K)
{
    __shared__ unsigned short As[BBM * LDS_S];
    __shared__ unsigned short Bs[BBN * LDS_S];

    int tid = threadIdx.x;
    int m0 = blockIdx.y * BBM, n0 = blockIdx.x * BBN;
    int lane = tid & 63, w = tid >> 6;
    int wm = (w >> 1) * 64, wn = (w & 1) * 64;
    int lm = lane & 15, q = lane >> 4;

    int lr = tid >> 3;          // 0..31  (staging row)
    int lc = (tid & 7) * 8;     // 0..56  (staging col, bf16 elems)

    f32x4 acc[4][4] = {};

    for (int k0 = 0; k0 < K; k0 += BBK) {
        #pragma unroll
        for (int r = 0; r < 4; ++r) {
            int row = lr + r * 32;
            uint4 av = *(const uint4*)(A + (size_t)(m0 + row) * K + k0 + lc);
            *(uint4*)&As[row * LDS_S + lc] = av;
        }
        #pragma unroll
        for (int r = 0; r < 4; ++r) {
            int row = lr + r * 32;
            uint4 pv = *(const uint4*)(Bw + (size_t)(n0 + row) * K + k0 + lc);
            *(uint4*)&Bs[row * LDS_S + lc] = pv;
        }
        __syncthreads();
        #pragma unroll
        for (int kk = 0; kk < BBK; kk += 32) {
            bf16x8 af[4], bf[4];
            #pragma unroll
            for (int i = 0; i < 4; ++i)
                af[i] = *(const bf16x8*)&As[(wm + i * 16 + lm) * LDS_S + kk + q * 8];
            #pragma unroll
            for (int j = 0; j < 4; ++j)
                bf[j] = *(const bf16x8*)&Bs[(wn + j * 16 + lm) * LDS_S + kk + q * 8];
            #pragma unroll
            for (int i = 0; i < 4; ++i)
                #pragma unroll
                for (int j = 0; j < 4; ++j)
                    acc[i][j] = __builtin_amdgcn_mfma_f32_16x16x32_bf16(
                        af[i], bf[j], acc[i][j], 0, 0, 0);
        }
        __syncthreads();
    }

    #pragma unroll
    for (int i = 0; i < 4; ++i)
        #pragma unroll
        for (int j = 0; j < 4; ++j)
            #pragma unroll
            for (int r = 0; r < 4; ++r) {
                int row = m0 + wm + i * 16 + q * 4 + r;
                int col = n0 + wn + j * 16 + lm;
                C[(size_t)row * N + col] = acc[i][j][r];
            }
}

// ---------------------------------------------------------------------------
// x_proj via hi/lo split-bf16 MFMA, split-K, NO LDS (direct global fragment
// loads). Grid: dim3(64 mtile(32 rows), 8 z(kslice 256)).
// ---------------------------------------------------------------------------
__global__ __launch_bounds__(256)
void xproj_hl(const unsigned short* __restrict__ Ah, const unsigned short* __restrict__ Al,
              const unsigned short* __restrict__ Bh, const unsigned short* __restrict__ Bl,
              float* __restrict__ C)
{
    int tid = threadIdx.x;
    int lane = tid & 63, w = tid >> 6;
    int lm = lane & 15, q = lane >> 4;
    int m0 = blockIdx.x * 32;
    int kb = blockIdx.y * 256;

    int wm = (w & 1) * 16;          // m-half
    int wn = (w >> 1) * 48;         // n-half (3 frags of 16)

    size_t arow = (size_t)(m0 + wm + lm) * 2048;

    f32x4 acc[3] = {};

    #pragma unroll 2
    for (int kc = 0; kc < 8; ++kc) {
        int k = kb + kc * 32 + q * 8;
        bf16x8 ah = *(const bf16x8*)&Ah[arow + k];
        bf16x8 al = *(const bf16x8*)&Al[arow + k];
        #pragma unroll
        for (int j = 0; j < 3; ++j) {
            size_t brow = (size_t)(wn + j * 16 + lm) * 2048;
            bf16x8 bh = *(const bf16x8*)&Bh[brow + k];
            bf16x8 bl = *(const bf16x8*)&Bl[brow + k];
            acc[j] = __builtin_amdgcn_mfma_f32_16x16x32_bf16(al, bh, acc[j], 0, 0, 0);
            acc[j] = __builtin_amdgcn_mfma_f32_16x16x32_bf16(ah, bl, acc[j], 0, 0, 0);
            acc[j] = __builtin_amdgcn_mfma_f32_16x16x32_bf16(ah, bh, acc[j], 0, 0, 0);
        }
    }

    #pragma unroll
    for (int j = 0; j < 3; ++j) {
        int col = wn + j * 16 + lm;
        #pragma unroll
        for (int r = 0; r < 4; ++r) {
            int row = m0 + wm + q * 4 + r;
            atomicAdd(&C[(size_t)row * 96 + col], acc[j][r]);
        }
    }
}

// ---------------------------------------------------------------------------
// dt_proj via hi/lo split-bf16 MFMA + fused bias+softplus. NO LDS.
// Grid: dim3(16 ntile(128), 32 mtile(64)).
// ---------------------------------------------------------------------------
__global__ __launch_bounds__(256)
void dtproj_hl(const unsigned short* __restrict__ Ah, const unsigned short* __restrict__ Al,
               const unsigned short* __restrict__ Bh, const unsigned short* __restrict__ Bl,
               const float* __restrict__ bias, float* __restrict__ dtb)
{
    int tid = threadIdx.x;
    int lane = tid & 63, w = tid >> 6;
    int lm = lane & 15, q = lane >> 4;
    int n0 = blockIdx.x * 128;
    int m0 = blockIdx.y * 64;

    size_t arow = (size_t)(m0 + w * 16 + lm) * 64;

    f32x4 acc[8] = {};

    #pragma unroll
    for (int kc = 0; kc < 2; ++kc) {
        int k = kc * 32 + q * 8;
        bf16x8 ah = *(const bf16x8*)&Ah[arow + k];
        bf16x8 al = *(const bf16x8*)&Al[arow + k];
        #pragma unroll
        for (int j = 0; j < 8; ++j) {
            size_t brow = (size_t)(n0 + j * 16 + lm) * 64;
            bf16x8 bh = *(const bf16x8*)&Bh[brow + k];
            bf16x8 bl = *(const bf16x8*)&Bl[brow + k];
            acc[j] = __builtin_amdgcn_mfma_f32_16x16x32_bf16(al, bh, acc[j], 0, 0, 0);
            acc[j] = __builtin_amdgcn_mfma_f32_16x16x32_bf16(ah, bl, acc[j], 0, 0, 0);
            acc[j] = __builtin_amdgcn_mfma_f32_16x16x32_bf16(ah, bh, acc[j], 0, 0, 0);
        }
    }

    #pragma unroll
    for (int j = 0; j < 8; ++j) {
        int col = n0 + j * 16 + lm;
        float bv = bias[col];
        #pragma unroll
        for (int r = 0; r < 4; ++r) {
            int row = m0 + w * 16 + q * 4 + r;
            float v = acc[j][r] + bv;
            v = (v > 20.f) ? v : log1pf(__expf(v));
            dtb[(size_t)row * D_INNER + col] = v;
        }
    }
}

// ---------------------------------------------------------------------------
// Depthwise causal conv (width 4) + bias + SiLU; also emits hi/lo bf16 split
// of the output for the MFMA x_proj.
// ---------------------------------------------------------------------------
__global__ __launch_bounds__(256)
void conv_silu_kernel(const float* __restrict__ xz, const float* __restrict__ cw,
                      const float* __restrict__ cb, float* __restrict__ xc,
                      unsigned short* __restrict__ xch, unsigned short* __restrict__ xcl)
{
    int idx = blockIdx.x * 256 + threadIdx.x;
    int d  = idx & (D_INNER - 1);
    int t  = (idx >> 11) & (LSEQ - 1);
    int bb = idx >> 21;

    const float* xcol = xz + (size_t)bb * LSEQ * 2 * D_INNER + d;
    float acc = cb[d];
    #pragma unroll
    for (int k = 0; k < D_CONV; ++k) {
        int tt = t + k - (D_CONV - 1);
        if (tt >= 0) acc += xcol[(size_t)tt * 2 * D_INNER] * cw[d * D_CONV + k];
    }
    acc = acc / (1.f + __expf(-acc));
    xc[idx] = acc;
    unsigned hb = bfbits(acc);
    xch[idx] = (unsigned short)hb;
    float hf = __uint_as_float(hb << 16);
    xcl[idx] = (unsigned short)bfbits(acc - hf);
}

// ---------------------------------------------------------------------------
// Chunked selective scan, v7: 4 lanes per d (4 states each) -> 8192 waves
// (full 8/SIMD machine capacity); unroll-2 + prefetch-distance-2 pipeline
// (named E/O register sets). Two shfl_xor for p-reduce. [r][d] layout.
// ---------------------------------------------------------------------------
#define UNPK4(dst, off, v) { dst[(off)+0]=(v).x; dst[(off)+1]=(v).y; \
                             dst[(off)+2]=(v).z; dst[(off)+3]=(v).w; }

__global__ __launch_bounds__(256)
void scan_pass1(const float* __restrict__ dtb, const float* __restrict__ xc,
                const float* __restrict__ dbl, const float* __restrict__ Alog,
                float* __restrict__ aPbuf, float* __restrict__ bAbuf)
{
    int tid = threadIdx.x;
    int q   = tid & 3;               // states q*4 .. q*4+3
    int blk = blockIdx.x;            // grid = NB * NCHUNK * 32 = 2048
    int dg  = blk & 31;
    int c   = (blk >> 5) & (NCHUNK - 1);
    int bb  = blk >> 10;
    int d   = dg * 64 + (tid >> 2);

    float A[4];
    {
        float4 v = *(const float4*)(Alog + (size_t)d * D_STATE + q * 4);
        A[0] = -__expf(v.x); A[1] = -__expf(v.y);
        A[2] = -__expf(v.z); A[3] = -__expf(v.w);
    }

    size_t rowbase = (size_t)bb * LSEQ + (size_t)c * TCH;
    const float* pdt = dtb + rowbase * D_INNER + d;
    const float* pxc = xc  + rowbase * D_INNER + d;
    const float* pbc = dbl + rowbase * 96 + DT_RANK + q * 4;

    float aP[4] = {1.f,1.f,1.f,1.f};
    float bA[4] = {0.f,0.f,0.f,0.f};

    // prefetch steps 0 (E) and 1 (O)
    float  dtE = pdt[0], xvE = pxc[0];
    float4 BE  = *(const float4*)pbc;
    float  dtO = pdt[D_INNER], xvO = pxc[D_INNER];
    float4 BO  = *(const float4*)(pbc + 96);

    for (int t = 0; t < TCH; t += 2) {
        int t2 = (t + 2 < TCH) ? t + 2 : TCH - 1;
        int t3 = (t + 3 < TCH) ? t + 3 : TCH - 1;
        float  dtEn = pdt[(size_t)t2 * D_INNER], xvEn = pxc[(size_t)t2 * D_INNER];
        float4 BEn  = *(const float4*)(pbc + (size_t)t2 * 96);
        float  dtOn = pdt[(size_t)t3 * D_INNER], xvOn = pxc[(size_t)t3 * D_INNER];
        float4 BOn  = *(const float4*)(pbc + (size_t)t3 * 96);

        {   // step t
            float B[4]; UNPK4(B, 0, BE)
            float dtx = dtE * xvE;
            #pragma unroll
            for (int s = 0; s < 4; ++s) {
                float a = __expf(dtE * A[s]);
                aP[s] *= a;
                bA[s] = bA[s] * a + dtx * B[s];
            }
        }
        {   // step t+1
            float B[4]; UNPK4(B, 0, BO)
            float dtx = dtO * xvO;
            #pragma unroll
            for (int s = 0; s < 4; ++s) {
                float a = __expf(dtO * A[s]);
                aP[s] *= a;
                bA[s] = bA[s] * a + dtx * B[s];
            }
        }
        dtE = dtEn; xvE = xvEn; BE = BEn;
        dtO = dtOn; xvO = xvOn; BO = BOn;
    }

    size_t o = ((size_t)(bb * NCHUNK + c) * D_INNER + d) * D_STATE + q * 4;
    *(float4*)(aPbuf + o) = make_float4(aP[0], aP[1], aP[2], aP[3]);
    *(float4*)(bAbuf + o) = make_float4(bA[0], bA[1], bA[2], bA[3]);
}

__global__ __launch_bounds__(256)
void scan_pass2(const float* __restrict__ dtb, const float* __restrict__ xc,
                const float* __restrict__ dbl, const float* __restrict__ xz,
                const float* __restrict__ Alog, const float* __restrict__ Dp,
                const float* __restrict__ aPbuf, const float* __restrict__ bAbuf,
                unsigned short* __restrict__ y)
{
    int tid = threadIdx.x;
    int q   = tid & 3;
    int blk = blockIdx.x;
    int dg  = blk & 31;
    int c   = (blk >> 5) & (NCHUNK - 1);
    int bb  = blk >> 10;
    int d   = dg * 64 + (tid >> 2);

    float A[4];
    {
        float4 v = *(const float4*)(Alog + (size_t)d * D_STATE + q * 4);
        A[0] = -__expf(v.x); A[1] = -__expf(v.y);
        A[2] = -__expf(v.z); A[3] = -__expf(v.w);
    }
    float Dd = Dp[d];

    float h[4] = {0.f,0.f,0.f,0.f};

    // prefix compose over chunks [0, c)
    for (int cc = 0; cc < c; ++cc) {
        size_t o = ((size_t)(bb * NCHUNK + cc) * D_INNER + d) * D_STATE + q * 4;
        float4 a0 = *(const float4*)(aPbuf + o);
        float4 b0 = *(const float4*)(bAbuf + o);
        h[0] = h[0] * a0.x + b0.x;
        h[1] = h[1] * a0.y + b0.y;
        h[2] = h[2] * a0.z + b0.z;
        h[3] = h[3] * a0.w + b0.w;
    }

    size_t rowbase = (size_t)bb * LSEQ + (size_t)c * TCH;
    const float* pdt = dtb + rowbase * D_INNER + d;
    const float* pxc = xc  + rowbase * D_INNER + d;
    const float* pz  = xz  + rowbase * 2 * D_INNER + D_INNER + d;
    const float* pbc = dbl + rowbase * 96 + DT_RANK + q * 4;
    unsigned short* py = y + rowbase * D_INNER + d;

    // prefetch steps 0 (E) and 1 (O)
    float  dtE = pdt[0], xvE = pxc[0], zvE = pz[0];
    float4 BE  = *(const float4*)pbc;
    float4 CE  = *(const float4*)(pbc + 16);
    float  dtO = pdt[D_INNER], xvO = pxc[D_INNER], zvO = pz[2 * D_INNER];
    float4 BO  = *(const float4*)(pbc + 96);
    float4 CO  = *(const float4*)(pbc + 96 + 16);

    for (int t = 0; t < TCH; t += 2) {
        int t2 = (t + 2 < TCH) ? t + 2 : TCH - 1;
        int t3 = (t + 3 < TCH) ? t + 3 : TCH - 1;
        float  dtEn = pdt[(size_t)t2 * D_INNER], xvEn = pxc[(size_t)t2 * D_INNER];
        float  zvEn = pz[(size_t)t2 * 2 * D_INNER];
        float4 BEn  = *(const float4*)(pbc + (size_t)t2 * 96);
        float4 CEn  = *(const float4*)(pbc + (size_t)t2 * 96 + 16);
        float  dtOn = pdt[(size_t)t3 * D_INNER], xvOn = pxc[(size_t)t3 * D_INNER];
        float  zvOn = pz[(size_t)t3 * 2 * D_INNER];
        float4 BOn  = *(const float4*)(pbc + (size_t)t3 * 96);
        float4 COn  = *(const float4*)(pbc + (size_t)t3 * 96 + 16);

        {   // step t
            float B[4], C[4];
            UNPK4(B, 0, BE) UNPK4(C, 0, CE)
            float dtx = dtE * xvE;
            float p = 0.f;
            #pragma unroll
            for (int s = 0; s < 4; ++s) {
                float a = __expf(dtE * A[s]);
                h[s] = h[s] * a + dtx * B[s];
                p += h[s] * C[s];
            }
            p += __shfl_xor(p, 1, 4);
            p += __shfl_xor(p, 2, 4);
            if (q == 0) {
                float sz = zvE / (1.f + __expf(-zvE));
                py[(size_t)t * D_INNER] = (unsigned short)bfbits((p + xvE * Dd) * sz);
            }
        }
        {   // step t+1
            float B[4], C[4];
            UNPK4(B, 0, BO) UNPK4(C, 0, CO)
            float dtx = dtO * xvO;
            float p = 0.f;
            #pragma unroll
            for (int s = 0; s < 4; ++s) {
                float a = __expf(dtO * A[s]);
                h[s] = h[s] * a + dtx * B[s];
                p += h[s] * C[s];
            }
            p += __shfl_xor(p, 1, 4);
            p += __shfl_xor(p, 2, 4);
            if (q == 0) {
                float sz = zvO / (1.f + __expf(-zvO));
                py[(size_t)(t + 1) * D_INNER] = (unsigned short)bfbits((p + xvO * Dd) * sz);
            }
        }
        dtE = dtEn; xvE = xvEn; zvE = zvEn; BE = BEn; CE = CEn;
        dtO = dtOn; xvO = xvOn; zvO = zvOn; BO = BOn; CO = COn;
    }
}

// ---------------------------------------------------------------------------
extern "C" void kernel_launch(void* const* d_in, const int* in_sizes, int n_in,
                              void* d_out, int out_size, void* d_ws, size_t ws_size,
                              hipStream_t stream)
{
    const float* h_in  = (const float*)d_in[0];
    const float* iw    = (const float*)d_in[1];   // (4, 4096, 1024)
    const float* cw    = (const float*)d_in[2];   // (4, 2048, 4)
    const float* cb    = (const float*)d_in[3];   // (4, 2048)
    const float* xw    = (const float*)d_in[4];   // (4, 96, 2048)
    const float* dw    = (const float*)d_in[5];   // (4, 2048, 64)
    const float* db    = (const float*)d_in[6];   // (4, 2048)
    const float* Alog  = (const float*)d_in[7];   // (4, 2048, 16)
    const float* Dp    = (const float*)d_in[8];   // (4, 2048)
    const float* ow    = (const float*)d_in[9];   // (4, 1024, 2048)
    const float* nw    = (const float*)d_in[10];  // (4, 1024)
    const float* nb    = (const float*)d_in[11];  // (4, 1024)
    const float* nfw   = (const float*)d_in[12];  // (1024,)
    const float* nfb   = (const float*)d_in[13];  // (1024,)

    // workspace layout — identical total (25,362,432 floats)
    float* ws = (float*)d_ws;
    float* residual = ws;                       // 2,097,152
    float* hs       = residual + 2097152;       // 2,097,152
    float* xz       = hs + 2097152;             // 8,388,608  [r][4096]
    float* xc       = xz + 8388608;             // 4,194,304  [r][2048]
    float* dtb      = xc + 4194304;             // 4,194,304  [r][2048]
    float* dbl      = dtb + 4194304;            // 196,608    [r][96]
    float* y        = dbl + 196608;             // 4,194,304

    // aPbuf aliases hs (dead add_ln-consume .. scan_pass1); bAbuf = y[2M..4M).
    float* aPbuf = hs;
    float* bAbuf = y + 2097152;

    // bf16 / hi-lo staging, all in dead regions (timeline-disjoint):
    unsigned short* wbuf_in  = (unsigned short*)y;
    unsigned short* hs_bf16  = (unsigned short*)(y + 2097152);
    unsigned short* y_bf16   = (unsigned short*)y;
    unsigned short* xc_hi    = (unsigned short*)y;
    unsigned short* xc_lo    = (unsigned short*)(y + 2097152);
    unsigned short* xwp_hi   = (unsigned short*)hs;
    unsigned short* xwp_lo   = (unsigned short*)(hs + 98304);
    unsigned short* dwp_hi   = (unsigned short*)(hs + 196608);
    unsigned short* dwp_lo   = (unsigned short*)(hs + 262144);
    unsigned short* dtl_hi   = (unsigned short*)(hs + 327680);
    unsigned short* dtl_lo   = (unsigned short*)(hs + 393216);
    unsigned short* wbuf_out = (unsigned short*)dtb;

    const float* cur_add = h_in;
    for (int i = 0; i < N_LAYER; ++i) {
        // residual add + LN, emit bf16
        add_ln_kernel<<<NROWS, 256, 0, stream>>>(cur_add, residual,
                                                 nw + i * D_MODEL, nb + i * D_MODEL,
                                                 hs_bf16, i == 0, 1);
        // convert in_proj weights -> bf16 (dead y space)
        f32_to_bf16_kernel<<<(2 * D_INNER * D_MODEL) / 1024, 256, 0, stream>>>(
            iw + (size_t)i * 2 * D_INNER * D_MODEL, wbuf_in);
        // in_proj (bf16 MFMA): -> xz [r][4096] fp32
        gemm_bf16_nt<<<dim3(2 * D_INNER / BBN, NROWS / BBM), 256, 0, stream>>>(
            hs_bf16, wbuf_in, xz, NROWS, 2 * D_INNER, D_MODEL);
        // conv + silu -> xc fp32 + hi/lo bf16 split (for MFMA x_proj)
        conv_silu_kernel<<<NB * LSEQ * D_INNER / 256, 256, 0, stream>>>(
            xz, cw + (size_t)i * D_INNER * D_CONV, cb + i * D_INNER, xc, xc_hi, xc_lo);
        // weight hi/lo prep (per layer; tiny)
        f32_to_hl_kernel<<<(96 * D_INNER) / 1024, 256, 0, stream>>>(
            xw + (size_t)i * 96 * D_INNER, xwp_hi, xwp_lo);
        f32_to_hl_kernel<<<(D_INNER * DT_RANK) / 1024, 256, 0, stream>>>(
            dw + (size_t)i * D_INNER * DT_RANK, dwp_hi, dwp_lo);
        // x_proj (hi/lo split-bf16 MFMA, split-K z=8): -> dbl [r][96]
        hipMemsetAsync(dbl, 0, 196608 * sizeof(float), stream);
        xproj_hl<<<dim3(NROWS / 32, 8), 256, 0, stream>>>(
            xc_hi, xc_lo, xwp_hi, xwp_lo, dbl);
        // extract dt-low cols -> compact hi/lo
        dtlow_hl_kernel<<<(NROWS * 16) / 256, 256, 0, stream>>>(dbl, dtl_hi, dtl_lo);
        // dt_proj (hi/lo split-bf16 MFMA + bias + softplus): -> dtb [r][2048]
        dtproj_hl<<<dim3(D_INNER / 128, NROWS / 64), 256, 0, stream>>>(
            dtl_hi, dtl_lo, dwp_hi, dwp_lo, db + i * D_INNER, dtb);
        // chunked selective scan — 4 lanes/d, 8192 waves, depth-2 pipeline
        scan_pass1<<<NB * NCHUNK * (D_INNER / 64), 256, 0, stream>>>(
            dtb, xc, dbl, Alog + (size_t)i * D_INNER * D_STATE, aPbuf, bAbuf);
        scan_pass2<<<NB * NCHUNK * (D_INNER / 64), 256, 0, stream>>>(
            dtb, xc, dbl, xz, Alog + (size_t)i * D_INNER * D_STATE, Dp + i * D_INNER,
            aPbuf, bAbuf, y_bf16);
        // convert out_proj weights -> bf16 (dead dtb space)
        f32_to_bf16_kernel<<<(D_MODEL * D_INNER) / 1024, 256, 0, stream>>>(
            ow + (size_t)i * D_MODEL * D_INNER, wbuf_out);
        // out_proj (bf16 MFMA): -> hs [r][1024] fp32
        gemm_bf16_nt<<<dim3(D_MODEL / BBN, NROWS / BBM), 256, 0, stream>>>(
            y_bf16, wbuf_out, hs, NROWS, D_MODEL, D_INNER);
        cur_add = hs;
    }
    add_ln_kernel<<<NROWS, 256, 0, stream>>>(hs, residual, nfw, nfb, d_out, 0, 0);
}

// Round 9
// 984.939 us; speedup vs baseline: 1.0391x; 1.0391x over previous
//
#include <hip/hip_runtime.h>
#include <math.h>

#define D_MODEL 1024
#define D_INNER 2048
#define D_STATE 16
#define D_CONV  4
#define DT_RANK 64
#define NB      2
#define LSEQ    1024
#define NROWS   (NB * LSEQ)   // 2048
#define LN_EPS  1e-5f
#define N_LAYER 4
#define NCHUNK  32
#define TCH     (LSEQ / NCHUNK)   // 32 steps per chunk

__device__ inline unsigned bfbits(float f) {
    unsigned u = __float_as_uint(f);
    return (u + 0x7fffu + ((u >> 16) & 1u)) >> 16;  // RNE
}

// ---------------------------------------------------------------------------
// Fused residual-add + LayerNorm. bf16out=1: emit bf16; 0: fp32.
// ---------------------------------------------------------------------------
__device__ inline float wave_sum(float s) {
    #pragma unroll
    for (int m = 1; m < 64; m <<= 1) s += __shfl_xor(s, m, 64);
    return s;
}

__global__ __launch_bounds__(256)
void add_ln_kernel(const float* __restrict__ add, float* __restrict__ residual,
                   const float* __restrict__ w, const float* __restrict__ b,
                   void* __restrict__ out, int first, int bf16out)
{
    int row = blockIdx.x;
    int tid = threadIdx.x;
    size_t base = (size_t)row * D_MODEL + tid * 4;

    float4 v = *(const float4*)(add + base);
    if (!first) {
        float4 r = *(const float4*)(residual + base);
        v.x += r.x; v.y += r.y; v.z += r.z; v.w += r.w;
    }
    *(float4*)(residual + base) = v;

    __shared__ float red[8];
    float s = v.x + v.y + v.z + v.w;
    s = wave_sum(s);
    if ((tid & 63) == 0) red[tid >> 6] = s;
    __syncthreads();
    float mu = (red[0] + red[1] + red[2] + red[3]) * (1.0f / D_MODEL);

    float dx = v.x - mu, dy = v.y - mu, dz = v.z - mu, dw2 = v.w - mu;
    float s2 = dx*dx + dy*dy + dz*dz + dw2*dw2;
    s2 = wave_sum(s2);
    if ((tid & 63) == 0) red[4 + (tid >> 6)] = s2;
    __syncthreads();
    float var = (red[4] + red[5] + red[6] + red[7]) * (1.0f / D_MODEL);
    float rs = rsqrtf(var + LN_EPS);

    float4 wv = *(const float4*)(w + tid * 4);
    float4 bv = *(const float4*)(b + tid * 4);
    float4 o;
    o.x = dx  * rs * wv.x + bv.x;
    o.y = dy  * rs * wv.y + bv.y;
    o.z = dz  * rs * wv.z + bv.z;
    o.w = dw2 * rs * wv.w + bv.w;
    if (bf16out) {
        ushort4 ov;
        ov.x = (unsigned short)bfbits(o.x);
        ov.y = (unsigned short)bfbits(o.y);
        ov.z = (unsigned short)bfbits(o.z);
        ov.w = (unsigned short)bfbits(o.w);
        *(ushort4*)((unsigned short*)out + base) = ov;
    } else {
        *(float4*)((float*)out + base) = o;
    }
}

// ---------------------------------------------------------------------------
// fp32 -> bf16 bulk convert (out_proj weights; runs after scan frees dtb).
// ---------------------------------------------------------------------------
__global__ __launch_bounds__(256)
void f32_to_bf16_kernel(const float* __restrict__ src, unsigned short* __restrict__ dst)
{
    int i = blockIdx.x * 256 + threadIdx.x;
    float4 v = *(const float4*)(src + (size_t)i * 4);
    ushort4 o;
    o.x = (unsigned short)bfbits(v.x);
    o.y = (unsigned short)bfbits(v.y);
    o.z = (unsigned short)bfbits(v.z);
    o.w = (unsigned short)bfbits(v.w);
    *(ushort4*)(dst + (size_t)i * 4) = o;
}

// ---------------------------------------------------------------------------
// Fused per-layer prep: one dispatch does
//   blocks [0,4096):     in_proj weights fp32 -> bf16
//   blocks [4096,4288):   xw hi/lo split (96x2048)
//   blocks [4288,4416):   dw hi/lo split (2048x64)
//   blocks [4416,4608):   zero dbl (196608 floats)
// Replaces 3 kernels + 1 memset per layer.
// ---------------------------------------------------------------------------
__device__ inline void hl_split4(float4 v, ushort4* h4, ushort4* l4)
{
    ushort4 h, l;
    float f;
    h.x = (unsigned short)bfbits(v.x); f = __uint_as_float((unsigned)h.x << 16); l.x = (unsigned short)bfbits(v.x - f);
    h.y = (unsigned short)bfbits(v.y); f = __uint_as_float((unsigned)h.y << 16); l.y = (unsigned short)bfbits(v.y - f);
    h.z = (unsigned short)bfbits(v.z); f = __uint_as_float((unsigned)h.z << 16); l.z = (unsigned short)bfbits(v.z - f);
    h.w = (unsigned short)bfbits(v.w); f = __uint_as_float((unsigned)h.w << 16); l.w = (unsigned short)bfbits(v.w - f);
    *h4 = h; *l4 = l;
}

__global__ __launch_bounds__(256)
void prep_layer(const float* __restrict__ iw, unsigned short* __restrict__ wbuf_in,
                const float* __restrict__ xw, unsigned short* __restrict__ xwh,
                unsigned short* __restrict__ xwl,
                const float* __restrict__ dw, unsigned short* __restrict__ dwh,
                unsigned short* __restrict__ dwl,
                float* __restrict__ dbl)
{
    int b = blockIdx.x;
    int tid = threadIdx.x;
    if (b < 4096) {
        int i = b * 256 + tid;
        float4 v = *(const float4*)(iw + (size_t)i * 4);
        ushort4 o;
        o.x = (unsigned short)bfbits(v.x);
        o.y = (unsigned short)bfbits(v.y);
        o.z = (unsigned short)bfbits(v.z);
        o.w = (unsigned short)bfbits(v.w);
        *(ushort4*)(wbuf_in + (size_t)i * 4) = o;
    } else if (b < 4288) {
        int i = (b - 4096) * 256 + tid;
        float4 v = *(const float4*)(xw + (size_t)i * 4);
        hl_split4(v, (ushort4*)(xwh + (size_t)i * 4), (ushort4*)(xwl + (size_t)i * 4));
    } else if (b < 4416) {
        int i = (b - 4288) * 256 + tid;
        float4 v = *(const float4*)(dw + (size_t)i * 4);
        hl_split4(v, (ushort4*)(dwh + (size_t)i * 4), (ushort4*)(dwl + (size_t)i * 4));
    } else {
        int i = (b - 4416) * 256 + tid;
        *(float4*)(dbl + (size_t)i * 4) = make_float4(0.f, 0.f, 0.f, 0.f);
    }
}

// ---------------------------------------------------------------------------
// Extract dt-low columns (0..63) of dbl [2048][96] -> compact hi/lo bf16
// [2048][64].
// ---------------------------------------------------------------------------
__global__ __launch_bounds__(256)
void dtlow_hl_kernel(const float* __restrict__ dbl, unsigned short* __restrict__ hi,
                     unsigned short* __restrict__ lo)
{
    int idx = blockIdx.x * 256 + threadIdx.x;   // 2048*16
    int m = idx >> 4, k4 = (idx & 15) * 4;
    float4 v = *(const float4*)(dbl + (size_t)m * 96 + k4);
    hl_split4(v, (ushort4*)(hi + (size_t)m * 64 + k4), (ushort4*)(lo + (size_t)m * 64 + k4));
}

// ---------------------------------------------------------------------------
// bf16 MFMA NT GEMM — both operands pre-converted bf16 (uint4 passthrough
// staging). 128x128 tile, BK=64, 4 waves, mfma_f32_16x16x32_bf16, LDS_S=72.
// ---------------------------------------------------------------------------
using bf16x8 = __attribute__((ext_vector_type(8))) short;
using f32x4  = __attribute__((ext_vector_type(4))) float;

#define BBM 128
#define BBN 128
#define BBK 64
#define LDS_S (BBK + 8)   // 72 bf16 -> 144B row stride

__global__ __launch_bounds__(256)
void gemm_bf16_nt(const unsigned short* __restrict__ A, const unsigned short* __restrict__ Bw,
                  float* __restrict__ C, int M, int N, int K)
{
    __shared__ unsigned short As[BBM * LDS_S];
    __shared__ unsigned short Bs[BBN * LDS_S];

    int tid = threadIdx.x;
    int m0 = blockIdx.y * BBM, n0 = blockIdx.x * BBN;
    int lane = tid & 63, w = tid >> 6;
    int wm = (w >> 1) * 64, wn = (w & 1) * 64;
    int lm = lane & 15, q = lane >> 4;

    int lr = tid >> 3;          // 0..31  (staging row)
    int lc = (tid & 7) * 8;     // 0..56  (staging col, bf16 elems)

    f32x4 acc[4][4] = {};

    for (int k0 = 0; k0 < K; k0 += BBK) {
        #pragma unroll
        for (int r = 0; r < 4; ++r) {
            int row = lr + r * 32;
            uint4 av = *(const uint4*)(A + (size_t)(m0 + row) * K + k0 + lc);
            *(uint4*)&As[row * LDS_S + lc] = av;
        }
        #pragma unroll
        for (int r = 0; r < 4; ++r) {
            int row = lr + r * 32;
            uint4 pv = *(const uint4*)(Bw + (size_t)(n0 + row) * K + k0 + lc);
            *(uint4*)&Bs[row * LDS_S + lc] = pv;
        }
        __syncthreads();
        #pragma unroll
        for (int kk = 0; kk < BBK; kk += 32) {
            bf16x8 af[4], bf[4];
            #pragma unroll
            for (int i = 0; i < 4; ++i)
                af[i] = *(const bf16x8*)&As[(wm + i * 16 + lm) * LDS_S + kk + q * 8];
            #pragma unroll
            for (int j = 0; j < 4; ++j)
                bf[j] = *(const bf16x8*)&Bs[(wn + j * 16 + lm) * LDS_S + kk + q * 8];
            #pragma unroll
            for (int i = 0; i < 4; ++i)
                #pragma unroll
                for (int j = 0; j < 4; ++j)
                    acc[i][j] = __builtin_amdgcn_mfma_f32_16x16x32_bf16(
                        af[i], bf[j], acc[i][j], 0, 0, 0);
        }
        __syncthreads();
    }

    #pragma unroll
    for (int i = 0; i < 4; ++i)
        #pragma unroll
        for (int j = 0; j < 4; ++j)
            #pragma unroll
            for (int r = 0; r < 4; ++r) {
                int row = m0 + wm + i * 16 + q * 4 + r;
                int col = n0 + wn + j * 16 + lm;
                C[(size_t)row * N + col] = acc[i][j][r];
            }
}

// ---------------------------------------------------------------------------
// x_proj via hi/lo split-bf16 MFMA, split-K, NO LDS (direct global fragment
// loads). Grid: dim3(64 mtile(32 rows), 8 z(kslice 256)).
// ---------------------------------------------------------------------------
__global__ __launch_bounds__(256)
void xproj_hl(const unsigned short* __restrict__ Ah, const unsigned short* __restrict__ Al,
              const unsigned short* __restrict__ Bh, const unsigned short* __restrict__ Bl,
              float* __restrict__ C)
{
    int tid = threadIdx.x;
    int lane = tid & 63, w = tid >> 6;
    int lm = lane & 15, q = lane >> 4;
    int m0 = blockIdx.x * 32;
    int kb = blockIdx.y * 256;

    int wm = (w & 1) * 16;          // m-half
    int wn = (w >> 1) * 48;         // n-half (3 frags of 16)

    size_t arow = (size_t)(m0 + wm + lm) * 2048;

    f32x4 acc[3] = {};

    #pragma unroll 2
    for (int kc = 0; kc < 8; ++kc) {
        int k = kb + kc * 32 + q * 8;
        bf16x8 ah = *(const bf16x8*)&Ah[arow + k];
        bf16x8 al = *(const bf16x8*)&Al[arow + k];
        #pragma unroll
        for (int j = 0; j < 3; ++j) {
            size_t brow = (size_t)(wn + j * 16 + lm) * 2048;
            bf16x8 bh = *(const bf16x8*)&Bh[brow + k];
            bf16x8 bl = *(const bf16x8*)&Bl[brow + k];
            acc[j] = __builtin_amdgcn_mfma_f32_16x16x32_bf16(al, bh, acc[j], 0, 0, 0);
            acc[j] = __builtin_amdgcn_mfma_f32_16x16x32_bf16(ah, bl, acc[j], 0, 0, 0);
            acc[j] = __builtin_amdgcn_mfma_f32_16x16x32_bf16(ah, bh, acc[j], 0, 0, 0);
        }
    }

    #pragma unroll
    for (int j = 0; j < 3; ++j) {
        int col = wn + j * 16 + lm;
        #pragma unroll
        for (int r = 0; r < 4; ++r) {
            int row = m0 + wm + q * 4 + r;
            atomicAdd(&C[(size_t)row * 96 + col], acc[j][r]);
        }
    }
}

// ---------------------------------------------------------------------------
// dt_proj via hi/lo split-bf16 MFMA + fused bias+softplus. NO LDS.
// Grid: dim3(16 ntile(128), 32 mtile(64)).
// ---------------------------------------------------------------------------
__global__ __launch_bounds__(256)
void dtproj_hl(const unsigned short* __restrict__ Ah, const unsigned short* __restrict__ Al,
               const unsigned short* __restrict__ Bh, const unsigned short* __restrict__ Bl,
               const float* __restrict__ bias, float* __restrict__ dtb)
{
    int tid = threadIdx.x;
    int lane = tid & 63, w = tid >> 6;
    int lm = lane & 15, q = lane >> 4;
    int n0 = blockIdx.x * 128;
    int m0 = blockIdx.y * 64;

    size_t arow = (size_t)(m0 + w * 16 + lm) * 64;

    f32x4 acc[8] = {};

    #pragma unroll
    for (int kc = 0; kc < 2; ++kc) {
        int k = kc * 32 + q * 8;
        bf16x8 ah = *(const bf16x8*)&Ah[arow + k];
        bf16x8 al = *(const bf16x8*)&Al[arow + k];
        #pragma unroll
        for (int j = 0; j < 8; ++j) {
            size_t brow = (size_t)(n0 + j * 16 + lm) * 64;
            bf16x8 bh = *(const bf16x8*)&Bh[brow + k];
            bf16x8 bl = *(const bf16x8*)&Bl[brow + k];
            acc[j] = __builtin_amdgcn_mfma_f32_16x16x32_bf16(al, bh, acc[j], 0, 0, 0);
            acc[j] = __builtin_amdgcn_mfma_f32_16x16x32_bf16(ah, bl, acc[j], 0, 0, 0);
            acc[j] = __builtin_amdgcn_mfma_f32_16x16x32_bf16(ah, bh, acc[j], 0, 0, 0);
        }
    }

    #pragma unroll
    for (int j = 0; j < 8; ++j) {
        int col = n0 + j * 16 + lm;
        float bv = bias[col];
        #pragma unroll
        for (int r = 0; r < 4; ++r) {
            int row = m0 + w * 16 + q * 4 + r;
            float v = acc[j][r] + bv;
            v = (v > 20.f) ? v : log1pf(__expf(v));
            dtb[(size_t)row * D_INNER + col] = v;
        }
    }
}

// ---------------------------------------------------------------------------
// Depthwise causal conv (width 4) + bias + SiLU; also emits hi/lo bf16 split
// of the output for the MFMA x_proj.
// ---------------------------------------------------------------------------
__global__ __launch_bounds__(256)
void conv_silu_kernel(const float* __restrict__ xz, const float* __restrict__ cw,
                      const float* __restrict__ cb, float* __restrict__ xc,
                      unsigned short* __restrict__ xch, unsigned short* __restrict__ xcl)
{
    int idx = blockIdx.x * 256 + threadIdx.x;
    int d  = idx & (D_INNER - 1);
    int t  = (idx >> 11) & (LSEQ - 1);
    int bb = idx >> 21;

    const float* xcol = xz + (size_t)bb * LSEQ * 2 * D_INNER + d;
    float acc = cb[d];
    #pragma unroll
    for (int k = 0; k < D_CONV; ++k) {
        int tt = t + k - (D_CONV - 1);
        if (tt >= 0) acc += xcol[(size_t)tt * 2 * D_INNER] * cw[d * D_CONV + k];
    }
    acc = acc / (1.f + __expf(-acc));
    xc[idx] = acc;
    unsigned hb = bfbits(acc);
    xch[idx] = (unsigned short)hb;
    float hf = __uint_as_float(hb << 16);
    xcl[idx] = (unsigned short)bfbits(acc - hf);
}

// ---------------------------------------------------------------------------
// Chunked selective scan (r7-proven optimum): 2 lanes per d (8 states each),
// 4096 waves, unroll-2 + prefetch-distance-2 pipeline. [r][d] layout.
// ---------------------------------------------------------------------------
#define UNPK4(dst, off, v) { dst[(off)+0]=(v).x; dst[(off)+1]=(v).y; \
                             dst[(off)+2]=(v).z; dst[(off)+3]=(v).w; }

__global__ __launch_bounds__(256)
void scan_pass1(const float* __restrict__ dtb, const float* __restrict__ xc,
                const float* __restrict__ dbl, const float* __restrict__ Alog,
                float* __restrict__ aPbuf, float* __restrict__ bAbuf)
{
    int tid  = threadIdx.x;
    int half = tid & 1;              // states half*8 .. half*8+7
    int blk  = blockIdx.x;           // grid = NB * NCHUNK * 16 = 1024
    int dg   = blk & 15;
    int c    = (blk >> 4) & (NCHUNK - 1);
    int bb   = blk >> 9;
    int d    = dg * 128 + (tid >> 1);

    float A[8];
    {
        const float* pA = Alog + (size_t)d * D_STATE + half * 8;
        float4 v0 = *(const float4*)pA;
        float4 v1 = *(const float4*)(pA + 4);
        A[0] = -__expf(v0.x); A[1] = -__expf(v0.y);
        A[2] = -__expf(v0.z); A[3] = -__expf(v0.w);
        A[4] = -__expf(v1.x); A[5] = -__expf(v1.y);
        A[6] = -__expf(v1.z); A[7] = -__expf(v1.w);
    }

    size_t rowbase = (size_t)bb * LSEQ + (size_t)c * TCH;
    const float* pdt = dtb + rowbase * D_INNER + d;
    const float* pxc = xc  + rowbase * D_INNER + d;
    const float* pbc = dbl + rowbase * 96 + DT_RANK + half * 8;

    float aP[8] = {1.f,1.f,1.f,1.f,1.f,1.f,1.f,1.f};
    float bA[8] = {0.f,0.f,0.f,0.f,0.f,0.f,0.f,0.f};

    // prefetch steps 0 (E) and 1 (O)
    float  dtE = pdt[0], xvE = pxc[0];
    float4 BE0 = *(const float4*)pbc;
    float4 BE1 = *(const float4*)(pbc + 4);
    float  dtO = pdt[D_INNER], xvO = pxc[D_INNER];
    float4 BO0 = *(const float4*)(pbc + 96);
    float4 BO1 = *(const float4*)(pbc + 96 + 4);

    for (int t = 0; t < TCH; t += 2) {
        int t2 = (t + 2 < TCH) ? t + 2 : TCH - 1;
        int t3 = (t + 3 < TCH) ? t + 3 : TCH - 1;
        float  dtEn = pdt[(size_t)t2 * D_INNER], xvEn = pxc[(size_t)t2 * D_INNER];
        float4 BE0n = *(const float4*)(pbc + (size_t)t2 * 96);
        float4 BE1n = *(const float4*)(pbc + (size_t)t2 * 96 + 4);
        float  dtOn = pdt[(size_t)t3 * D_INNER], xvOn = pxc[(size_t)t3 * D_INNER];
        float4 BO0n = *(const float4*)(pbc + (size_t)t3 * 96);
        float4 BO1n = *(const float4*)(pbc + (size_t)t3 * 96 + 4);

        {   // step t
            float B[8];
            UNPK4(B, 0, BE0) UNPK4(B, 4, BE1)
            float dtx = dtE * xvE;
            #pragma unroll
            for (int s = 0; s < 8; ++s) {
                float a = __expf(dtE * A[s]);
                aP[s] *= a;
                bA[s] = bA[s] * a + dtx * B[s];
            }
        }
        {   // step t+1
            float B[8];
            UNPK4(B, 0, BO0) UNPK4(B, 4, BO1)
            float dtx = dtO * xvO;
            #pragma unroll
            for (int s = 0; s < 8; ++s) {
                float a = __expf(dtO * A[s]);
                aP[s] *= a;
                bA[s] = bA[s] * a + dtx * B[s];
            }
        }
        dtE = dtEn; xvE = xvEn; BE0 = BE0n; BE1 = BE1n;
        dtO = dtOn; xvO = xvOn; BO0 = BO0n; BO1 = BO1n;
    }

    float* pa = aPbuf + ((size_t)(bb * NCHUNK + c) * D_INNER + d) * D_STATE + half * 8;
    float* pb = bAbuf + ((size_t)(bb * NCHUNK + c) * D_INNER + d) * D_STATE + half * 8;
    *(float4*)(pa + 0) = make_float4(aP[0], aP[1], aP[2], aP[3]);
    *(float4*)(pa + 4) = make_float4(aP[4], aP[5], aP[6], aP[7]);
    *(float4*)(pb + 0) = make_float4(bA[0], bA[1], bA[2], bA[3]);
    *(float4*)(pb + 4) = make_float4(bA[4], bA[5], bA[6], bA[7]);
}

__global__ __launch_bounds__(256)
void scan_pass2(const float* __restrict__ dtb, const float* __restrict__ xc,
                const float* __restrict__ dbl, const float* __restrict__ xz,
                const float* __restrict__ Alog, const float* __restrict__ Dp,
                const float* __restrict__ aPbuf, const float* __restrict__ bAbuf,
                unsigned short* __restrict__ y)
{
    int tid  = threadIdx.x;
    int half = tid & 1;
    int blk  = blockIdx.x;
    int dg   = blk & 15;
    int c    = (blk >> 4) & (NCHUNK - 1);
    int bb   = blk >> 9;
    int d    = dg * 128 + (tid >> 1);

    float A[8];
    {
        const float* pA = Alog + (size_t)d * D_STATE + half * 8;
        float4 v0 = *(const float4*)pA;
        float4 v1 = *(const float4*)(pA + 4);
        A[0] = -__expf(v0.x); A[1] = -__expf(v0.y);
        A[2] = -__expf(v0.z); A[3] = -__expf(v0.w);
        A[4] = -__expf(v1.x); A[5] = -__expf(v1.y);
        A[6] = -__expf(v1.z); A[7] = -__expf(v1.w);
    }
    float Dd = Dp[d];

    float h[8] = {0.f,0.f,0.f,0.f,0.f,0.f,0.f,0.f};

    // prefix compose over chunks [0, c)
    for (int cc = 0; cc < c; ++cc) {
        const float* pa = aPbuf + ((size_t)(bb * NCHUNK + cc) * D_INNER + d) * D_STATE + half * 8;
        const float* pb = bAbuf + ((size_t)(bb * NCHUNK + cc) * D_INNER + d) * D_STATE + half * 8;
        float4 a0 = *(const float4*)(pa + 0), a1 = *(const float4*)(pa + 4);
        float4 b0 = *(const float4*)(pb + 0), b1 = *(const float4*)(pb + 4);
        float av[8], bv[8];
        UNPK4(av, 0, a0) UNPK4(av, 4, a1)
        UNPK4(bv, 0, b0) UNPK4(bv, 4, b1)
        #pragma unroll
        for (int s = 0; s < 8; ++s) h[s] = h[s] * av[s] + bv[s];
    }

    size_t rowbase = (size_t)bb * LSEQ + (size_t)c * TCH;
    const float* pdt = dtb + rowbase * D_INNER + d;
    const float* pxc = xc  + rowbase * D_INNER + d;
    const float* pz  = xz  + rowbase * 2 * D_INNER + D_INNER + d;
    const float* pbc = dbl + rowbase * 96 + DT_RANK + half * 8;
    unsigned short* py = y + rowbase * D_INNER + d;

    // prefetch steps 0 (E) and 1 (O)
    float  dtE = pdt[0], xvE = pxc[0], zvE = pz[0];
    float4 BE0 = *(const float4*)pbc;
    float4 BE1 = *(const float4*)(pbc + 4);
    float4 CE0 = *(const float4*)(pbc + 16);
    float4 CE1 = *(const float4*)(pbc + 20);
    float  dtO = pdt[D_INNER], xvO = pxc[D_INNER], zvO = pz[2 * D_INNER];
    float4 BO0 = *(const float4*)(pbc + 96);
    float4 BO1 = *(const float4*)(pbc + 96 + 4);
    float4 CO0 = *(const float4*)(pbc + 96 + 16);
    float4 CO1 = *(const float4*)(pbc + 96 + 20);

    for (int t = 0; t < TCH; t += 2) {
        int t2 = (t + 2 < TCH) ? t + 2 : TCH - 1;
        int t3 = (t + 3 < TCH) ? t + 3 : TCH - 1;
        float  dtEn = pdt[(size_t)t2 * D_INNER], xvEn = pxc[(size_t)t2 * D_INNER];
        float  zvEn = pz[(size_t)t2 * 2 * D_INNER];
        float4 BE0n = *(const float4*)(pbc + (size_t)t2 * 96);
        float4 BE1n = *(const float4*)(pbc + (size_t)t2 * 96 + 4);
        float4 CE0n = *(const float4*)(pbc + (size_t)t2 * 96 + 16);
        float4 CE1n = *(const float4*)(pbc + (size_t)t2 * 96 + 20);
        float  dtOn = pdt[(size_t)t3 * D_INNER], xvOn = pxc[(size_t)t3 * D_INNER];
        float  zvOn = pz[(size_t)t3 * 2 * D_INNER];
        float4 BO0n = *(const float4*)(pbc + (size_t)t3 * 96);
        float4 BO1n = *(const float4*)(pbc + (size_t)t3 * 96 + 4);
        float4 CO0n = *(const float4*)(pbc + (size_t)t3 * 96 + 16);
        float4 CO1n = *(const float4*)(pbc + (size_t)t3 * 96 + 20);

        {   // step t
            float B[8], C[8];
            UNPK4(B, 0, BE0) UNPK4(B, 4, BE1)
            UNPK4(C, 0, CE0) UNPK4(C, 4, CE1)
            float dtx = dtE * xvE;
            float p = 0.f;
            #pragma unroll
            for (int s = 0; s < 8; ++s) {
                float a = __expf(dtE * A[s]);
                h[s] = h[s] * a + dtx * B[s];
                p += h[s] * C[s];
            }
            p += __shfl_xor(p, 1, 2);
            if (half == 0) {
                float sz = zvE / (1.f + __expf(-zvE));
                py[(size_t)t * D_INNER] = (unsigned short)bfbits((p + xvE * Dd) * sz);
            }
        }
        {   // step t+1
            float B[8], C[8];
            UNPK4(B, 0, BO0) UNPK4(B, 4, BO1)
            UNPK4(C, 0, CO0) UNPK4(C, 4, CO1)
            float dtx = dtO * xvO;
            float p = 0.f;
            #pragma unroll
            for (int s = 0; s < 8; ++s) {
                float a = __expf(dtO * A[s]);
                h[s] = h[s] * a + dtx * B[s];
                p += h[s] * C[s];
            }
            p += __shfl_xor(p, 1, 2);
            if (half == 0) {
                float sz = zvO / (1.f + __expf(-zvO));
                py[(size_t)(t + 1) * D_INNER] = (unsigned short)bfbits((p + xvO * Dd) * sz);
            }
        }
        dtE = dtEn; xvE = xvEn; zvE = zvEn;
        BE0 = BE0n; BE1 = BE1n; CE0 = CE0n; CE1 = CE1n;
        dtO = dtOn; xvO = xvOn; zvO = zvOn;
        BO0 = BO0n; BO1 = BO1n; CO0 = CO0n; CO1 = CO1n;
    }
}

// ---------------------------------------------------------------------------
extern "C" void kernel_launch(void* const* d_in, const int* in_sizes, int n_in,
                              void* d_out, int out_size, void* d_ws, size_t ws_size,
                              hipStream_t stream)
{
    const float* h_in  = (const float*)d_in[0];
    const float* iw    = (const float*)d_in[1];   // (4, 4096, 1024)
    const float* cw    = (const float*)d_in[2];   // (4, 2048, 4)
    const float* cb    = (const float*)d_in[3];   // (4, 2048)
    const float* xw    = (const float*)d_in[4];   // (4, 96, 2048)
    const float* dw    = (const float*)d_in[5];   // (4, 2048, 64)
    const float* db    = (const float*)d_in[6];   // (4, 2048)
    const float* Alog  = (const float*)d_in[7];   // (4, 2048, 16)
    const float* Dp    = (const float*)d_in[8];   // (4, 2048)
    const float* ow    = (const float*)d_in[9];   // (4, 1024, 2048)
    const float* nw    = (const float*)d_in[10];  // (4, 1024)
    const float* nb    = (const float*)d_in[11];  // (4, 1024)
    const float* nfw   = (const float*)d_in[12];  // (1024,)
    const float* nfb   = (const float*)d_in[13];  // (1024,)

    // workspace layout — identical total (25,362,432 floats)
    float* ws = (float*)d_ws;
    float* residual = ws;                       // 2,097,152
    float* hs       = residual + 2097152;       // 2,097,152
    float* xz       = hs + 2097152;             // 8,388,608  [r][4096]
    float* xc       = xz + 8388608;             // 4,194,304  [r][2048]
    float* dtb      = xc + 4194304;             // 4,194,304  [r][2048]
    float* dbl      = dtb + 4194304;            // 196,608    [r][96]
    float* y        = dbl + 196608;             // 4,194,304

    // aPbuf aliases hs (dead add_ln-consume .. scan); bAbuf = y[2M..4M).
    float* aPbuf = hs;
    float* bAbuf = y + 2097152;

    // bf16 / hi-lo staging, all in dead regions (timeline-disjoint):
    unsigned short* wbuf_in  = (unsigned short*)y;
    unsigned short* hs_bf16  = (unsigned short*)(y + 2097152);
    unsigned short* y_bf16   = (unsigned short*)y;
    unsigned short* xc_hi    = (unsigned short*)y;
    unsigned short* xc_lo    = (unsigned short*)(y + 2097152);
    unsigned short* xwp_hi   = (unsigned short*)hs;
    unsigned short* xwp_lo   = (unsigned short*)(hs + 98304);
    unsigned short* dwp_hi   = (unsigned short*)(hs + 196608);
    unsigned short* dwp_lo   = (unsigned short*)(hs + 262144);
    unsigned short* dtl_hi   = (unsigned short*)(hs + 327680);
    unsigned short* dtl_lo   = (unsigned short*)(hs + 393216);
    unsigned short* wbuf_out = (unsigned short*)dtb;

    const float* cur_add = h_in;
    for (int i = 0; i < N_LAYER; ++i) {
        // residual add + LN, emit bf16
        add_ln_kernel<<<NROWS, 256, 0, stream>>>(cur_add, residual,
                                                 nw + i * D_MODEL, nb + i * D_MODEL,
                                                 hs_bf16, i == 0, 1);
        // fused prep: in_proj w->bf16, xw/dw hi-lo, zero dbl  (one dispatch)
        prep_layer<<<4608, 256, 0, stream>>>(
            iw + (size_t)i * 2 * D_INNER * D_MODEL, wbuf_in,
            xw + (size_t)i * 96 * D_INNER, xwp_hi, xwp_lo,
            dw + (size_t)i * D_INNER * DT_RANK, dwp_hi, dwp_lo,
            dbl);
        // in_proj (bf16 MFMA): -> xz [r][4096] fp32
        gemm_bf16_nt<<<dim3(2 * D_INNER / BBN, NROWS / BBM), 256, 0, stream>>>(
            hs_bf16, wbuf_in, xz, NROWS, 2 * D_INNER, D_MODEL);
        // conv + silu -> xc fp32 + hi/lo bf16 split (for MFMA x_proj)
        conv_silu_kernel<<<NB * LSEQ * D_INNER / 256, 256, 0, stream>>>(
            xz, cw + (size_t)i * D_INNER * D_CONV, cb + i * D_INNER, xc, xc_hi, xc_lo);
        // x_proj (hi/lo split-bf16 MFMA, split-K z=8): -> dbl [r][96]
        xproj_hl<<<dim3(NROWS / 32, 8), 256, 0, stream>>>(
            xc_hi, xc_lo, xwp_hi, xwp_lo, dbl);
        // extract dt-low cols -> compact hi/lo
        dtlow_hl_kernel<<<(NROWS * 16) / 256, 256, 0, stream>>>(dbl, dtl_hi, dtl_lo);
        // dt_proj (hi/lo split-bf16 MFMA + bias + softplus): -> dtb [r][2048]
        dtproj_hl<<<dim3(D_INNER / 128, NROWS / 64), 256, 0, stream>>>(
            dtl_hi, dtl_lo, dwp_hi, dwp_lo, db + i * D_INNER, dtb);
        // chunked selective scan — 2 lanes/d, 4096 waves, depth-2 pipeline
        scan_pass1<<<NB * NCHUNK * (D_INNER / 128), 256, 0, stream>>>(
            dtb, xc, dbl, Alog + (size_t)i * D_INNER * D_STATE, aPbuf, bAbuf);
        scan_pass2<<<NB * NCHUNK * (D_INNER / 128), 256, 0, stream>>>(
            dtb, xc, dbl, xz, Alog + (size_t)i * D_INNER * D_STATE, Dp + i * D_INNER,
            aPbuf, bAbuf, y_bf16);
        // convert out_proj weights -> bf16 (dead dtb space; must follow scan)
        f32_to_bf16_kernel<<<(D_MODEL * D_INNER) / 1024, 256, 0, stream>>>(
            ow + (size_t)i * D_MODEL * D_INNER, wbuf_out);
        // out_proj (bf16 MFMA): -> hs [r][1024] fp32
        gemm_bf16_nt<<<dim3(D_MODEL / BBN, NROWS / BBM), 256, 0, stream>>>(
            y_bf16, wbuf_out, hs, NROWS, D_MODEL, D_INNER);
        cur_add = hs;
    }
    add_ln_kernel<<<NROWS, 256, 0, stream>>>(hs, residual, nfw, nfb, d_out, 0, 0);
}

// Round 10
// 972.256 us; speedup vs baseline: 1.0527x; 1.0130x over previous
//
#include <hip/hip_runtime.h>
#include <math.h>

#define D_MODEL 1024
#define D_INNER 2048
#define D_STATE 16
#define D_CONV  4
#define DT_RANK 64
#define NB      2
#define LSEQ    1024
#define NROWS   (NB * LSEQ)   // 2048
#define LN_EPS  1e-5f
#define N_LAYER 4
#define NCHUNK  32
#define TCH     (LSEQ / NCHUNK)   // 32 steps per chunk

__device__ inline unsigned bfbits(float f) {
    unsigned u = __float_as_uint(f);
    return (u + 0x7fffu + ((u >> 16) & 1u)) >> 16;  // RNE
}

// async global->LDS, 16B per lane. LDS dest = wave-uniform base + lane*16
// (linear, in lane order); global src is per-lane (may be swizzled).
#define GLOAD_LDS16(gp, lp) \
    __builtin_amdgcn_global_load_lds( \
        (const __attribute__((address_space(1))) void*)(gp), \
        (__attribute__((address_space(3))) void*)(lp), 16, 0, 0)

// ---------------------------------------------------------------------------
// Fused residual-add + LayerNorm. bf16out=1: emit bf16; 0: fp32.
// ---------------------------------------------------------------------------
__device__ inline float wave_sum(float s) {
    #pragma unroll
    for (int m = 1; m < 64; m <<= 1) s += __shfl_xor(s, m, 64);
    return s;
}

__global__ __launch_bounds__(256)
void add_ln_kernel(const float* __restrict__ add, float* __restrict__ residual,
                   const float* __restrict__ w, const float* __restrict__ b,
                   void* __restrict__ out, int first, int bf16out)
{
    int row = blockIdx.x;
    int tid = threadIdx.x;
    size_t base = (size_t)row * D_MODEL + tid * 4;

    float4 v = *(const float4*)(add + base);
    if (!first) {
        float4 r = *(const float4*)(residual + base);
        v.x += r.x; v.y += r.y; v.z += r.z; v.w += r.w;
    }
    *(float4*)(residual + base) = v;

    __shared__ float red[8];
    float s = v.x + v.y + v.z + v.w;
    s = wave_sum(s);
    if ((tid & 63) == 0) red[tid >> 6] = s;
    __syncthreads();
    float mu = (red[0] + red[1] + red[2] + red[3]) * (1.0f / D_MODEL);

    float dx = v.x - mu, dy = v.y - mu, dz = v.z - mu, dw2 = v.w - mu;
    float s2 = dx*dx + dy*dy + dz*dz + dw2*dw2;
    s2 = wave_sum(s2);
    if ((tid & 63) == 0) red[4 + (tid >> 6)] = s2;
    __syncthreads();
    float var = (red[4] + red[5] + red[6] + red[7]) * (1.0f / D_MODEL);
    float rs = rsqrtf(var + LN_EPS);

    float4 wv = *(const float4*)(w + tid * 4);
    float4 bv = *(const float4*)(b + tid * 4);
    float4 o;
    o.x = dx  * rs * wv.x + bv.x;
    o.y = dy  * rs * wv.y + bv.y;
    o.z = dz  * rs * wv.z + bv.z;
    o.w = dw2 * rs * wv.w + bv.w;
    if (bf16out) {
        ushort4 ov;
        ov.x = (unsigned short)bfbits(o.x);
        ov.y = (unsigned short)bfbits(o.y);
        ov.z = (unsigned short)bfbits(o.z);
        ov.w = (unsigned short)bfbits(o.w);
        *(ushort4*)((unsigned short*)out + base) = ov;
    } else {
        *(float4*)((float*)out + base) = o;
    }
}

// ---------------------------------------------------------------------------
// fp32 -> bf16 bulk convert (out_proj weights; runs after scan frees dtb).
// ---------------------------------------------------------------------------
__global__ __launch_bounds__(256)
void f32_to_bf16_kernel(const float* __restrict__ src, unsigned short* __restrict__ dst)
{
    int i = blockIdx.x * 256 + threadIdx.x;
    float4 v = *(const float4*)(src + (size_t)i * 4);
    ushort4 o;
    o.x = (unsigned short)bfbits(v.x);
    o.y = (unsigned short)bfbits(v.y);
    o.z = (unsigned short)bfbits(v.z);
    o.w = (unsigned short)bfbits(v.w);
    *(ushort4*)(dst + (size_t)i * 4) = o;
}

// ---------------------------------------------------------------------------
// Fused per-layer prep (r9-proven): one dispatch does
//   blocks [0,4096):     in_proj weights fp32 -> bf16
//   blocks [4096,4288):  xw hi/lo split (96x2048)
//   blocks [4288,4416):  dw hi/lo split (2048x64)
//   blocks [4416,4608):  zero dbl (196608 floats)
// ---------------------------------------------------------------------------
__device__ inline void hl_split4(float4 v, ushort4* h4, ushort4* l4)
{
    ushort4 h, l;
    float f;
    h.x = (unsigned short)bfbits(v.x); f = __uint_as_float((unsigned)h.x << 16); l.x = (unsigned short)bfbits(v.x - f);
    h.y = (unsigned short)bfbits(v.y); f = __uint_as_float((unsigned)h.y << 16); l.y = (unsigned short)bfbits(v.y - f);
    h.z = (unsigned short)bfbits(v.z); f = __uint_as_float((unsigned)h.z << 16); l.z = (unsigned short)bfbits(v.z - f);
    h.w = (unsigned short)bfbits(v.w); f = __uint_as_float((unsigned)h.w << 16); l.w = (unsigned short)bfbits(v.w - f);
    *h4 = h; *l4 = l;
}

__global__ __launch_bounds__(256)
void prep_layer(const float* __restrict__ iw, unsigned short* __restrict__ wbuf_in,
                const float* __restrict__ xw, unsigned short* __restrict__ xwh,
                unsigned short* __restrict__ xwl,
                const float* __restrict__ dw, unsigned short* __restrict__ dwh,
                unsigned short* __restrict__ dwl,
                float* __restrict__ dbl)
{
    int b = blockIdx.x;
    int tid = threadIdx.x;
    if (b < 4096) {
        int i = b * 256 + tid;
        float4 v = *(const float4*)(iw + (size_t)i * 4);
        ushort4 o;
        o.x = (unsigned short)bfbits(v.x);
        o.y = (unsigned short)bfbits(v.y);
        o.z = (unsigned short)bfbits(v.z);
        o.w = (unsigned short)bfbits(v.w);
        *(ushort4*)(wbuf_in + (size_t)i * 4) = o;
    } else if (b < 4288) {
        int i = (b - 4096) * 256 + tid;
        float4 v = *(const float4*)(xw + (size_t)i * 4);
        hl_split4(v, (ushort4*)(xwh + (size_t)i * 4), (ushort4*)(xwl + (size_t)i * 4));
    } else if (b < 4416) {
        int i = (b - 4288) * 256 + tid;
        float4 v = *(const float4*)(dw + (size_t)i * 4);
        hl_split4(v, (ushort4*)(dwh + (size_t)i * 4), (ushort4*)(dwl + (size_t)i * 4));
    } else {
        int i = (b - 4416) * 256 + tid;
        *(float4*)(dbl + (size_t)i * 4) = make_float4(0.f, 0.f, 0.f, 0.f);
    }
}

// ---------------------------------------------------------------------------
// bf16 MFMA NT GEMM, v2: global_load_lds width-16 staging (no VGPR round
// trip), linear LDS [128][64], XOR-swizzle (slot ^= row&7) applied on the
// pre-swizzled GLOBAL source and on the ds_read side (rule: linear dest +
// inverse-swz source + swz read). 128x128 tile, BK=64, 4 waves.
// ---------------------------------------------------------------------------
using bf16x8 = __attribute__((ext_vector_type(8))) short;
using f32x4  = __attribute__((ext_vector_type(4))) float;

#define BBM 128
#define BBN 128
#define BBK 64

__global__ __launch_bounds__(256)
void gemm_bf16_nt(const unsigned short* __restrict__ A, const unsigned short* __restrict__ Bw,
                  float* __restrict__ C, int M, int N, int K)
{
    __shared__ unsigned short As[BBM * BBK];   // linear [128][64], 128B rows
    __shared__ unsigned short Bs[BBN * BBK];

    int tid = threadIdx.x;
    int m0 = blockIdx.y * BBM, n0 = blockIdx.x * BBN;
    int lane = tid & 63, w = tid >> 6;
    int wm = (w >> 1) * 64, wn = (w & 1) * 64;
    int lm = lane & 15, q = lane >> 4;

    // staging: wave w covers rows [w*32, w*32+32) in 4 calls of 8 rows.
    // lane l -> rel-row l>>3, stored slot l&7; src col pre-swizzled so that
    // LDS[row][slot] holds logical cols (slot ^ (row&7))*8 .. +8.
    int lrow8 = lane >> 3;
    int scol  = ((lane & 7) ^ lrow8) * 8;

    f32x4 acc[4][4] = {};

    for (int k0 = 0; k0 < K; k0 += BBK) {
        #pragma unroll
        for (int j = 0; j < 4; ++j) {
            int rbase = w * 32 + j * 8;
            GLOAD_LDS16(A + (size_t)(m0 + rbase + lrow8) * K + k0 + scol,
                        &As[rbase * BBK]);
        }
        #pragma unroll
        for (int j = 0; j < 4; ++j) {
            int rbase = w * 32 + j * 8;
            GLOAD_LDS16(Bw + (size_t)(n0 + rbase + lrow8) * K + k0 + scol,
                        &Bs[rbase * BBK]);
        }
        __syncthreads();   // drains vmcnt (async LDS writes) + all waves
        #pragma unroll
        for (int kk = 0; kk < BBK; kk += 32) {
            bf16x8 af[4], bf[4];
            #pragma unroll
            for (int i = 0; i < 4; ++i) {
                int row = wm + i * 16 + lm;
                int col = (kk + q * 8) ^ ((row & 7) << 3);
                af[i] = *(const bf16x8*)&As[row * BBK + col];
            }
            #pragma unroll
            for (int j = 0; j < 4; ++j) {
                int row = wn + j * 16 + lm;
                int col = (kk + q * 8) ^ ((row & 7) << 3);
                bf[j] = *(const bf16x8*)&Bs[row * BBK + col];
            }
            #pragma unroll
            for (int i = 0; i < 4; ++i)
                #pragma unroll
                for (int j = 0; j < 4; ++j)
                    acc[i][j] = __builtin_amdgcn_mfma_f32_16x16x32_bf16(
                        af[i], bf[j], acc[i][j], 0, 0, 0);
        }
        __syncthreads();
    }

    #pragma unroll
    for (int i = 0; i < 4; ++i)
        #pragma unroll
        for (int j = 0; j < 4; ++j)
            #pragma unroll
            for (int r = 0; r < 4; ++r) {
                int row = m0 + wm + i * 16 + q * 4 + r;
                int col = n0 + wn + j * 16 + lm;
                C[(size_t)row * N + col] = acc[i][j][r];
            }
}

// ---------------------------------------------------------------------------
// x_proj via hi/lo split-bf16 MFMA, split-K, NO LDS (direct global fragment
// loads). Grid: dim3(64 mtile(32 rows), 8 z(kslice 256)).
// ---------------------------------------------------------------------------
__global__ __launch_bounds__(256)
void xproj_hl(const unsigned short* __restrict__ Ah, const unsigned short* __restrict__ Al,
              const unsigned short* __restrict__ Bh, const unsigned short* __restrict__ Bl,
              float* __restrict__ C)
{
    int tid = threadIdx.x;
    int lane = tid & 63, w = tid >> 6;
    int lm = lane & 15, q = lane >> 4;
    int m0 = blockIdx.x * 32;
    int kb = blockIdx.y * 256;

    int wm = (w & 1) * 16;          // m-half
    int wn = (w >> 1) * 48;         // n-half (3 frags of 16)

    size_t arow = (size_t)(m0 + wm + lm) * 2048;

    f32x4 acc[3] = {};

    #pragma unroll 2
    for (int kc = 0; kc < 8; ++kc) {
        int k = kb + kc * 32 + q * 8;
        bf16x8 ah = *(const bf16x8*)&Ah[arow + k];
        bf16x8 al = *(const bf16x8*)&Al[arow + k];
        #pragma unroll
        for (int j = 0; j < 3; ++j) {
            size_t brow = (size_t)(wn + j * 16 + lm) * 2048;
            bf16x8 bh = *(const bf16x8*)&Bh[brow + k];
            bf16x8 bl = *(const bf16x8*)&Bl[brow + k];
            acc[j] = __builtin_amdgcn_mfma_f32_16x16x32_bf16(al, bh, acc[j], 0, 0, 0);
            acc[j] = __builtin_amdgcn_mfma_f32_16x16x32_bf16(ah, bl, acc[j], 0, 0, 0);
            acc[j] = __builtin_amdgcn_mfma_f32_16x16x32_bf16(ah, bh, acc[j], 0, 0, 0);
        }
    }

    #pragma unroll
    for (int j = 0; j < 3; ++j) {
        int col = wn + j * 16 + lm;
        #pragma unroll
        for (int r = 0; r < 4; ++r) {
            int row = m0 + wm + q * 4 + r;
            atomicAdd(&C[(size_t)row * 96 + col], acc[j][r]);
        }
    }
}

// ---------------------------------------------------------------------------
// dt_proj via hi/lo split-bf16 MFMA + fused bias+softplus. NO LDS.
// A now read DIRECTLY from dbl fp32 [2048][96] cols 0..63, hi/lo split
// in-register (same RNE ops as the removed dtlow_hl kernel).
// Grid: dim3(16 ntile(128), 32 mtile(64)).
// ---------------------------------------------------------------------------
__global__ __launch_bounds__(256)
void dtproj_hl(const float* __restrict__ dbl,
               const unsigned short* __restrict__ Bh, const unsigned short* __restrict__ Bl,
               const float* __restrict__ bias, float* __restrict__ dtb)
{
    int tid = threadIdx.x;
    int lane = tid & 63, w = tid >> 6;
    int lm = lane & 15, q = lane >> 4;
    int n0 = blockIdx.x * 128;
    int m0 = blockIdx.y * 64;

    const float* arow = dbl + (size_t)(m0 + w * 16 + lm) * 96;

    f32x4 acc[8] = {};

    #pragma unroll
    for (int kc = 0; kc < 2; ++kc) {
        int k = kc * 32 + q * 8;
        float4 v0 = *(const float4*)(arow + k);
        float4 v1 = *(const float4*)(arow + k + 4);
        float vv[8] = {v0.x, v0.y, v0.z, v0.w, v1.x, v1.y, v1.z, v1.w};
        bf16x8 ah, al;
        #pragma unroll
        for (int s = 0; s < 8; ++s) {
            unsigned hb = bfbits(vv[s]);
            ah[s] = (short)hb;
            al[s] = (short)bfbits(vv[s] - __uint_as_float(hb << 16));
        }
        #pragma unroll
        for (int j = 0; j < 8; ++j) {
            size_t brow = (size_t)(n0 + j * 16 + lm) * 64;
            bf16x8 bh = *(const bf16x8*)&Bh[brow + k];
            bf16x8 bl = *(const bf16x8*)&Bl[brow + k];
            acc[j] = __builtin_amdgcn_mfma_f32_16x16x32_bf16(al, bh, acc[j], 0, 0, 0);
            acc[j] = __builtin_amdgcn_mfma_f32_16x16x32_bf16(ah, bl, acc[j], 0, 0, 0);
            acc[j] = __builtin_amdgcn_mfma_f32_16x16x32_bf16(ah, bh, acc[j], 0, 0, 0);
        }
    }

    #pragma unroll
    for (int j = 0; j < 8; ++j) {
        int col = n0 + j * 16 + lm;
        float bv = bias[col];
        #pragma unroll
        for (int r = 0; r < 4; ++r) {
            int row = m0 + w * 16 + q * 4 + r;
            float v = acc[j][r] + bv;
            v = (v > 20.f) ? v : log1pf(__expf(v));
            dtb[(size_t)row * D_INNER + col] = v;
        }
    }
}

// ---------------------------------------------------------------------------
// Depthwise causal conv (width 4) + bias + SiLU; also emits hi/lo bf16 split
// of the output for the MFMA x_proj.
// ---------------------------------------------------------------------------
__global__ __launch_bounds__(256)
void conv_silu_kernel(const float* __restrict__ xz, const float* __restrict__ cw,
                      const float* __restrict__ cb, float* __restrict__ xc,
                      unsigned short* __restrict__ xch, unsigned short* __restrict__ xcl)
{
    int idx = blockIdx.x * 256 + threadIdx.x;
    int d  = idx & (D_INNER - 1);
    int t  = (idx >> 11) & (LSEQ - 1);
    int bb = idx >> 21;

    const float* xcol = xz + (size_t)bb * LSEQ * 2 * D_INNER + d;
    float acc = cb[d];
    #pragma unroll
    for (int k = 0; k < D_CONV; ++k) {
        int tt = t + k - (D_CONV - 1);
        if (tt >= 0) acc += xcol[(size_t)tt * 2 * D_INNER] * cw[d * D_CONV + k];
    }
    acc = acc / (1.f + __expf(-acc));
    xc[idx] = acc;
    unsigned hb = bfbits(acc);
    xch[idx] = (unsigned short)hb;
    float hf = __uint_as_float(hb << 16);
    xcl[idx] = (unsigned short)bfbits(acc - hf);
}

// ---------------------------------------------------------------------------
// Chunked selective scan (r7-proven optimum): 2 lanes per d (8 states each),
// 4096 waves, unroll-2 + prefetch-distance-2 pipeline. [r][d] layout.
// ---------------------------------------------------------------------------
#define UNPK4(dst, off, v) { dst[(off)+0]=(v).x; dst[(off)+1]=(v).y; \
                             dst[(off)+2]=(v).z; dst[(off)+3]=(v).w; }

__global__ __launch_bounds__(256)
void scan_pass1(const float* __restrict__ dtb, const float* __restrict__ xc,
                const float* __restrict__ dbl, const float* __restrict__ Alog,
                float* __restrict__ aPbuf, float* __restrict__ bAbuf)
{
    int tid  = threadIdx.x;
    int half = tid & 1;              // states half*8 .. half*8+7
    int blk  = blockIdx.x;           // grid = NB * NCHUNK * 16 = 1024
    int dg   = blk & 15;
    int c    = (blk >> 4) & (NCHUNK - 1);
    int bb   = blk >> 9;
    int d    = dg * 128 + (tid >> 1);

    float A[8];
    {
        const float* pA = Alog + (size_t)d * D_STATE + half * 8;
        float4 v0 = *(const float4*)pA;
        float4 v1 = *(const float4*)(pA + 4);
        A[0] = -__expf(v0.x); A[1] = -__expf(v0.y);
        A[2] = -__expf(v0.z); A[3] = -__expf(v0.w);
        A[4] = -__expf(v1.x); A[5] = -__expf(v1.y);
        A[6] = -__expf(v1.z); A[7] = -__expf(v1.w);
    }

    size_t rowbase = (size_t)bb * LSEQ + (size_t)c * TCH;
    const float* pdt = dtb + rowbase * D_INNER + d;
    const float* pxc = xc  + rowbase * D_INNER + d;
    const float* pbc = dbl + rowbase * 96 + DT_RANK + half * 8;

    float aP[8] = {1.f,1.f,1.f,1.f,1.f,1.f,1.f,1.f};
    float bA[8] = {0.f,0.f,0.f,0.f,0.f,0.f,0.f,0.f};

    // prefetch steps 0 (E) and 1 (O)
    float  dtE = pdt[0], xvE = pxc[0];
    float4 BE0 = *(const float4*)pbc;
    float4 BE1 = *(const float4*)(pbc + 4);
    float  dtO = pdt[D_INNER], xvO = pxc[D_INNER];
    float4 BO0 = *(const float4*)(pbc + 96);
    float4 BO1 = *(const float4*)(pbc + 96 + 4);

    for (int t = 0; t < TCH; t += 2) {
        int t2 = (t + 2 < TCH) ? t + 2 : TCH - 1;
        int t3 = (t + 3 < TCH) ? t + 3 : TCH - 1;
        float  dtEn = pdt[(size_t)t2 * D_INNER], xvEn = pxc[(size_t)t2 * D_INNER];
        float4 BE0n = *(const float4*)(pbc + (size_t)t2 * 96);
        float4 BE1n = *(const float4*)(pbc + (size_t)t2 * 96 + 4);
        float  dtOn = pdt[(size_t)t3 * D_INNER], xvOn = pxc[(size_t)t3 * D_INNER];
        float4 BO0n = *(const float4*)(pbc + (size_t)t3 * 96);
        float4 BO1n = *(const float4*)(pbc + (size_t)t3 * 96 + 4);

        {   // step t
            float B[8];
            UNPK4(B, 0, BE0) UNPK4(B, 4, BE1)
            float dtx = dtE * xvE;
            #pragma unroll
            for (int s = 0; s < 8; ++s) {
                float a = __expf(dtE * A[s]);
                aP[s] *= a;
                bA[s] = bA[s] * a + dtx * B[s];
            }
        }
        {   // step t+1
            float B[8];
            UNPK4(B, 0, BO0) UNPK4(B, 4, BO1)
            float dtx = dtO * xvO;
            #pragma unroll
            for (int s = 0; s < 8; ++s) {
                float a = __expf(dtO * A[s]);
                aP[s] *= a;
                bA[s] = bA[s] * a + dtx * B[s];
            }
        }
        dtE = dtEn; xvE = xvEn; BE0 = BE0n; BE1 = BE1n;
        dtO = dtOn; xvO = xvOn; BO0 = BO0n; BO1 = BO1n;
    }

    float* pa = aPbuf + ((size_t)(bb * NCHUNK + c) * D_INNER + d) * D_STATE + half * 8;
    float* pb = bAbuf + ((size_t)(bb * NCHUNK + c) * D_INNER + d) * D_STATE + half * 8;
    *(float4*)(pa + 0) = make_float4(aP[0], aP[1], aP[2], aP[3]);
    *(float4*)(pa + 4) = make_float4(aP[4], aP[5], aP[6], aP[7]);
    *(float4*)(pb + 0) = make_float4(bA[0], bA[1], bA[2], bA[3]);
    *(float4*)(pb + 4) = make_float4(bA[4], bA[5], bA[6], bA[7]);
}

__global__ __launch_bounds__(256)
void scan_pass2(const float* __restrict__ dtb, const float* __restrict__ xc,
                const float* __restrict__ dbl, const float* __restrict__ xz,
                const float* __restrict__ Alog, const float* __restrict__ Dp,
                const float* __restrict__ aPbuf, const float* __restrict__ bAbuf,
                unsigned short* __restrict__ y)
{
    int tid  = threadIdx.x;
    int half = tid & 1;
    int blk  = blockIdx.x;
    int dg   = blk & 15;
    int c    = (blk >> 4) & (NCHUNK - 1);
    int bb   = blk >> 9;
    int d    = dg * 128 + (tid >> 1);

    float A[8];
    {
        const float* pA = Alog + (size_t)d * D_STATE + half * 8;
        float4 v0 = *(const float4*)pA;
        float4 v1 = *(const float4*)(pA + 4);
        A[0] = -__expf(v0.x); A[1] = -__expf(v0.y);
        A[2] = -__expf(v0.z); A[3] = -__expf(v0.w);
        A[4] = -__expf(v1.x); A[5] = -__expf(v1.y);
        A[6] = -__expf(v1.z); A[7] = -__expf(v1.w);
    }
    float Dd = Dp[d];

    float h[8] = {0.f,0.f,0.f,0.f,0.f,0.f,0.f,0.f};

    // prefix compose over chunks [0, c)
    for (int cc = 0; cc < c; ++cc) {
        const float* pa = aPbuf + ((size_t)(bb * NCHUNK + cc) * D_INNER + d) * D_STATE + half * 8;
        const float* pb = bAbuf + ((size_t)(bb * NCHUNK + cc) * D_INNER + d) * D_STATE + half * 8;
        float4 a0 = *(const float4*)(pa + 0), a1 = *(const float4*)(pa + 4);
        float4 b0 = *(const float4*)(pb + 0), b1 = *(const float4*)(pb + 4);
        float av[8], bv[8];
        UNPK4(av, 0, a0) UNPK4(av, 4, a1)
        UNPK4(bv, 0, b0) UNPK4(bv, 4, b1)
        #pragma unroll
        for (int s = 0; s < 8; ++s) h[s] = h[s] * av[s] + bv[s];
    }

    size_t rowbase = (size_t)bb * LSEQ + (size_t)c * TCH;
    const float* pdt = dtb + rowbase * D_INNER + d;
    const float* pxc = xc  + rowbase * D_INNER + d;
    const float* pz  = xz  + rowbase * 2 * D_INNER + D_INNER + d;
    const float* pbc = dbl + rowbase * 96 + DT_RANK + half * 8;
    unsigned short* py = y + rowbase * D_INNER + d;

    // prefetch steps 0 (E) and 1 (O)
    float  dtE = pdt[0], xvE = pxc[0], zvE = pz[0];
    float4 BE0 = *(const float4*)pbc;
    float4 BE1 = *(const float4*)(pbc + 4);
    float4 CE0 = *(const float4*)(pbc + 16);
    float4 CE1 = *(const float4*)(pbc + 20);
    float  dtO = pdt[D_INNER], xvO = pxc[D_INNER], zvO = pz[2 * D_INNER];
    float4 BO0 = *(const float4*)(pbc + 96);
    float4 BO1 = *(const float4*)(pbc + 96 + 4);
    float4 CO0 = *(const float4*)(pbc + 96 + 16);
    float4 CO1 = *(const float4*)(pbc + 96 + 20);

    for (int t = 0; t < TCH; t += 2) {
        int t2 = (t + 2 < TCH) ? t + 2 : TCH - 1;
        int t3 = (t + 3 < TCH) ? t + 3 : TCH - 1;
        float  dtEn = pdt[(size_t)t2 * D_INNER], xvEn = pxc[(size_t)t2 * D_INNER];
        float  zvEn = pz[(size_t)t2 * 2 * D_INNER];
        float4 BE0n = *(const float4*)(pbc + (size_t)t2 * 96);
        float4 BE1n = *(const float4*)(pbc + (size_t)t2 * 96 + 4);
        float4 CE0n = *(const float4*)(pbc + (size_t)t2 * 96 + 16);
        float4 CE1n = *(const float4*)(pbc + (size_t)t2 * 96 + 20);
        float  dtOn = pdt[(size_t)t3 * D_INNER], xvOn = pxc[(size_t)t3 * D_INNER];
        float  zvOn = pz[(size_t)t3 * 2 * D_INNER];
        float4 BO0n = *(const float4*)(pbc + (size_t)t3 * 96);
        float4 BO1n = *(const float4*)(pbc + (size_t)t3 * 96 + 4);
        float4 CO0n = *(const float4*)(pbc + (size_t)t3 * 96 + 16);
        float4 CO1n = *(const float4*)(pbc + (size_t)t3 * 96 + 20);

        {   // step t
            float B[8], C[8];
            UNPK4(B, 0, BE0) UNPK4(B, 4, BE1)
            UNPK4(C, 0, CE0) UNPK4(C, 4, CE1)
            float dtx = dtE * xvE;
            float p = 0.f;
            #pragma unroll
            for (int s = 0; s < 8; ++s) {
                float a = __expf(dtE * A[s]);
                h[s] = h[s] * a + dtx * B[s];
                p += h[s] * C[s];
            }
            p += __shfl_xor(p, 1, 2);
            if (half == 0) {
                float sz = zvE / (1.f + __expf(-zvE));
                py[(size_t)t * D_INNER] = (unsigned short)bfbits((p + xvE * Dd) * sz);
            }
        }
        {   // step t+1
            float B[8], C[8];
            UNPK4(B, 0, BO0) UNPK4(B, 4, BO1)
            UNPK4(C, 0, CO0) UNPK4(C, 4, CO1)
            float dtx = dtO * xvO;
            float p = 0.f;
            #pragma unroll
            for (int s = 0; s < 8; ++s) {
                float a = __expf(dtO * A[s]);
                h[s] = h[s] * a + dtx * B[s];
                p += h[s] * C[s];
            }
            p += __shfl_xor(p, 1, 2);
            if (half == 0) {
                float sz = zvO / (1.f + __expf(-zvO));
                py[(size_t)(t + 1) * D_INNER] = (unsigned short)bfbits((p + xvO * Dd) * sz);
            }
        }
        dtE = dtEn; xvE = xvEn; zvE = zvEn;
        BE0 = BE0n; BE1 = BE1n; CE0 = CE0n; CE1 = CE1n;
        dtO = dtOn; xvO = xvOn; zvO = zvOn;
        BO0 = BO0n; BO1 = BO1n; CO0 = CO0n; CO1 = CO1n;
    }
}

// ---------------------------------------------------------------------------
extern "C" void kernel_launch(void* const* d_in, const int* in_sizes, int n_in,
                              void* d_out, int out_size, void* d_ws, size_t ws_size,
                              hipStream_t stream)
{
    const float* h_in  = (const float*)d_in[0];
    const float* iw    = (const float*)d_in[1];   // (4, 4096, 1024)
    const float* cw    = (const float*)d_in[2];   // (4, 2048, 4)
    const float* cb    = (const float*)d_in[3];   // (4, 2048)
    const float* xw    = (const float*)d_in[4];   // (4, 96, 2048)
    const float* dw    = (const float*)d_in[5];   // (4, 2048, 64)
    const float* db    = (const float*)d_in[6];   // (4, 2048)
    const float* Alog  = (const float*)d_in[7];   // (4, 2048, 16)
    const float* Dp    = (const float*)d_in[8];   // (4, 2048)
    const float* ow    = (const float*)d_in[9];   // (4, 1024, 2048)
    const float* nw    = (const float*)d_in[10];  // (4, 1024)
    const float* nb    = (const float*)d_in[11];  // (4, 1024)
    const float* nfw   = (const float*)d_in[12];  // (1024,)
    const float* nfb   = (const float*)d_in[13];  // (1024,)

    // workspace layout — identical total (25,362,432 floats)
    float* ws = (float*)d_ws;
    float* residual = ws;                       // 2,097,152
    float* hs       = residual + 2097152;       // 2,097,152
    float* xz       = hs + 2097152;             // 8,388,608  [r][4096]
    float* xc       = xz + 8388608;             // 4,194,304  [r][2048]
    float* dtb      = xc + 4194304;             // 4,194,304  [r][2048]
    float* dbl      = dtb + 4194304;            // 196,608    [r][96]
    float* y        = dbl + 196608;             // 4,194,304

    // aPbuf aliases hs (dead add_ln-consume .. scan); bAbuf = y[2M..4M).
    float* aPbuf = hs;
    float* bAbuf = y + 2097152;

    // bf16 / hi-lo staging, all in dead regions (timeline-disjoint):
    unsigned short* wbuf_in  = (unsigned short*)y;
    unsigned short* hs_bf16  = (unsigned short*)(y + 2097152);
    unsigned short* y_bf16   = (unsigned short*)y;
    unsigned short* xc_hi    = (unsigned short*)y;
    unsigned short* xc_lo    = (unsigned short*)(y + 2097152);
    unsigned short* xwp_hi   = (unsigned short*)hs;
    unsigned short* xwp_lo   = (unsigned short*)(hs + 98304);
    unsigned short* dwp_hi   = (unsigned short*)(hs + 196608);
    unsigned short* dwp_lo   = (unsigned short*)(hs + 262144);
    unsigned short* wbuf_out = (unsigned short*)dtb;

    const float* cur_add = h_in;
    for (int i = 0; i < N_LAYER; ++i) {
        // residual add + LN, emit bf16
        add_ln_kernel<<<NROWS, 256, 0, stream>>>(cur_add, residual,
                                                 nw + i * D_MODEL, nb + i * D_MODEL,
                                                 hs_bf16, i == 0, 1);
        // fused prep: in_proj w->bf16, xw/dw hi-lo, zero dbl  (one dispatch)
        prep_layer<<<4608, 256, 0, stream>>>(
            iw + (size_t)i * 2 * D_INNER * D_MODEL, wbuf_in,
            xw + (size_t)i * 96 * D_INNER, xwp_hi, xwp_lo,
            dw + (size_t)i * D_INNER * DT_RANK, dwp_hi, dwp_lo,
            dbl);
        // in_proj (bf16 MFMA, global_load_lds staging): -> xz [r][4096] fp32
        gemm_bf16_nt<<<dim3(2 * D_INNER / BBN, NROWS / BBM), 256, 0, stream>>>(
            hs_bf16, wbuf_in, xz, NROWS, 2 * D_INNER, D_MODEL);
        // conv + silu -> xc fp32 + hi/lo bf16 split (for MFMA x_proj)
        conv_silu_kernel<<<NB * LSEQ * D_INNER / 256, 256, 0, stream>>>(
            xz, cw + (size_t)i * D_INNER * D_CONV, cb + i * D_INNER, xc, xc_hi, xc_lo);
        // x_proj (hi/lo split-bf16 MFMA, split-K z=8): -> dbl [r][96]
        xproj_hl<<<dim3(NROWS / 32, 8), 256, 0, stream>>>(
            xc_hi, xc_lo, xwp_hi, xwp_lo, dbl);
        // dt_proj (reads dbl directly, in-reg hi/lo split + bias + softplus)
        dtproj_hl<<<dim3(D_INNER / 128, NROWS / 64), 256, 0, stream>>>(
            dbl, dwp_hi, dwp_lo, db + i * D_INNER, dtb);
        // chunked selective scan — 2 lanes/d, 4096 waves, depth-2 pipeline
        scan_pass1<<<NB * NCHUNK * (D_INNER / 128), 256, 0, stream>>>(
            dtb, xc, dbl, Alog + (size_t)i * D_INNER * D_STATE, aPbuf, bAbuf);
        scan_pass2<<<NB * NCHUNK * (D_INNER / 128), 256, 0, stream>>>(
            dtb, xc, dbl, xz, Alog + (size_t)i * D_INNER * D_STATE, Dp + i * D_INNER,
            aPbuf, bAbuf, y_bf16);
        // convert out_proj weights -> bf16 (dead dtb space; must follow scan)
        f32_to_bf16_kernel<<<(D_MODEL * D_INNER) / 1024, 256, 0, stream>>>(
            ow + (size_t)i * D_MODEL * D_INNER, wbuf_out);
        // out_proj (bf16 MFMA, global_load_lds staging): -> hs [r][1024] fp32
        gemm_bf16_nt<<<dim3(D_MODEL / BBN, NROWS / BBM), 256, 0, stream>>>(
            y_bf16, wbuf_out, hs, NROWS, D_MODEL, D_INNER);
        cur_add = hs;
    }
    add_ln_kernel<<<NROWS, 256, 0, stream>>>(hs, residual, nfw, nfb, d_out, 0, 0);
}

// Round 12
// 961.317 us; speedup vs baseline: 1.0646x; 1.0114x over previous
//
#include <hip/hip_runtime.h>
#include <math.h>

#define D_MODEL 1024
#define D_INNER 2048
#define D_STATE 16
#define D_CONV  4
#define DT_RANK 64
#define NB      2
#define LSEQ    1024
#define NROWS   (NB * LSEQ)   // 2048
#define LN_EPS  1e-5f
#define N_LAYER 4
#define NCHUNK  32
#define TCH     (LSEQ / NCHUNK)   // 32 steps per chunk

__device__ inline unsigned bfbits(float f) {
    unsigned u = __float_as_uint(f);
    return (u + 0x7fffu + ((u >> 16) & 1u)) >> 16;  // RNE
}

// async global->LDS, 16B per lane. LDS dest = wave-uniform base + lane*16.
#define GLOAD_LDS16(gp, lp) \
    __builtin_amdgcn_global_load_lds( \
        (const __attribute__((address_space(1))) void*)(gp), \
        (__attribute__((address_space(3))) void*)(lp), 16, 0, 0)

// ---------------------------------------------------------------------------
// Fused residual-add + LayerNorm body (shared by fused and standalone kernels)
// ---------------------------------------------------------------------------
__device__ inline float wave_sum(float s) {
    #pragma unroll
    for (int m = 1; m < 64; m <<= 1) s += __shfl_xor(s, m, 64);
    return s;
}

__device__ inline void add_ln_body(int row, int tid,
                                   const float* __restrict__ add,
                                   float* __restrict__ residual,
                                   const float* __restrict__ w, const float* __restrict__ b,
                                   void* __restrict__ out, int first, int bf16out,
                                   float* red)
{
    size_t base = (size_t)row * D_MODEL + tid * 4;

    float4 v = *(const float4*)(add + base);
    if (!first) {
        float4 r = *(const float4*)(residual + base);
        v.x += r.x; v.y += r.y; v.z += r.z; v.w += r.w;
    }
    *(float4*)(residual + base) = v;

    float s = v.x + v.y + v.z + v.w;
    s = wave_sum(s);
    if ((tid & 63) == 0) red[tid >> 6] = s;
    __syncthreads();
    float mu = (red[0] + red[1] + red[2] + red[3]) * (1.0f / D_MODEL);

    float dx = v.x - mu, dy = v.y - mu, dz = v.z - mu, dw2 = v.w - mu;
    float s2 = dx*dx + dy*dy + dz*dz + dw2*dw2;
    s2 = wave_sum(s2);
    if ((tid & 63) == 0) red[4 + (tid >> 6)] = s2;
    __syncthreads();
    float var = (red[4] + red[5] + red[6] + red[7]) * (1.0f / D_MODEL);
    float rs = rsqrtf(var + LN_EPS);

    float4 wv = *(const float4*)(w + tid * 4);
    float4 bv = *(const float4*)(b + tid * 4);
    float4 o;
    o.x = dx  * rs * wv.x + bv.x;
    o.y = dy  * rs * wv.y + bv.y;
    o.z = dz  * rs * wv.z + bv.z;
    o.w = dw2 * rs * wv.w + bv.w;
    if (bf16out) {
        ushort4 ov;
        ov.x = (unsigned short)bfbits(o.x);
        ov.y = (unsigned short)bfbits(o.y);
        ov.z = (unsigned short)bfbits(o.z);
        ov.w = (unsigned short)bfbits(o.w);
        *(ushort4*)((unsigned short*)out + base) = ov;
    } else {
        *(float4*)((float*)out + base) = o;
    }
}

__global__ __launch_bounds__(256)
void add_ln_kernel(const float* __restrict__ add, float* __restrict__ residual,
                   const float* __restrict__ w, const float* __restrict__ b,
                   void* __restrict__ out, int first, int bf16out)
{
    __shared__ float red[8];
    add_ln_body(blockIdx.x, threadIdx.x, add, residual, w, b, out, first, bf16out, red);
}

// ---------------------------------------------------------------------------
// fp32 -> bf16 bulk convert (out_proj weights; runs after scan frees dtb).
// ---------------------------------------------------------------------------
__global__ __launch_bounds__(256)
void f32_to_bf16_kernel(const float* __restrict__ src, unsigned short* __restrict__ dst)
{
    int i = blockIdx.x * 256 + threadIdx.x;
    float4 v = *(const float4*)(src + (size_t)i * 4);
    ushort4 o;
    o.x = (unsigned short)bfbits(v.x);
    o.y = (unsigned short)bfbits(v.y);
    o.z = (unsigned short)bfbits(v.z);
    o.w = (unsigned short)bfbits(v.w);
    *(ushort4*)(dst + (size_t)i * 4) = o;
}

// ---------------------------------------------------------------------------
// Fused add_ln + per-layer prep (one dispatch, block-range split):
//   blocks [0,2048):      residual add + LN -> bf16
//   blocks [2048,6144):   in_proj weights fp32 -> bf16
//   blocks [6144,6336):   xw hi/lo split (96x2048)
//   blocks [6336,6464):   dw hi/lo split (2048x64)
//   blocks [6464,6656):   zero dbl (196608 floats)
// ---------------------------------------------------------------------------
__device__ inline void hl_split4(float4 v, ushort4* h4, ushort4* l4)
{
    ushort4 h, l;
    float f;
    h.x = (unsigned short)bfbits(v.x); f = __uint_as_float((unsigned)h.x << 16); l.x = (unsigned short)bfbits(v.x - f);
    h.y = (unsigned short)bfbits(v.y); f = __uint_as_float((unsigned)h.y << 16); l.y = (unsigned short)bfbits(v.y - f);
    h.z = (unsigned short)bfbits(v.z); f = __uint_as_float((unsigned)h.z << 16); l.z = (unsigned short)bfbits(v.z - f);
    h.w = (unsigned short)bfbits(v.w); f = __uint_as_float((unsigned)h.w << 16); l.w = (unsigned short)bfbits(v.w - f);
    *h4 = h; *l4 = l;
}

__global__ __launch_bounds__(256)
void lnprep_kernel(const float* __restrict__ add, float* __restrict__ residual,
                   const float* __restrict__ w, const float* __restrict__ b,
                   unsigned short* __restrict__ ln_out, int first,
                   const float* __restrict__ iw, unsigned short* __restrict__ wbuf_in,
                   const float* __restrict__ xw, unsigned short* __restrict__ xwh,
                   unsigned short* __restrict__ xwl,
                   const float* __restrict__ dw, unsigned short* __restrict__ dwh,
                   unsigned short* __restrict__ dwl,
                   float* __restrict__ dbl)
{
    __shared__ float red[8];
    int b0 = blockIdx.x;
    int tid = threadIdx.x;
    if (b0 < 2048) {
        add_ln_body(b0, tid, add, residual, w, b, ln_out, first, 1, red);
    } else if (b0 < 6144) {
        int i = (b0 - 2048) * 256 + tid;
        float4 v = *(const float4*)(iw + (size_t)i * 4);
        ushort4 o;
        o.x = (unsigned short)bfbits(v.x);
        o.y = (unsigned short)bfbits(v.y);
        o.z = (unsigned short)bfbits(v.z);
        o.w = (unsigned short)bfbits(v.w);
        *(ushort4*)(wbuf_in + (size_t)i * 4) = o;
    } else if (b0 < 6336) {
        int i = (b0 - 6144) * 256 + tid;
        float4 v = *(const float4*)(xw + (size_t)i * 4);
        hl_split4(v, (ushort4*)(xwh + (size_t)i * 4), (ushort4*)(xwl + (size_t)i * 4));
    } else if (b0 < 6464) {
        int i = (b0 - 6336) * 256 + tid;
        float4 v = *(const float4*)(dw + (size_t)i * 4);
        hl_split4(v, (ushort4*)(dwh + (size_t)i * 4), (ushort4*)(dwl + (size_t)i * 4));
    } else {
        int i = (b0 - 6464) * 256 + tid;
        *(float4*)(dbl + (size_t)i * 4) = make_float4(0.f, 0.f, 0.f, 0.f);
    }
}

// ---------------------------------------------------------------------------
// bf16 MFMA NT GEMM (r10-proven): global_load_lds width-16 staging, linear
// LDS [128][64], XOR-swizzle on global source + ds_read side. 128x128 tile.
// ---------------------------------------------------------------------------
using bf16x8 = __attribute__((ext_vector_type(8))) short;
using f32x4  = __attribute__((ext_vector_type(4))) float;

#define BBM 128
#define BBN 128
#define BBK 64

__global__ __launch_bounds__(256)
void gemm_bf16_nt(const unsigned short* __restrict__ A, const unsigned short* __restrict__ Bw,
                  float* __restrict__ C, int M, int N, int K)
{
    __shared__ unsigned short As[BBM * BBK];
    __shared__ unsigned short Bs[BBN * BBK];

    int tid = threadIdx.x;
    int m0 = blockIdx.y * BBM, n0 = blockIdx.x * BBN;
    int lane = tid & 63, w = tid >> 6;
    int wm = (w >> 1) * 64, wn = (w & 1) * 64;
    int lm = lane & 15, q = lane >> 4;

    int lrow8 = lane >> 3;
    int scol  = ((lane & 7) ^ lrow8) * 8;

    f32x4 acc[4][4] = {};

    for (int k0 = 0; k0 < K; k0 += BBK) {
        #pragma unroll
        for (int j = 0; j < 4; ++j) {
            int rbase = w * 32 + j * 8;
            GLOAD_LDS16(A + (size_t)(m0 + rbase + lrow8) * K + k0 + scol,
                        &As[rbase * BBK]);
        }
        #pragma unroll
        for (int j = 0; j < 4; ++j) {
            int rbase = w * 32 + j * 8;
            GLOAD_LDS16(Bw + (size_t)(n0 + rbase + lrow8) * K + k0 + scol,
                        &Bs[rbase * BBK]);
        }
        __syncthreads();
        #pragma unroll
        for (int kk = 0; kk < BBK; kk += 32) {
            bf16x8 af[4], bf[4];
            #pragma unroll
            for (int i = 0; i < 4; ++i) {
                int row = wm + i * 16 + lm;
                int col = (kk + q * 8) ^ ((row & 7) << 3);
                af[i] = *(const bf16x8*)&As[row * BBK + col];
            }
            #pragma unroll
            for (int j = 0; j < 4; ++j) {
                int row = wn + j * 16 + lm;
                int col = (kk + q * 8) ^ ((row & 7) << 3);
                bf[j] = *(const bf16x8*)&Bs[row * BBK + col];
            }
            #pragma unroll
            for (int i = 0; i < 4; ++i)
                #pragma unroll
                for (int j = 0; j < 4; ++j)
                    acc[i][j] = __builtin_amdgcn_mfma_f32_16x16x32_bf16(
                        af[i], bf[j], acc[i][j], 0, 0, 0);
        }
        __syncthreads();
    }

    #pragma unroll
    for (int i = 0; i < 4; ++i)
        #pragma unroll
        for (int j = 0; j < 4; ++j)
            #pragma unroll
            for (int r = 0; r < 4; ++r) {
                int row = m0 + wm + i * 16 + q * 4 + r;
                int col = n0 + wn + j * 16 + lm;
                C[(size_t)row * N + col] = acc[i][j][r];
            }
}

// ---------------------------------------------------------------------------
// x_proj via hi/lo split-bf16 MFMA, split-K, NO LDS.
// ---------------------------------------------------------------------------
__global__ __launch_bounds__(256)
void xproj_hl(const unsigned short* __restrict__ Ah, const unsigned short* __restrict__ Al,
              const unsigned short* __restrict__ Bh, const unsigned short* __restrict__ Bl,
              float* __restrict__ C)
{
    int tid = threadIdx.x;
    int lane = tid & 63, w = tid >> 6;
    int lm = lane & 15, q = lane >> 4;
    int m0 = blockIdx.x * 32;
    int kb = blockIdx.y * 256;

    int wm = (w & 1) * 16;
    int wn = (w >> 1) * 48;

    size_t arow = (size_t)(m0 + wm + lm) * 2048;

    f32x4 acc[3] = {};

    #pragma unroll 2
    for (int kc = 0; kc < 8; ++kc) {
        int k = kb + kc * 32 + q * 8;
        bf16x8 ah = *(const bf16x8*)&Ah[arow + k];
        bf16x8 al = *(const bf16x8*)&Al[arow + k];
        #pragma unroll
        for (int j = 0; j < 3; ++j) {
            size_t brow = (size_t)(wn + j * 16 + lm) * 2048;
            bf16x8 bh = *(const bf16x8*)&Bh[brow + k];
            bf16x8 bl = *(const bf16x8*)&Bl[brow + k];
            acc[j] = __builtin_amdgcn_mfma_f32_16x16x32_bf16(al, bh, acc[j], 0, 0, 0);
            acc[j] = __builtin_amdgcn_mfma_f32_16x16x32_bf16(ah, bl, acc[j], 0, 0, 0);
            acc[j] = __builtin_amdgcn_mfma_f32_16x16x32_bf16(ah, bh, acc[j], 0, 0, 0);
        }
    }

    #pragma unroll
    for (int j = 0; j < 3; ++j) {
        int col = wn + j * 16 + lm;
        #pragma unroll
        for (int r = 0; r < 4; ++r) {
            int row = m0 + wm + q * 4 + r;
            atomicAdd(&C[(size_t)row * 96 + col], acc[j][r]);
        }
    }
}

// ---------------------------------------------------------------------------
// dt_proj via hi/lo split-bf16 MFMA + fused bias+softplus. NO LDS.
// ---------------------------------------------------------------------------
__global__ __launch_bounds__(256)
void dtproj_hl(const float* __restrict__ dbl,
               const unsigned short* __restrict__ Bh, const unsigned short* __restrict__ Bl,
               const float* __restrict__ bias, float* __restrict__ dtb)
{
    int tid = threadIdx.x;
    int lane = tid & 63, w = tid >> 6;
    int lm = lane & 15, q = lane >> 4;
    int n0 = blockIdx.x * 128;
    int m0 = blockIdx.y * 64;

    const float* arow = dbl + (size_t)(m0 + w * 16 + lm) * 96;

    f32x4 acc[8] = {};

    #pragma unroll
    for (int kc = 0; kc < 2; ++kc) {
        int k = kc * 32 + q * 8;
        float4 v0 = *(const float4*)(arow + k);
        float4 v1 = *(const float4*)(arow + k + 4);
        float vv[8] = {v0.x, v0.y, v0.z, v0.w, v1.x, v1.y, v1.z, v1.w};
        bf16x8 ah, al;
        #pragma unroll
        for (int s = 0; s < 8; ++s) {
            unsigned hb = bfbits(vv[s]);
            ah[s] = (short)hb;
            al[s] = (short)bfbits(vv[s] - __uint_as_float(hb << 16));
        }
        #pragma unroll
        for (int j = 0; j < 8; ++j) {
            size_t brow = (size_t)(n0 + j * 16 + lm) * 64;
            bf16x8 bh = *(const bf16x8*)&Bh[brow + k];
            bf16x8 bl = *(const bf16x8*)&Bl[brow + k];
            acc[j] = __builtin_amdgcn_mfma_f32_16x16x32_bf16(al, bh, acc[j], 0, 0, 0);
            acc[j] = __builtin_amdgcn_mfma_f32_16x16x32_bf16(ah, bl, acc[j], 0, 0, 0);
            acc[j] = __builtin_amdgcn_mfma_f32_16x16x32_bf16(ah, bh, acc[j], 0, 0, 0);
        }
    }

    #pragma unroll
    for (int j = 0; j < 8; ++j) {
        int col = n0 + j * 16 + lm;
        float bv = bias[col];
        #pragma unroll
        for (int r = 0; r < 4; ++r) {
            int row = m0 + w * 16 + q * 4 + r;
            float v = acc[j][r] + bv;
            v = (v > 20.f) ? v : log1pf(__expf(v));
            dtb[(size_t)row * D_INNER + col] = v;
        }
    }
}

// ---------------------------------------------------------------------------
// Depthwise causal conv (width 4) + bias + SiLU; also emits hi/lo bf16 split.
// ---------------------------------------------------------------------------
__global__ __launch_bounds__(256)
void conv_silu_kernel(const float* __restrict__ xz, const float* __restrict__ cw,
                      const float* __restrict__ cb, float* __restrict__ xc,
                      unsigned short* __restrict__ xch, unsigned short* __restrict__ xcl)
{
    int idx = blockIdx.x * 256 + threadIdx.x;
    int d  = idx & (D_INNER - 1);
    int t  = (idx >> 11) & (LSEQ - 1);
    int bb = idx >> 21;

    const float* xcol = xz + (size_t)bb * LSEQ * 2 * D_INNER + d;
    float acc = cb[d];
    #pragma unroll
    for (int k = 0; k < D_CONV; ++k) {
        int tt = t + k - (D_CONV - 1);
        if (tt >= 0) acc += xcol[(size_t)tt * 2 * D_INNER] * cw[d * D_CONV + k];
    }
    acc = acc / (1.f + __expf(-acc));
    xc[idx] = acc;
    unsigned hb = bfbits(acc);
    xch[idx] = (unsigned short)hb;
    float hf = __uint_as_float(hb << 16);
    xcl[idx] = (unsigned short)bfbits(acc - hf);
}

// ---------------------------------------------------------------------------
// Chunked selective scan (r7/r10 structure: 2 lanes/d, 8 states/lane, 4096
// waves, depth-2 pipeline), v3: clamp-free main loop with STEPPED POINTERS
// (kills per-load 64-bit address math) + explicit 2-iteration tail.
// ---------------------------------------------------------------------------
#define UNPK4(dst, off, v) { dst[(off)+0]=(v).x; dst[(off)+1]=(v).y; \
                             dst[(off)+2]=(v).z; dst[(off)+3]=(v).w; }

__global__ __launch_bounds__(256)
void scan_pass1(const float* __restrict__ dtb, const float* __restrict__ xc,
                const float* __restrict__ dbl, const float* __restrict__ Alog,
                float* __restrict__ aPbuf, float* __restrict__ bAbuf)
{
    int tid  = threadIdx.x;
    int half = tid & 1;              // states half*8 .. half*8+7
    int blk  = blockIdx.x;           // grid = NB * NCHUNK * 16 = 1024
    int dg   = blk & 15;
    int c    = (blk >> 4) & (NCHUNK - 1);
    int bb   = blk >> 9;
    int d    = dg * 128 + (tid >> 1);

    float A[8];
    {
        const float* pA = Alog + (size_t)d * D_STATE + half * 8;
        float4 v0 = *(const float4*)pA;
        float4 v1 = *(const float4*)(pA + 4);
        A[0] = -__expf(v0.x); A[1] = -__expf(v0.y);
        A[2] = -__expf(v0.z); A[3] = -__expf(v0.w);
        A[4] = -__expf(v1.x); A[5] = -__expf(v1.y);
        A[6] = -__expf(v1.z); A[7] = -__expf(v1.w);
    }

    size_t rowbase = (size_t)bb * LSEQ + (size_t)c * TCH;
    const float* pdt = dtb + rowbase * D_INNER + d;
    const float* pxc = xc  + rowbase * D_INNER + d;
    const float* pbc = dbl + rowbase * 96 + DT_RANK + half * 8;

    float aP[8] = {1.f,1.f,1.f,1.f,1.f,1.f,1.f,1.f};
    float bA[8] = {0.f,0.f,0.f,0.f,0.f,0.f,0.f,0.f};

    // current sets: steps 0 (E), 1 (O)
    float  dtE = pdt[0], xvE = pxc[0];
    float4 BE0 = *(const float4*)pbc;
    float4 BE1 = *(const float4*)(pbc + 4);
    float  dtO = pdt[D_INNER], xvO = pxc[D_INNER];
    float4 BO0 = *(const float4*)(pbc + 96);
    float4 BO1 = *(const float4*)(pbc + 96 + 4);

    // stepped prefetch pointers (point at t+2 / t+3)
    const float* qdtE = pdt + 2 * D_INNER;
    const float* qdtO = pdt + 3 * D_INNER;
    const float* qxcE = pxc + 2 * D_INNER;
    const float* qxcO = pxc + 3 * D_INNER;
    const float* qbcE = pbc + 2 * 96;
    const float* qbcO = pbc + 3 * 96;

#define P1_STEP(DT, XV, B0, B1) { \
        float B[8]; UNPK4(B, 0, B0) UNPK4(B, 4, B1) \
        float dtx = (DT) * (XV); \
        _Pragma("unroll") \
        for (int s = 0; s < 8; ++s) { \
            float a = __expf((DT) * A[s]); \
            aP[s] *= a; \
            bA[s] = bA[s] * a + dtx * B[s]; \
        } }

    for (int t = 0; t < TCH - 4; t += 2) {
        float  dtEn = qdtE[0], xvEn = qxcE[0];
        float4 BE0n = *(const float4*)qbcE;
        float4 BE1n = *(const float4*)(qbcE + 4);
        float  dtOn = qdtO[0], xvOn = qxcO[0];
        float4 BO0n = *(const float4*)qbcO;
        float4 BO1n = *(const float4*)(qbcO + 4);
        qdtE += 2 * D_INNER; qdtO += 2 * D_INNER;
        qxcE += 2 * D_INNER; qxcO += 2 * D_INNER;
        qbcE += 192; qbcO += 192;

        P1_STEP(dtE, xvE, BE0, BE1)
        P1_STEP(dtO, xvO, BO0, BO1)

        dtE = dtEn; xvE = xvEn; BE0 = BE0n; BE1 = BE1n;
        dtO = dtOn; xvO = xvOn; BO0 = BO0n; BO1 = BO1n;
    }
    {   // tail iter A: prefetch last two steps, process TCH-4, TCH-3
        float  dtEn = qdtE[0], xvEn = qxcE[0];
        float4 BE0n = *(const float4*)qbcE;
        float4 BE1n = *(const float4*)(qbcE + 4);
        float  dtOn = qdtO[0], xvOn = qxcO[0];
        float4 BO0n = *(const float4*)qbcO;
        float4 BO1n = *(const float4*)(qbcO + 4);

        P1_STEP(dtE, xvE, BE0, BE1)
        P1_STEP(dtO, xvO, BO0, BO1)

        dtE = dtEn; xvE = xvEn; BE0 = BE0n; BE1 = BE1n;
        dtO = dtOn; xvO = xvOn; BO0 = BO0n; BO1 = BO1n;
    }
    {   // tail iter B: process TCH-2, TCH-1
        P1_STEP(dtE, xvE, BE0, BE1)
        P1_STEP(dtO, xvO, BO0, BO1)
    }
#undef P1_STEP

    float* pa = aPbuf + ((size_t)(bb * NCHUNK + c) * D_INNER + d) * D_STATE + half * 8;
    float* pb = bAbuf + ((size_t)(bb * NCHUNK + c) * D_INNER + d) * D_STATE + half * 8;
    *(float4*)(pa + 0) = make_float4(aP[0], aP[1], aP[2], aP[3]);
    *(float4*)(pa + 4) = make_float4(aP[4], aP[5], aP[6], aP[7]);
    *(float4*)(pb + 0) = make_float4(bA[0], bA[1], bA[2], bA[3]);
    *(float4*)(pb + 4) = make_float4(bA[4], bA[5], bA[6], bA[7]);
}

__global__ __launch_bounds__(256)
void scan_pass2(const float* __restrict__ dtb, const float* __restrict__ xc,
                const float* __restrict__ dbl, const float* __restrict__ xz,
                const float* __restrict__ Alog, const float* __restrict__ Dp,
                const float* __restrict__ aPbuf, const float* __restrict__ bAbuf,
                unsigned short* __restrict__ y)
{
    int tid  = threadIdx.x;
    int half = tid & 1;
    int blk  = blockIdx.x;
    int dg   = blk & 15;
    int c    = (blk >> 4) & (NCHUNK - 1);
    int bb   = blk >> 9;
    int d    = dg * 128 + (tid >> 1);

    float A[8];
    {
        const float* pA = Alog + (size_t)d * D_STATE + half * 8;
        float4 v0 = *(const float4*)pA;
        float4 v1 = *(const float4*)(pA + 4);
        A[0] = -__expf(v0.x); A[1] = -__expf(v0.y);
        A[2] = -__expf(v0.z); A[3] = -__expf(v0.w);
        A[4] = -__expf(v1.x); A[5] = -__expf(v1.y);
        A[6] = -__expf(v1.z); A[7] = -__expf(v1.w);
    }
    float Dd = Dp[d];

    float h[8] = {0.f,0.f,0.f,0.f,0.f,0.f,0.f,0.f};

    // prefix compose over chunks [0, c)
    for (int cc = 0; cc < c; ++cc) {
        const float* pa = aPbuf + ((size_t)(bb * NCHUNK + cc) * D_INNER + d) * D_STATE + half * 8;
        const float* pb = bAbuf + ((size_t)(bb * NCHUNK + cc) * D_INNER + d) * D_STATE + half * 8;
        float4 a0 = *(const float4*)(pa + 0), a1 = *(const float4*)(pa + 4);
        float4 b0 = *(const float4*)(pb + 0), b1 = *(const float4*)(pb + 4);
        float av[8], bv[8];
        UNPK4(av, 0, a0) UNPK4(av, 4, a1)
        UNPK4(bv, 0, b0) UNPK4(bv, 4, b1)
        #pragma unroll
        for (int s = 0; s < 8; ++s) h[s] = h[s] * av[s] + bv[s];
    }

    size_t rowbase = (size_t)bb * LSEQ + (size_t)c * TCH;
    const float* pdt = dtb + rowbase * D_INNER + d;
    const float* pxc = xc  + rowbase * D_INNER + d;
    const float* pz  = xz  + rowbase * 2 * D_INNER + D_INNER + d;
    const float* pbc = dbl + rowbase * 96 + DT_RANK + half * 8;
    unsigned short* qyE = y + rowbase * D_INNER + d;
    unsigned short* qyO = qyE + D_INNER;

    // current sets: steps 0 (E), 1 (O)
    float  dtE = pdt[0], xvE = pxc[0], zvE = pz[0];
    float4 BE0 = *(const float4*)pbc;
    float4 BE1 = *(const float4*)(pbc + 4);
    float4 CE0 = *(const float4*)(pbc + 16);
    float4 CE1 = *(const float4*)(pbc + 20);
    float  dtO = pdt[D_INNER], xvO = pxc[D_INNER], zvO = pz[2 * D_INNER];
    float4 BO0 = *(const float4*)(pbc + 96);
    float4 BO1 = *(const float4*)(pbc + 96 + 4);
    float4 CO0 = *(const float4*)(pbc + 96 + 16);
    float4 CO1 = *(const float4*)(pbc + 96 + 20);

    // stepped prefetch pointers (point at t+2 / t+3)
    const float* qdtE = pdt + 2 * D_INNER;
    const float* qdtO = pdt + 3 * D_INNER;
    const float* qxcE = pxc + 2 * D_INNER;
    const float* qxcO = pxc + 3 * D_INNER;
    const float* qzE  = pz  + 4 * D_INNER;          // step stride 2*D_INNER
    const float* qzO  = pz  + 6 * D_INNER;
    const float* qbcE = pbc + 2 * 96;
    const float* qbcO = pbc + 3 * 96;

#define P2_STEP(DT, XV, ZV, B0, B1, C0, C1, PY) { \
        float B[8], C[8]; \
        UNPK4(B, 0, B0) UNPK4(B, 4, B1) \
        UNPK4(C, 0, C0) UNPK4(C, 4, C1) \
        float dtx = (DT) * (XV); \
        float p = 0.f; \
        _Pragma("unroll") \
        for (int s = 0; s < 8; ++s) { \
            float a = __expf((DT) * A[s]); \
            h[s] = h[s] * a + dtx * B[s]; \
            p += h[s] * C[s]; \
        } \
        p += __shfl_xor(p, 1, 2); \
        if (half == 0) { \
            float sz = (ZV) / (1.f + __expf(-(ZV))); \
            *(PY) = (unsigned short)bfbits((p + (XV) * Dd) * sz); \
        } }

    for (int t = 0; t < TCH - 4; t += 2) {
        float  dtEn = qdtE[0], xvEn = qxcE[0], zvEn = qzE[0];
        float4 BE0n = *(const float4*)qbcE;
        float4 BE1n = *(const float4*)(qbcE + 4);
        float4 CE0n = *(const float4*)(qbcE + 16);
        float4 CE1n = *(const float4*)(qbcE + 20);
        float  dtOn = qdtO[0], xvOn = qxcO[0], zvOn = qzO[0];
        float4 BO0n = *(const float4*)qbcO;
        float4 BO1n = *(const float4*)(qbcO + 4);
        float4 CO0n = *(const float4*)(qbcO + 16);
        float4 CO1n = *(const float4*)(qbcO + 20);
        qdtE += 2 * D_INNER; qdtO += 2 * D_INNER;
        qxcE += 2 * D_INNER; qxcO += 2 * D_INNER;
        qzE  += 4 * D_INNER; qzO  += 4 * D_INNER;
        qbcE += 192; qbcO += 192;

        P2_STEP(dtE, xvE, zvE, BE0, BE1, CE0, CE1, qyE)
        qyE += 2 * D_INNER;
        P2_STEP(dtO, xvO, zvO, BO0, BO1, CO0, CO1, qyO)
        qyO += 2 * D_INNER;

        dtE = dtEn; xvE = xvEn; zvE = zvEn;
        BE0 = BE0n; BE1 = BE1n; CE0 = CE0n; CE1 = CE1n;
        dtO = dtOn; xvO = xvOn; zvO = zvOn;
        BO0 = BO0n; BO1 = BO1n; CO0 = CO0n; CO1 = CO1n;
    }
    {   // tail iter A: prefetch last two steps, process TCH-4, TCH-3
        float  dtEn = qdtE[0], xvEn = qxcE[0], zvEn = qzE[0];
        float4 BE0n = *(const float4*)qbcE;
        float4 BE1n = *(const float4*)(qbcE + 4);
        float4 CE0n = *(const float4*)(qbcE + 16);
        float4 CE1n = *(const float4*)(qbcE + 20);
        float  dtOn = qdtO[0], xvOn = qxcO[0], zvOn = qzO[0];
        float4 BO0n = *(const float4*)qbcO;
        float4 BO1n = *(const float4*)(qbcO + 4);
        float4 CO0n = *(const float4*)(qbcO + 16);
        float4 CO1n = *(const float4*)(qbcO + 20);

        P2_STEP(dtE, xvE, zvE, BE0, BE1, CE0, CE1, qyE)
        qyE += 2 * D_INNER;
        P2_STEP(dtO, xvO, zvO, BO0, BO1, CO0, CO1, qyO)
        qyO += 2 * D_INNER;

        dtE = dtEn; xvE = xvEn; zvE = zvEn;
        BE0 = BE0n; BE1 = BE1n; CE0 = CE0n; CE1 = CE1n;
        dtO = dtOn; xvO = xvOn; zvO = zvOn;
        BO0 = BO0n; BO1 = BO1n; CO0 = CO0n; CO1 = CO1n;
    }
    {   // tail iter B: process TCH-2, TCH-1
        P2_STEP(dtE, xvE, zvE, BE0, BE1, CE0, CE1, qyE)
        P2_STEP(dtO, xvO, zvO, BO0, BO1, CO0, CO1, qyO)
    }
#undef P2_STEP
}

// ---------------------------------------------------------------------------
extern "C" void kernel_launch(void* const* d_in, const int* in_sizes, int n_in,
                              void* d_out, int out_size, void* d_ws, size_t ws_size,
                              hipStream_t stream)
{
    const float* h_in  = (const float*)d_in[0];
    const float* iw    = (const float*)d_in[1];   // (4, 4096, 1024)
    const float* cw    = (const float*)d_in[2];   // (4, 2048, 4)
    const float* cb    = (const float*)d_in[3];   // (4, 2048)
    const float* xw    = (const float*)d_in[4];   // (4, 96, 2048)
    const float* dw    = (const float*)d_in[5];   // (4, 2048, 64)
    const float* db    = (const float*)d_in[6];   // (4, 2048)
    const float* Alog  = (const float*)d_in[7];   // (4, 2048, 16)
    const float* Dp    = (const float*)d_in[8];   // (4, 2048)
    const float* ow    = (const float*)d_in[9];   // (4, 1024, 2048)
    const float* nw    = (const float*)d_in[10];  // (4, 1024)
    const float* nb    = (const float*)d_in[11];  // (4, 1024)
    const float* nfw   = (const float*)d_in[12];  // (1024,)
    const float* nfb   = (const float*)d_in[13];  // (1024,)

    // workspace layout — identical total (25,362,432 floats)
    float* ws = (float*)d_ws;
    float* residual = ws;                       // 2,097,152
    float* hs       = residual + 2097152;       // 2,097,152
    float* xz       = hs + 2097152;             // 8,388,608  [r][4096]
    float* xc       = xz + 8388608;             // 4,194,304  [r][2048]
    float* dtb      = xc + 4194304;             // 4,194,304  [r][2048]
    float* dbl      = dtb + 4194304;            // 196,608    [r][96]
    float* y        = dbl + 196608;             // 4,194,304

    // aPbuf aliases hs (dead add_ln-consume .. scan); bAbuf = y[2M..4M).
    float* aPbuf = hs;
    float* bAbuf = y + 2097152;

    // bf16 / hi-lo staging, all in dead regions (timeline-disjoint):
    unsigned short* wbuf_in  = (unsigned short*)y;
    unsigned short* hs_bf16  = (unsigned short*)(y + 2097152);
    unsigned short* y_bf16   = (unsigned short*)y;
    unsigned short* xc_hi    = (unsigned short*)y;
    unsigned short* xc_lo    = (unsigned short*)(y + 2097152);
    unsigned short* xwp_hi   = (unsigned short*)hs;
    unsigned short* xwp_lo   = (unsigned short*)(hs + 98304);
    unsigned short* dwp_hi   = (unsigned short*)(hs + 196608);
    unsigned short* dwp_lo   = (unsigned short*)(hs + 262144);
    unsigned short* wbuf_out = (unsigned short*)dtb;

    const float* cur_add = h_in;
    for (int i = 0; i < N_LAYER; ++i) {
        // fused: residual add + LN (bf16) | in_proj w->bf16 | xw/dw hi-lo | zero dbl
        lnprep_kernel<<<6656, 256, 0, stream>>>(
            cur_add, residual, nw + i * D_MODEL, nb + i * D_MODEL, hs_bf16, i == 0,
            iw + (size_t)i * 2 * D_INNER * D_MODEL, wbuf_in,
            xw + (size_t)i * 96 * D_INNER, xwp_hi, xwp_lo,
            dw + (size_t)i * D_INNER * DT_RANK, dwp_hi, dwp_lo,
            dbl);
        // in_proj (bf16 MFMA, global_load_lds staging): -> xz [r][4096] fp32
        gemm_bf16_nt<<<dim3(2 * D_INNER / BBN, NROWS / BBM), 256, 0, stream>>>(
            hs_bf16, wbuf_in, xz, NROWS, 2 * D_INNER, D_MODEL);
        // conv + silu -> xc fp32 + hi/lo bf16 split (for MFMA x_proj)
        conv_silu_kernel<<<NB * LSEQ * D_INNER / 256, 256, 0, stream>>>(
            xz, cw + (size_t)i * D_INNER * D_CONV, cb + i * D_INNER, xc, xc_hi, xc_lo);
        // x_proj (hi/lo split-bf16 MFMA, split-K z=8): -> dbl [r][96]
        xproj_hl<<<dim3(NROWS / 32, 8), 256, 0, stream>>>(
            xc_hi, xc_lo, xwp_hi, xwp_lo, dbl);
        // dt_proj (reads dbl directly, in-reg hi/lo split + bias + softplus)
        dtproj_hl<<<dim3(D_INNER / 128, NROWS / 64), 256, 0, stream>>>(
            dbl, dwp_hi, dwp_lo, db + i * D_INNER, dtb);
        // chunked selective scan — 2 lanes/d, 4096 waves, stepped-pointer pipeline
        scan_pass1<<<NB * NCHUNK * (D_INNER / 128), 256, 0, stream>>>(
            dtb, xc, dbl, Alog + (size_t)i * D_INNER * D_STATE, aPbuf, bAbuf);
        scan_pass2<<<NB * NCHUNK * (D_INNER / 128), 256, 0, stream>>>(
            dtb, xc, dbl, xz, Alog + (size_t)i * D_INNER * D_STATE, Dp + i * D_INNER,
            aPbuf, bAbuf, y_bf16);
        // convert out_proj weights -> bf16 (dead dtb space; must follow scan)
        f32_to_bf16_kernel<<<(D_MODEL * D_INNER) / 1024, 256, 0, stream>>>(
            ow + (size_t)i * D_MODEL * D_INNER, wbuf_out);
        // out_proj (bf16 MFMA, global_load_lds staging): -> hs [r][1024] fp32
        gemm_bf16_nt<<<dim3(D_MODEL / BBN, NROWS / BBM), 256, 0, stream>>>(
            y_bf16, wbuf_out, hs, NROWS, D_MODEL, D_INNER);
        cur_add = hs;
    }
    add_ln_kernel<<<NROWS, 256, 0, stream>>>(hs, residual, nfw, nfb, d_out, 0, 0);
}

// Round 13
// 942.194 us; speedup vs baseline: 1.0863x; 1.0203x over previous
//
#include <hip/hip_runtime.h>
#include <math.h>

#define D_MODEL 1024
#define D_INNER 2048
#define D_STATE 16
#define D_CONV  4
#define DT_RANK 64
#define NB      2
#define LSEQ    1024
#define NROWS   (NB * LSEQ)   // 2048
#define LN_EPS  1e-5f
#define N_LAYER 4
#define NCHUNK  32
#define TCH     (LSEQ / NCHUNK)   // 32 steps per chunk

__device__ inline unsigned bfbits(float f) {
    unsigned u = __float_as_uint(f);
    return (u + 0x7fffu + ((u >> 16) & 1u)) >> 16;  // RNE
}

// async global->LDS, 16B per lane. LDS dest = wave-uniform base + lane*16.
#define GLOAD_LDS16(gp, lp) \
    __builtin_amdgcn_global_load_lds( \
        (const __attribute__((address_space(1))) void*)(gp), \
        (__attribute__((address_space(3))) void*)(lp), 16, 0, 0)

// ---------------------------------------------------------------------------
// Fused residual-add + LayerNorm body (shared by fused and standalone kernels)
// ---------------------------------------------------------------------------
__device__ inline float wave_sum(float s) {
    #pragma unroll
    for (int m = 1; m < 64; m <<= 1) s += __shfl_xor(s, m, 64);
    return s;
}

__device__ inline void add_ln_body(int row, int tid,
                                   const float* __restrict__ add,
                                   float* __restrict__ residual,
                                   const float* __restrict__ w, const float* __restrict__ b,
                                   void* __restrict__ out, int first, int bf16out,
                                   float* red)
{
    size_t base = (size_t)row * D_MODEL + tid * 4;

    float4 v = *(const float4*)(add + base);
    if (!first) {
        float4 r = *(const float4*)(residual + base);
        v.x += r.x; v.y += r.y; v.z += r.z; v.w += r.w;
    }
    *(float4*)(residual + base) = v;

    float s = v.x + v.y + v.z + v.w;
    s = wave_sum(s);
    if ((tid & 63) == 0) red[tid >> 6] = s;
    __syncthreads();
    float mu = (red[0] + red[1] + red[2] + red[3]) * (1.0f / D_MODEL);

    float dx = v.x - mu, dy = v.y - mu, dz = v.z - mu, dw2 = v.w - mu;
    float s2 = dx*dx + dy*dy + dz*dz + dw2*dw2;
    s2 = wave_sum(s2);
    if ((tid & 63) == 0) red[4 + (tid >> 6)] = s2;
    __syncthreads();
    float var = (red[4] + red[5] + red[6] + red[7]) * (1.0f / D_MODEL);
    float rs = rsqrtf(var + LN_EPS);

    float4 wv = *(const float4*)(w + tid * 4);
    float4 bv = *(const float4*)(b + tid * 4);
    float4 o;
    o.x = dx  * rs * wv.x + bv.x;
    o.y = dy  * rs * wv.y + bv.y;
    o.z = dz  * rs * wv.z + bv.z;
    o.w = dw2 * rs * wv.w + bv.w;
    if (bf16out) {
        ushort4 ov;
        ov.x = (unsigned short)bfbits(o.x);
        ov.y = (unsigned short)bfbits(o.y);
        ov.z = (unsigned short)bfbits(o.z);
        ov.w = (unsigned short)bfbits(o.w);
        *(ushort4*)((unsigned short*)out + base) = ov;
    } else {
        *(float4*)((float*)out + base) = o;
    }
}

__global__ __launch_bounds__(256)
void add_ln_kernel(const float* __restrict__ add, float* __restrict__ residual,
                   const float* __restrict__ w, const float* __restrict__ b,
                   void* __restrict__ out, int first, int bf16out)
{
    __shared__ float red[8];
    add_ln_body(blockIdx.x, threadIdx.x, add, residual, w, b, out, first, bf16out, red);
}

// ---------------------------------------------------------------------------
// fp32 -> bf16 bulk convert (out_proj weights; runs after scan frees dtb).
// ---------------------------------------------------------------------------
__global__ __launch_bounds__(256)
void f32_to_bf16_kernel(const float* __restrict__ src, unsigned short* __restrict__ dst)
{
    int i = blockIdx.x * 256 + threadIdx.x;
    float4 v = *(const float4*)(src + (size_t)i * 4);
    ushort4 o;
    o.x = (unsigned short)bfbits(v.x);
    o.y = (unsigned short)bfbits(v.y);
    o.z = (unsigned short)bfbits(v.z);
    o.w = (unsigned short)bfbits(v.w);
    *(ushort4*)(dst + (size_t)i * 4) = o;
}

// ---------------------------------------------------------------------------
// Fused add_ln + per-layer prep (one dispatch, block-range split):
//   blocks [0,2048):      residual add + LN -> bf16
//   blocks [2048,6144):   in_proj weights fp32 -> bf16
//   blocks [6144,6336):   xw hi/lo split (96x2048)
//   blocks [6336,6464):   dw hi/lo split (2048x64)
//   blocks [6464,6656):   zero dbl (196608 floats)
// ---------------------------------------------------------------------------
__device__ inline void hl_split4(float4 v, ushort4* h4, ushort4* l4)
{
    ushort4 h, l;
    float f;
    h.x = (unsigned short)bfbits(v.x); f = __uint_as_float((unsigned)h.x << 16); l.x = (unsigned short)bfbits(v.x - f);
    h.y = (unsigned short)bfbits(v.y); f = __uint_as_float((unsigned)h.y << 16); l.y = (unsigned short)bfbits(v.y - f);
    h.z = (unsigned short)bfbits(v.z); f = __uint_as_float((unsigned)h.z << 16); l.z = (unsigned short)bfbits(v.z - f);
    h.w = (unsigned short)bfbits(v.w); f = __uint_as_float((unsigned)h.w << 16); l.w = (unsigned short)bfbits(v.w - f);
    *h4 = h; *l4 = l;
}

__global__ __launch_bounds__(256)
void lnprep_kernel(const float* __restrict__ add, float* __restrict__ residual,
                   const float* __restrict__ w, const float* __restrict__ b,
                   unsigned short* __restrict__ ln_out, int first,
                   const float* __restrict__ iw, unsigned short* __restrict__ wbuf_in,
                   const float* __restrict__ xw, unsigned short* __restrict__ xwh,
                   unsigned short* __restrict__ xwl,
                   const float* __restrict__ dw, unsigned short* __restrict__ dwh,
                   unsigned short* __restrict__ dwl,
                   float* __restrict__ dbl)
{
    __shared__ float red[8];
    int b0 = blockIdx.x;
    int tid = threadIdx.x;
    if (b0 < 2048) {
        add_ln_body(b0, tid, add, residual, w, b, ln_out, first, 1, red);
    } else if (b0 < 6144) {
        int i = (b0 - 2048) * 256 + tid;
        float4 v = *(const float4*)(iw + (size_t)i * 4);
        ushort4 o;
        o.x = (unsigned short)bfbits(v.x);
        o.y = (unsigned short)bfbits(v.y);
        o.z = (unsigned short)bfbits(v.z);
        o.w = (unsigned short)bfbits(v.w);
        *(ushort4*)(wbuf_in + (size_t)i * 4) = o;
    } else if (b0 < 6336) {
        int i = (b0 - 6144) * 256 + tid;
        float4 v = *(const float4*)(xw + (size_t)i * 4);
        hl_split4(v, (ushort4*)(xwh + (size_t)i * 4), (ushort4*)(xwl + (size_t)i * 4));
    } else if (b0 < 6464) {
        int i = (b0 - 6336) * 256 + tid;
        float4 v = *(const float4*)(dw + (size_t)i * 4);
        hl_split4(v, (ushort4*)(dwh + (size_t)i * 4), (ushort4*)(dwl + (size_t)i * 4));
    } else {
        int i = (b0 - 6464) * 256 + tid;
        *(float4*)(dbl + (size_t)i * 4) = make_float4(0.f, 0.f, 0.f, 0.f);
    }
}

// ---------------------------------------------------------------------------
// bf16 MFMA NT GEMM (r10-proven): global_load_lds width-16 staging, linear
// LDS [128][64], XOR-swizzle on global source + ds_read side. 128x128 tile.
// ---------------------------------------------------------------------------
using bf16x8 = __attribute__((ext_vector_type(8))) short;
using f32x4  = __attribute__((ext_vector_type(4))) float;

#define BBM 128
#define BBN 128
#define BBK 64

__global__ __launch_bounds__(256)
void gemm_bf16_nt(const unsigned short* __restrict__ A, const unsigned short* __restrict__ Bw,
                  float* __restrict__ C, int M, int N, int K)
{
    __shared__ unsigned short As[BBM * BBK];
    __shared__ unsigned short Bs[BBN * BBK];

    int tid = threadIdx.x;
    int m0 = blockIdx.y * BBM, n0 = blockIdx.x * BBN;
    int lane = tid & 63, w = tid >> 6;
    int wm = (w >> 1) * 64, wn = (w & 1) * 64;
    int lm = lane & 15, q = lane >> 4;

    int lrow8 = lane >> 3;
    int scol  = ((lane & 7) ^ lrow8) * 8;

    f32x4 acc[4][4] = {};

    for (int k0 = 0; k0 < K; k0 += BBK) {
        #pragma unroll
        for (int j = 0; j < 4; ++j) {
            int rbase = w * 32 + j * 8;
            GLOAD_LDS16(A + (size_t)(m0 + rbase + lrow8) * K + k0 + scol,
                        &As[rbase * BBK]);
        }
        #pragma unroll
        for (int j = 0; j < 4; ++j) {
            int rbase = w * 32 + j * 8;
            GLOAD_LDS16(Bw + (size_t)(n0 + rbase + lrow8) * K + k0 + scol,
                        &Bs[rbase * BBK]);
        }
        __syncthreads();
        #pragma unroll
        for (int kk = 0; kk < BBK; kk += 32) {
            bf16x8 af[4], bf[4];
            #pragma unroll
            for (int i = 0; i < 4; ++i) {
                int row = wm + i * 16 + lm;
                int col = (kk + q * 8) ^ ((row & 7) << 3);
                af[i] = *(const bf16x8*)&As[row * BBK + col];
            }
            #pragma unroll
            for (int j = 0; j < 4; ++j) {
                int row = wn + j * 16 + lm;
                int col = (kk + q * 8) ^ ((row & 7) << 3);
                bf[j] = *(const bf16x8*)&Bs[row * BBK + col];
            }
            #pragma unroll
            for (int i = 0; i < 4; ++i)
                #pragma unroll
                for (int j = 0; j < 4; ++j)
                    acc[i][j] = __builtin_amdgcn_mfma_f32_16x16x32_bf16(
                        af[i], bf[j], acc[i][j], 0, 0, 0);
        }
        __syncthreads();
    }

    #pragma unroll
    for (int i = 0; i < 4; ++i)
        #pragma unroll
        for (int j = 0; j < 4; ++j)
            #pragma unroll
            for (int r = 0; r < 4; ++r) {
                int row = m0 + wm + i * 16 + q * 4 + r;
                int col = n0 + wn + j * 16 + lm;
                C[(size_t)row * N + col] = acc[i][j][r];
            }
}

// ---------------------------------------------------------------------------
// x_proj via hi/lo split-bf16 MFMA, split-K, NO LDS.
// ---------------------------------------------------------------------------
__global__ __launch_bounds__(256)
void xproj_hl(const unsigned short* __restrict__ Ah, const unsigned short* __restrict__ Al,
              const unsigned short* __restrict__ Bh, const unsigned short* __restrict__ Bl,
              float* __restrict__ C)
{
    int tid = threadIdx.x;
    int lane = tid & 63, w = tid >> 6;
    int lm = lane & 15, q = lane >> 4;
    int m0 = blockIdx.x * 32;
    int kb = blockIdx.y * 256;

    int wm = (w & 1) * 16;
    int wn = (w >> 1) * 48;

    size_t arow = (size_t)(m0 + wm + lm) * 2048;

    f32x4 acc[3] = {};

    #pragma unroll 2
    for (int kc = 0; kc < 8; ++kc) {
        int k = kb + kc * 32 + q * 8;
        bf16x8 ah = *(const bf16x8*)&Ah[arow + k];
        bf16x8 al = *(const bf16x8*)&Al[arow + k];
        #pragma unroll
        for (int j = 0; j < 3; ++j) {
            size_t brow = (size_t)(wn + j * 16 + lm) * 2048;
            bf16x8 bh = *(const bf16x8*)&Bh[brow + k];
            bf16x8 bl = *(const bf16x8*)&Bl[brow + k];
            acc[j] = __builtin_amdgcn_mfma_f32_16x16x32_bf16(al, bh, acc[j], 0, 0, 0);
            acc[j] = __builtin_amdgcn_mfma_f32_16x16x32_bf16(ah, bl, acc[j], 0, 0, 0);
            acc[j] = __builtin_amdgcn_mfma_f32_16x16x32_bf16(ah, bh, acc[j], 0, 0, 0);
        }
    }

    #pragma unroll
    for (int j = 0; j < 3; ++j) {
        int col = wn + j * 16 + lm;
        #pragma unroll
        for (int r = 0; r < 4; ++r) {
            int row = m0 + wm + q * 4 + r;
            atomicAdd(&C[(size_t)row * 96 + col], acc[j][r]);
        }
    }
}

// ---------------------------------------------------------------------------
// dt_proj via hi/lo split-bf16 MFMA + fused bias+softplus. NO LDS.
// ---------------------------------------------------------------------------
__global__ __launch_bounds__(256)
void dtproj_hl(const float* __restrict__ dbl,
               const unsigned short* __restrict__ Bh, const unsigned short* __restrict__ Bl,
               const float* __restrict__ bias, float* __restrict__ dtb)
{
    int tid = threadIdx.x;
    int lane = tid & 63, w = tid >> 6;
    int lm = lane & 15, q = lane >> 4;
    int n0 = blockIdx.x * 128;
    int m0 = blockIdx.y * 64;

    const float* arow = dbl + (size_t)(m0 + w * 16 + lm) * 96;

    f32x4 acc[8] = {};

    #pragma unroll
    for (int kc = 0; kc < 2; ++kc) {
        int k = kc * 32 + q * 8;
        float4 v0 = *(const float4*)(arow + k);
        float4 v1 = *(const float4*)(arow + k + 4);
        float vv[8] = {v0.x, v0.y, v0.z, v0.w, v1.x, v1.y, v1.z, v1.w};
        bf16x8 ah, al;
        #pragma unroll
        for (int s = 0; s < 8; ++s) {
            unsigned hb = bfbits(vv[s]);
            ah[s] = (short)hb;
            al[s] = (short)bfbits(vv[s] - __uint_as_float(hb << 16));
        }
        #pragma unroll
        for (int j = 0; j < 8; ++j) {
            size_t brow = (size_t)(n0 + j * 16 + lm) * 64;
            bf16x8 bh = *(const bf16x8*)&Bh[brow + k];
            bf16x8 bl = *(const bf16x8*)&Bl[brow + k];
            acc[j] = __builtin_amdgcn_mfma_f32_16x16x32_bf16(al, bh, acc[j], 0, 0, 0);
            acc[j] = __builtin_amdgcn_mfma_f32_16x16x32_bf16(ah, bl, acc[j], 0, 0, 0);
            acc[j] = __builtin_amdgcn_mfma_f32_16x16x32_bf16(ah, bh, acc[j], 0, 0, 0);
        }
    }

    #pragma unroll
    for (int j = 0; j < 8; ++j) {
        int col = n0 + j * 16 + lm;
        float bv = bias[col];
        #pragma unroll
        for (int r = 0; r < 4; ++r) {
            int row = m0 + w * 16 + q * 4 + r;
            float v = acc[j][r] + bv;
            v = (v > 20.f) ? v : log1pf(__expf(v));
            dtb[(size_t)row * D_INNER + col] = v;
        }
    }
}

// ---------------------------------------------------------------------------
// Depthwise causal conv (width 4) + bias + SiLU; also emits hi/lo bf16 split.
// ---------------------------------------------------------------------------
__global__ __launch_bounds__(256)
void conv_silu_kernel(const float* __restrict__ xz, const float* __restrict__ cw,
                      const float* __restrict__ cb, float* __restrict__ xc,
                      unsigned short* __restrict__ xch, unsigned short* __restrict__ xcl)
{
    int idx = blockIdx.x * 256 + threadIdx.x;
    int d  = idx & (D_INNER - 1);
    int t  = (idx >> 11) & (LSEQ - 1);
    int bb = idx >> 21;

    const float* xcol = xz + (size_t)bb * LSEQ * 2 * D_INNER + d;
    float acc = cb[d];
    #pragma unroll
    for (int k = 0; k < D_CONV; ++k) {
        int tt = t + k - (D_CONV - 1);
        if (tt >= 0) acc += xcol[(size_t)tt * 2 * D_INNER] * cw[d * D_CONV + k];
    }
    acc = acc / (1.f + __expf(-acc));
    xc[idx] = acc;
    unsigned hb = bfbits(acc);
    xch[idx] = (unsigned short)hb;
    float hf = __uint_as_float(hb << 16);
    xcl[idx] = (unsigned short)bfbits(acc - hf);
}

// ---------------------------------------------------------------------------
// Chunked selective scan, 3-phase Blelloch:
//   pass1:      per-chunk transfer ops (aP, bA) — unchanged r12 kernel.
//   scan_prefix: exclusive prefix over chunks, IN-PLACE in bAbuf (bAbuf[c]
//                becomes h0 entering chunk c). Bit-identical compose order.
//   pass2:      loads h0 directly (no O(c) compose — removes tail imbalance).
// ---------------------------------------------------------------------------
#define UNPK4(dst, off, v) { dst[(off)+0]=(v).x; dst[(off)+1]=(v).y; \
                             dst[(off)+2]=(v).z; dst[(off)+3]=(v).w; }

__global__ __launch_bounds__(256)
void scan_pass1(const float* __restrict__ dtb, const float* __restrict__ xc,
                const float* __restrict__ dbl, const float* __restrict__ Alog,
                float* __restrict__ aPbuf, float* __restrict__ bAbuf)
{
    int tid  = threadIdx.x;
    int half = tid & 1;              // states half*8 .. half*8+7
    int blk  = blockIdx.x;           // grid = NB * NCHUNK * 16 = 1024
    int dg   = blk & 15;
    int c    = (blk >> 4) & (NCHUNK - 1);
    int bb   = blk >> 9;
    int d    = dg * 128 + (tid >> 1);

    float A[8];
    {
        const float* pA = Alog + (size_t)d * D_STATE + half * 8;
        float4 v0 = *(const float4*)pA;
        float4 v1 = *(const float4*)(pA + 4);
        A[0] = -__expf(v0.x); A[1] = -__expf(v0.y);
        A[2] = -__expf(v0.z); A[3] = -__expf(v0.w);
        A[4] = -__expf(v1.x); A[5] = -__expf(v1.y);
        A[6] = -__expf(v1.z); A[7] = -__expf(v1.w);
    }

    size_t rowbase = (size_t)bb * LSEQ + (size_t)c * TCH;
    const float* pdt = dtb + rowbase * D_INNER + d;
    const float* pxc = xc  + rowbase * D_INNER + d;
    const float* pbc = dbl + rowbase * 96 + DT_RANK + half * 8;

    float aP[8] = {1.f,1.f,1.f,1.f,1.f,1.f,1.f,1.f};
    float bA[8] = {0.f,0.f,0.f,0.f,0.f,0.f,0.f,0.f};

    // current sets: steps 0 (E), 1 (O)
    float  dtE = pdt[0], xvE = pxc[0];
    float4 BE0 = *(const float4*)pbc;
    float4 BE1 = *(const float4*)(pbc + 4);
    float  dtO = pdt[D_INNER], xvO = pxc[D_INNER];
    float4 BO0 = *(const float4*)(pbc + 96);
    float4 BO1 = *(const float4*)(pbc + 96 + 4);

    // stepped prefetch pointers (point at t+2 / t+3)
    const float* qdtE = pdt + 2 * D_INNER;
    const float* qdtO = pdt + 3 * D_INNER;
    const float* qxcE = pxc + 2 * D_INNER;
    const float* qxcO = pxc + 3 * D_INNER;
    const float* qbcE = pbc + 2 * 96;
    const float* qbcO = pbc + 3 * 96;

#define P1_STEP(DT, XV, B0, B1) { \
        float B[8]; UNPK4(B, 0, B0) UNPK4(B, 4, B1) \
        float dtx = (DT) * (XV); \
        _Pragma("unroll") \
        for (int s = 0; s < 8; ++s) { \
            float a = __expf((DT) * A[s]); \
            aP[s] *= a; \
            bA[s] = bA[s] * a + dtx * B[s]; \
        } }

    for (int t = 0; t < TCH - 4; t += 2) {
        float  dtEn = qdtE[0], xvEn = qxcE[0];
        float4 BE0n = *(const float4*)qbcE;
        float4 BE1n = *(const float4*)(qbcE + 4);
        float  dtOn = qdtO[0], xvOn = qxcO[0];
        float4 BO0n = *(const float4*)qbcO;
        float4 BO1n = *(const float4*)(qbcO + 4);
        qdtE += 2 * D_INNER; qdtO += 2 * D_INNER;
        qxcE += 2 * D_INNER; qxcO += 2 * D_INNER;
        qbcE += 192; qbcO += 192;

        P1_STEP(dtE, xvE, BE0, BE1)
        P1_STEP(dtO, xvO, BO0, BO1)

        dtE = dtEn; xvE = xvEn; BE0 = BE0n; BE1 = BE1n;
        dtO = dtOn; xvO = xvOn; BO0 = BO0n; BO1 = BO1n;
    }
    {   // tail iter A: prefetch last two steps, process TCH-4, TCH-3
        float  dtEn = qdtE[0], xvEn = qxcE[0];
        float4 BE0n = *(const float4*)qbcE;
        float4 BE1n = *(const float4*)(qbcE + 4);
        float  dtOn = qdtO[0], xvOn = qxcO[0];
        float4 BO0n = *(const float4*)qbcO;
        float4 BO1n = *(const float4*)(qbcO + 4);

        P1_STEP(dtE, xvE, BE0, BE1)
        P1_STEP(dtO, xvO, BO0, BO1)

        dtE = dtEn; xvE = xvEn; BE0 = BE0n; BE1 = BE1n;
        dtO = dtOn; xvO = xvOn; BO0 = BO0n; BO1 = BO1n;
    }
    {   // tail iter B: process TCH-2, TCH-1
        P1_STEP(dtE, xvE, BE0, BE1)
        P1_STEP(dtO, xvO, BO0, BO1)
    }
#undef P1_STEP

    float* pa = aPbuf + ((size_t)(bb * NCHUNK + c) * D_INNER + d) * D_STATE + half * 8;
    float* pb = bAbuf + ((size_t)(bb * NCHUNK + c) * D_INNER + d) * D_STATE + half * 8;
    *(float4*)(pa + 0) = make_float4(aP[0], aP[1], aP[2], aP[3]);
    *(float4*)(pa + 4) = make_float4(aP[4], aP[5], aP[6], aP[7]);
    *(float4*)(pb + 0) = make_float4(bA[0], bA[1], bA[2], bA[3]);
    *(float4*)(pb + 4) = make_float4(bA[4], bA[5], bA[6], bA[7]);
}

// Exclusive prefix over chunks, in-place: bAbuf[c] <- h0 entering chunk c.
// 32768 threads (128 blocks); thread owns (bb, d, state-pair sp).
__global__ __launch_bounds__(256)
void scan_prefix(const float* __restrict__ aPbuf, float* __restrict__ bAbuf)
{
    int idx = blockIdx.x * 256 + threadIdx.x;
    int sp = idx & 7;
    int d  = (idx >> 3) & (D_INNER - 1);
    int bb = idx >> 14;

    size_t o = ((size_t)(bb * NCHUNK) * D_INNER + d) * D_STATE + sp * 2;
    const size_t stride = (size_t)D_INNER * D_STATE;
    float h0 = 0.f, h1 = 0.f;
    #pragma unroll 4
    for (int c = 0; c < NCHUNK; ++c) {
        float2 a2 = *(const float2*)(aPbuf + o);
        float2 b2 = *(const float2*)(bAbuf + o);
        *(float2*)(bAbuf + o) = make_float2(h0, h1);
        h0 = h0 * a2.x + b2.x;
        h1 = h1 * a2.y + b2.y;
        o += stride;
    }
}

__global__ __launch_bounds__(256)
void scan_pass2(const float* __restrict__ dtb, const float* __restrict__ xc,
                const float* __restrict__ dbl, const float* __restrict__ xz,
                const float* __restrict__ Alog, const float* __restrict__ Dp,
                const float* __restrict__ bAbuf,
                unsigned short* __restrict__ y)
{
    int tid  = threadIdx.x;
    int half = tid & 1;
    int blk  = blockIdx.x;
    int dg   = blk & 15;
    int c    = (blk >> 4) & (NCHUNK - 1);
    int bb   = blk >> 9;
    int d    = dg * 128 + (tid >> 1);

    float A[8];
    {
        const float* pA = Alog + (size_t)d * D_STATE + half * 8;
        float4 v0 = *(const float4*)pA;
        float4 v1 = *(const float4*)(pA + 4);
        A[0] = -__expf(v0.x); A[1] = -__expf(v0.y);
        A[2] = -__expf(v0.z); A[3] = -__expf(v0.w);
        A[4] = -__expf(v1.x); A[5] = -__expf(v1.y);
        A[6] = -__expf(v1.z); A[7] = -__expf(v1.w);
    }
    float Dd = Dp[d];

    // initial state: exclusive-prefix h0 for this chunk (from scan_prefix)
    float h[8];
    {
        const float* ph = bAbuf + ((size_t)(bb * NCHUNK + c) * D_INNER + d) * D_STATE + half * 8;
        float4 h0v = *(const float4*)(ph + 0);
        float4 h1v = *(const float4*)(ph + 4);
        UNPK4(h, 0, h0v) UNPK4(h, 4, h1v)
    }

    size_t rowbase = (size_t)bb * LSEQ + (size_t)c * TCH;
    const float* pdt = dtb + rowbase * D_INNER + d;
    const float* pxc = xc  + rowbase * D_INNER + d;
    const float* pz  = xz  + rowbase * 2 * D_INNER + D_INNER + d;
    const float* pbc = dbl + rowbase * 96 + DT_RANK + half * 8;
    unsigned short* qyE = y + rowbase * D_INNER + d;
    unsigned short* qyO = qyE + D_INNER;

    // current sets: steps 0 (E), 1 (O)
    float  dtE = pdt[0], xvE = pxc[0], zvE = pz[0];
    float4 BE0 = *(const float4*)pbc;
    float4 BE1 = *(const float4*)(pbc + 4);
    float4 CE0 = *(const float4*)(pbc + 16);
    float4 CE1 = *(const float4*)(pbc + 20);
    float  dtO = pdt[D_INNER], xvO = pxc[D_INNER], zvO = pz[2 * D_INNER];
    float4 BO0 = *(const float4*)(pbc + 96);
    float4 BO1 = *(const float4*)(pbc + 96 + 4);
    float4 CO0 = *(const float4*)(pbc + 96 + 16);
    float4 CO1 = *(const float4*)(pbc + 96 + 20);

    // stepped prefetch pointers (point at t+2 / t+3)
    const float* qdtE = pdt + 2 * D_INNER;
    const float* qdtO = pdt + 3 * D_INNER;
    const float* qxcE = pxc + 2 * D_INNER;
    const float* qxcO = pxc + 3 * D_INNER;
    const float* qzE  = pz  + 4 * D_INNER;          // step stride 2*D_INNER
    const float* qzO  = pz  + 6 * D_INNER;
    const float* qbcE = pbc + 2 * 96;
    const float* qbcO = pbc + 3 * 96;

#define P2_STEP(DT, XV, ZV, B0, B1, C0, C1, PY) { \
        float B[8], C[8]; \
        UNPK4(B, 0, B0) UNPK4(B, 4, B1) \
        UNPK4(C, 0, C0) UNPK4(C, 4, C1) \
        float dtx = (DT) * (XV); \
        float p = 0.f; \
        _Pragma("unroll") \
        for (int s = 0; s < 8; ++s) { \
            float a = __expf((DT) * A[s]); \
            h[s] = h[s] * a + dtx * B[s]; \
            p += h[s] * C[s]; \
        } \
        p += __shfl_xor(p, 1, 2); \
        if (half == 0) { \
            float sz = (ZV) / (1.f + __expf(-(ZV))); \
            *(PY) = (unsigned short)bfbits((p + (XV) * Dd) * sz); \
        } }

    for (int t = 0; t < TCH - 4; t += 2) {
        float  dtEn = qdtE[0], xvEn = qxcE[0], zvEn = qzE[0];
        float4 BE0n = *(const float4*)qbcE;
        float4 BE1n = *(const float4*)(qbcE + 4);
        float4 CE0n = *(const float4*)(qbcE + 16);
        float4 CE1n = *(const float4*)(qbcE + 20);
        float  dtOn = qdtO[0], xvOn = qxcO[0], zvOn = qzO[0];
        float4 BO0n = *(const float4*)qbcO;
        float4 BO1n = *(const float4*)(qbcO + 4);
        float4 CO0n = *(const float4*)(qbcO + 16);
        float4 CO1n = *(const float4*)(qbcO + 20);
        qdtE += 2 * D_INNER; qdtO += 2 * D_INNER;
        qxcE += 2 * D_INNER; qxcO += 2 * D_INNER;
        qzE  += 4 * D_INNER; qzO  += 4 * D_INNER;
        qbcE += 192; qbcO += 192;

        P2_STEP(dtE, xvE, zvE, BE0, BE1, CE0, CE1, qyE)
        qyE += 2 * D_INNER;
        P2_STEP(dtO, xvO, zvO, BO0, BO1, CO0, CO1, qyO)
        qyO += 2 * D_INNER;

        dtE = dtEn; xvE = xvEn; zvE = zvEn;
        BE0 = BE0n; BE1 = BE1n; CE0 = CE0n; CE1 = CE1n;
        dtO = dtOn; xvO = xvOn; zvO = zvOn;
        BO0 = BO0n; BO1 = BO1n; CO0 = CO0n; CO1 = CO1n;
    }
    {   // tail iter A: prefetch last two steps, process TCH-4, TCH-3
        float  dtEn = qdtE[0], xvEn = qxcE[0], zvEn = qzE[0];
        float4 BE0n = *(const float4*)qbcE;
        float4 BE1n = *(const float4*)(qbcE + 4);
        float4 CE0n = *(const float4*)(qbcE + 16);
        float4 CE1n = *(const float4*)(qbcE + 20);
        float  dtOn = qdtO[0], xvOn = qxcO[0], zvOn = qzO[0];
        float4 BO0n = *(const float4*)qbcO;
        float4 BO1n = *(const float4*)(qbcO + 4);
        float4 CO0n = *(const float4*)(qbcO + 16);
        float4 CO1n = *(const float4*)(qbcO + 20);

        P2_STEP(dtE, xvE, zvE, BE0, BE1, CE0, CE1, qyE)
        qyE += 2 * D_INNER;
        P2_STEP(dtO, xvO, zvO, BO0, BO1, CO0, CO1, qyO)
        qyO += 2 * D_INNER;

        dtE = dtEn; xvE = xvEn; zvE = zvEn;
        BE0 = BE0n; BE1 = BE1n; CE0 = CE0n; CE1 = CE1n;
        dtO = dtOn; xvO = xvOn; zvO = zvOn;
        BO0 = BO0n; BO1 = BO1n; CO0 = CO0n; CO1 = CO1n;
    }
    {   // tail iter B: process TCH-2, TCH-1
        P2_STEP(dtE, xvE, zvE, BE0, BE1, CE0, CE1, qyE)
        P2_STEP(dtO, xvO, zvO, BO0, BO1, CO0, CO1, qyO)
    }
#undef P2_STEP
}

// ---------------------------------------------------------------------------
extern "C" void kernel_launch(void* const* d_in, const int* in_sizes, int n_in,
                              void* d_out, int out_size, void* d_ws, size_t ws_size,
                              hipStream_t stream)
{
    const float* h_in  = (const float*)d_in[0];
    const float* iw    = (const float*)d_in[1];   // (4, 4096, 1024)
    const float* cw    = (const float*)d_in[2];   // (4, 2048, 4)
    const float* cb    = (const float*)d_in[3];   // (4, 2048)
    const float* xw    = (const float*)d_in[4];   // (4, 96, 2048)
    const float* dw    = (const float*)d_in[5];   // (4, 2048, 64)
    const float* db    = (const float*)d_in[6];   // (4, 2048)
    const float* Alog  = (const float*)d_in[7];   // (4, 2048, 16)
    const float* Dp    = (const float*)d_in[8];   // (4, 2048)
    const float* ow    = (const float*)d_in[9];   // (4, 1024, 2048)
    const float* nw    = (const float*)d_in[10];  // (4, 1024)
    const float* nb    = (const float*)d_in[11];  // (4, 1024)
    const float* nfw   = (const float*)d_in[12];  // (1024,)
    const float* nfb   = (const float*)d_in[13];  // (1024,)

    // workspace layout — identical total (25,362,432 floats)
    float* ws = (float*)d_ws;
    float* residual = ws;                       // 2,097,152
    float* hs       = residual + 2097152;       // 2,097,152
    float* xz       = hs + 2097152;             // 8,388,608  [r][4096]
    float* xc       = xz + 8388608;             // 4,194,304  [r][2048]
    float* dtb      = xc + 4194304;             // 4,194,304  [r][2048]
    float* dbl      = dtb + 4194304;            // 196,608    [r][96]
    float* y        = dbl + 196608;             // 4,194,304

    // aPbuf aliases hs (dead add_ln-consume .. scan); bAbuf = y[2M..4M).
    float* aPbuf = hs;
    float* bAbuf = y + 2097152;

    // bf16 / hi-lo staging, all in dead regions (timeline-disjoint):
    unsigned short* wbuf_in  = (unsigned short*)y;
    unsigned short* hs_bf16  = (unsigned short*)(y + 2097152);
    unsigned short* y_bf16   = (unsigned short*)y;
    unsigned short* xc_hi    = (unsigned short*)y;
    unsigned short* xc_lo    = (unsigned short*)(y + 2097152);
    unsigned short* xwp_hi   = (unsigned short*)hs;
    unsigned short* xwp_lo   = (unsigned short*)(hs + 98304);
    unsigned short* dwp_hi   = (unsigned short*)(hs + 196608);
    unsigned short* dwp_lo   = (unsigned short*)(hs + 262144);
    unsigned short* wbuf_out = (unsigned short*)dtb;

    const float* cur_add = h_in;
    for (int i = 0; i < N_LAYER; ++i) {
        // fused: residual add + LN (bf16) | in_proj w->bf16 | xw/dw hi-lo | zero dbl
        lnprep_kernel<<<6656, 256, 0, stream>>>(
            cur_add, residual, nw + i * D_MODEL, nb + i * D_MODEL, hs_bf16, i == 0,
            iw + (size_t)i * 2 * D_INNER * D_MODEL, wbuf_in,
            xw + (size_t)i * 96 * D_INNER, xwp_hi, xwp_lo,
            dw + (size_t)i * D_INNER * DT_RANK, dwp_hi, dwp_lo,
            dbl);
        // in_proj (bf16 MFMA, global_load_lds staging): -> xz [r][4096] fp32
        gemm_bf16_nt<<<dim3(2 * D_INNER / BBN, NROWS / BBM), 256, 0, stream>>>(
            hs_bf16, wbuf_in, xz, NROWS, 2 * D_INNER, D_MODEL);
        // conv + silu -> xc fp32 + hi/lo bf16 split (for MFMA x_proj)
        conv_silu_kernel<<<NB * LSEQ * D_INNER / 256, 256, 0, stream>>>(
            xz, cw + (size_t)i * D_INNER * D_CONV, cb + i * D_INNER, xc, xc_hi, xc_lo);
        // x_proj (hi/lo split-bf16 MFMA, split-K z=8): -> dbl [r][96]
        xproj_hl<<<dim3(NROWS / 32, 8), 256, 0, stream>>>(
            xc_hi, xc_lo, xwp_hi, xwp_lo, dbl);
        // dt_proj (reads dbl directly, in-reg hi/lo split + bias + softplus)
        dtproj_hl<<<dim3(D_INNER / 128, NROWS / 64), 256, 0, stream>>>(
            dbl, dwp_hi, dwp_lo, db + i * D_INNER, dtb);
        // chunked selective scan — 3-phase Blelloch
        scan_pass1<<<NB * NCHUNK * (D_INNER / 128), 256, 0, stream>>>(
            dtb, xc, dbl, Alog + (size_t)i * D_INNER * D_STATE, aPbuf, bAbuf);
        scan_prefix<<<(NB * D_INNER * 8) / 256, 256, 0, stream>>>(aPbuf, bAbuf);
        scan_pass2<<<NB * NCHUNK * (D_INNER / 128), 256, 0, stream>>>(
            dtb, xc, dbl, xz, Alog + (size_t)i * D_INNER * D_STATE, Dp + i * D_INNER,
            bAbuf, y_bf16);
        // convert out_proj weights -> bf16 (dead dtb space; must follow scan)
        f32_to_bf16_kernel<<<(D_MODEL * D_INNER) / 1024, 256, 0, stream>>>(
            ow + (size_t)i * D_MODEL * D_INNER, wbuf_out);
        // out_proj (bf16 MFMA, global_load_lds staging): -> hs [r][1024] fp32
        gemm_bf16_nt<<<dim3(D_MODEL / BBN, NROWS / BBM), 256, 0, stream>>>(
            y_bf16, wbuf_out, hs, NROWS, D_MODEL, D_INNER);
        cur_add = hs;
    }
    add_ln_kernel<<<NROWS, 256, 0, stream>>>(hs, residual, nfw, nfb, d_out, 0, 0);
}

// Round 14
// 899.560 us; speedup vs baseline: 1.1377x; 1.0474x over previous
//
#include <hip/hip_runtime.h>
#include <math.h>

#define D_MODEL 1024
#define D_INNER 2048
#define D_STATE 16
#define D_CONV  4
#define DT_RANK 64
#define NB      2
#define LSEQ    1024
#define NROWS   (NB * LSEQ)   // 2048
#define LN_EPS  1e-5f
#define N_LAYER 4
#define NCHUNK  32
#define TCH     (LSEQ / NCHUNK)   // 32 steps per chunk

__device__ inline unsigned bfbits(float f) {
    unsigned u = __float_as_uint(f);
    return (u + 0x7fffu + ((u >> 16) & 1u)) >> 16;  // RNE
}

// async global->LDS, 16B per lane. LDS dest = wave-uniform base + lane*16.
#define GLOAD_LDS16(gp, lp) \
    __builtin_amdgcn_global_load_lds( \
        (const __attribute__((address_space(1))) void*)(gp), \
        (__attribute__((address_space(3))) void*)(lp), 16, 0, 0)

// ---------------------------------------------------------------------------
// Fused residual-add + LayerNorm body (shared by fused and standalone kernels)
// ---------------------------------------------------------------------------
__device__ inline float wave_sum(float s) {
    #pragma unroll
    for (int m = 1; m < 64; m <<= 1) s += __shfl_xor(s, m, 64);
    return s;
}

__device__ inline void add_ln_body(int row, int tid,
                                   const float* __restrict__ add,
                                   float* __restrict__ residual,
                                   const float* __restrict__ w, const float* __restrict__ b,
                                   void* __restrict__ out, int first, int bf16out,
                                   float* red)
{
    size_t base = (size_t)row * D_MODEL + tid * 4;

    float4 v = *(const float4*)(add + base);
    if (!first) {
        float4 r = *(const float4*)(residual + base);
        v.x += r.x; v.y += r.y; v.z += r.z; v.w += r.w;
    }
    *(float4*)(residual + base) = v;

    float s = v.x + v.y + v.z + v.w;
    s = wave_sum(s);
    if ((tid & 63) == 0) red[tid >> 6] = s;
    __syncthreads();
    float mu = (red[0] + red[1] + red[2] + red[3]) * (1.0f / D_MODEL);

    float dx = v.x - mu, dy = v.y - mu, dz = v.z - mu, dw2 = v.w - mu;
    float s2 = dx*dx + dy*dy + dz*dz + dw2*dw2;
    s2 = wave_sum(s2);
    if ((tid & 63) == 0) red[4 + (tid >> 6)] = s2;
    __syncthreads();
    float var = (red[4] + red[5] + red[6] + red[7]) * (1.0f / D_MODEL);
    float rs = rsqrtf(var + LN_EPS);

    float4 wv = *(const float4*)(w + tid * 4);
    float4 bv = *(const float4*)(b + tid * 4);
    float4 o;
    o.x = dx  * rs * wv.x + bv.x;
    o.y = dy  * rs * wv.y + bv.y;
    o.z = dz  * rs * wv.z + bv.z;
    o.w = dw2 * rs * wv.w + bv.w;
    if (bf16out) {
        ushort4 ov;
        ov.x = (unsigned short)bfbits(o.x);
        ov.y = (unsigned short)bfbits(o.y);
        ov.z = (unsigned short)bfbits(o.z);
        ov.w = (unsigned short)bfbits(o.w);
        *(ushort4*)((unsigned short*)out + base) = ov;
    } else {
        *(float4*)((float*)out + base) = o;
    }
}

__global__ __launch_bounds__(256)
void add_ln_kernel(const float* __restrict__ add, float* __restrict__ residual,
                   const float* __restrict__ w, const float* __restrict__ b,
                   void* __restrict__ out, int first, int bf16out)
{
    __shared__ float red[8];
    add_ln_body(blockIdx.x, threadIdx.x, add, residual, w, b, out, first, bf16out, red);
}

// ---------------------------------------------------------------------------
// fp32 -> bf16 bulk convert (out_proj weights; runs after scan frees dtb).
// ---------------------------------------------------------------------------
__global__ __launch_bounds__(256)
void f32_to_bf16_kernel(const float* __restrict__ src, unsigned short* __restrict__ dst)
{
    int i = blockIdx.x * 256 + threadIdx.x;
    float4 v = *(const float4*)(src + (size_t)i * 4);
    ushort4 o;
    o.x = (unsigned short)bfbits(v.x);
    o.y = (unsigned short)bfbits(v.y);
    o.z = (unsigned short)bfbits(v.z);
    o.w = (unsigned short)bfbits(v.w);
    *(ushort4*)(dst + (size_t)i * 4) = o;
}

// ---------------------------------------------------------------------------
// Fused add_ln + per-layer prep (one dispatch, block-range split):
//   blocks [0,2048):      residual add + LN -> bf16
//   blocks [2048,6144):   in_proj weights fp32 -> bf16
//   blocks [6144,6336):   xw hi/lo split (96x2048)
//   blocks [6336,6464):   dw hi/lo split (2048x64)
//   blocks [6464,6656):   zero dbl (196608 floats)
// ---------------------------------------------------------------------------
__device__ inline void hl_split4(float4 v, ushort4* h4, ushort4* l4)
{
    ushort4 h, l;
    float f;
    h.x = (unsigned short)bfbits(v.x); f = __uint_as_float((unsigned)h.x << 16); l.x = (unsigned short)bfbits(v.x - f);
    h.y = (unsigned short)bfbits(v.y); f = __uint_as_float((unsigned)h.y << 16); l.y = (unsigned short)bfbits(v.y - f);
    h.z = (unsigned short)bfbits(v.z); f = __uint_as_float((unsigned)h.z << 16); l.z = (unsigned short)bfbits(v.z - f);
    h.w = (unsigned short)bfbits(v.w); f = __uint_as_float((unsigned)h.w << 16); l.w = (unsigned short)bfbits(v.w - f);
    *h4 = h; *l4 = l;
}

__global__ __launch_bounds__(256)
void lnprep_kernel(const float* __restrict__ add, float* __restrict__ residual,
                   const float* __restrict__ w, const float* __restrict__ b,
                   unsigned short* __restrict__ ln_out, int first,
                   const float* __restrict__ iw, unsigned short* __restrict__ wbuf_in,
                   const float* __restrict__ xw, unsigned short* __restrict__ xwh,
                   unsigned short* __restrict__ xwl,
                   const float* __restrict__ dw, unsigned short* __restrict__ dwh,
                   unsigned short* __restrict__ dwl,
                   float* __restrict__ dbl)
{
    __shared__ float red[8];
    int b0 = blockIdx.x;
    int tid = threadIdx.x;
    if (b0 < 2048) {
        add_ln_body(b0, tid, add, residual, w, b, ln_out, first, 1, red);
    } else if (b0 < 6144) {
        int i = (b0 - 2048) * 256 + tid;
        float4 v = *(const float4*)(iw + (size_t)i * 4);
        ushort4 o;
        o.x = (unsigned short)bfbits(v.x);
        o.y = (unsigned short)bfbits(v.y);
        o.z = (unsigned short)bfbits(v.z);
        o.w = (unsigned short)bfbits(v.w);
        *(ushort4*)(wbuf_in + (size_t)i * 4) = o;
    } else if (b0 < 6336) {
        int i = (b0 - 6144) * 256 + tid;
        float4 v = *(const float4*)(xw + (size_t)i * 4);
        hl_split4(v, (ushort4*)(xwh + (size_t)i * 4), (ushort4*)(xwl + (size_t)i * 4));
    } else if (b0 < 6464) {
        int i = (b0 - 6336) * 256 + tid;
        float4 v = *(const float4*)(dw + (size_t)i * 4);
        hl_split4(v, (ushort4*)(dwh + (size_t)i * 4), (ushort4*)(dwl + (size_t)i * 4));
    } else {
        int i = (b0 - 6464) * 256 + tid;
        *(float4*)(dbl + (size_t)i * 4) = make_float4(0.f, 0.f, 0.f, 0.f);
    }
}

// ---------------------------------------------------------------------------
// bf16 MFMA NT GEMM, v3: DOUBLE-BUFFERED global_load_lds pipeline.
// Stage tile k+1 is issued BEFORE computing tile k; the single
// __syncthreads() per K-step then drains loads that have been in flight
// for a whole compute phase (latency hidden even at 2 blocks/CU).
// Templated tile <BM,BN> for occupancy: in_proj 128x64 (grid 1024),
// out_proj 64x64 (grid 512). Linear LDS + XOR swizzle (r10-proven).
// ---------------------------------------------------------------------------
using bf16x8 = __attribute__((ext_vector_type(8))) short;
using f32x4  = __attribute__((ext_vector_type(4))) float;

template<int BM, int BN>
__global__ __launch_bounds__(256)
void gemm_bf16_dbuf(const unsigned short* __restrict__ A, const unsigned short* __restrict__ Bw,
                    float* __restrict__ C, int M, int N, int K)
{
    constexpr int MF = BM / 32;   // A frags per wave (m-dim), also A stage calls
    constexpr int NF = BN / 32;   // B frags per wave (n-dim), also B stage calls
    __shared__ unsigned short As[2][BM * 64];
    __shared__ unsigned short Bs[2][BN * 64];

    int tid = threadIdx.x;
    int m0 = blockIdx.y * BM, n0 = blockIdx.x * BN;
    int lane = tid & 63, w = tid >> 6;
    int wm = (w >> 1) * (BM / 2), wn = (w & 1) * (BN / 2);
    int lm = lane & 15, q = lane >> 4;

    int lrow8 = lane >> 3;
    int scol  = ((lane & 7) ^ lrow8) * 8;

    f32x4 acc[MF][NF] = {};

    auto STAGE = [&](int buf, int k0) {
        #pragma unroll
        for (int j = 0; j < MF; ++j) {
            int rb = w * (BM / 4) + j * 8;
            GLOAD_LDS16(A + (size_t)(m0 + rb + lrow8) * K + k0 + scol,
                        &As[buf][rb * 64]);
        }
        #pragma unroll
        for (int j = 0; j < NF; ++j) {
            int rb = w * (BN / 4) + j * 8;
            GLOAD_LDS16(Bw + (size_t)(n0 + rb + lrow8) * K + k0 + scol,
                        &Bs[buf][rb * 64]);
        }
    };

    STAGE(0, 0);
    __syncthreads();   // drains vmcnt -> buf0 ready

    int nk = K >> 6;
    for (int kt = 0; kt < nk; ++kt) {
        int cur = kt & 1;
        if (kt + 1 < nk) STAGE(cur ^ 1, (kt + 1) << 6);   // overlap with compute
        #pragma unroll
        for (int kk = 0; kk < 64; kk += 32) {
            bf16x8 af[MF], bf[NF];
            #pragma unroll
            for (int i = 0; i < MF; ++i) {
                int row = wm + i * 16 + lm;
                int col = (kk + q * 8) ^ ((row & 7) << 3);
                af[i] = *(const bf16x8*)&As[cur][row * 64 + col];
            }
            #pragma unroll
            for (int j = 0; j < NF; ++j) {
                int row = wn + j * 16 + lm;
                int col = (kk + q * 8) ^ ((row & 7) << 3);
                bf[j] = *(const bf16x8*)&Bs[cur][row * 64 + col];
            }
            #pragma unroll
            for (int i = 0; i < MF; ++i)
                #pragma unroll
                for (int j = 0; j < NF; ++j)
                    acc[i][j] = __builtin_amdgcn_mfma_f32_16x16x32_bf16(
                        af[i], bf[j], acc[i][j], 0, 0, 0);
        }
        __syncthreads();   // drains next-stage loads + fences buffer reuse
    }

    #pragma unroll
    for (int i = 0; i < MF; ++i)
        #pragma unroll
        for (int j = 0; j < NF; ++j)
            #pragma unroll
            for (int r = 0; r < 4; ++r) {
                int row = m0 + wm + i * 16 + q * 4 + r;
                int col = n0 + wn + j * 16 + lm;
                C[(size_t)row * N + col] = acc[i][j][r];
            }
}

// ---------------------------------------------------------------------------
// x_proj via hi/lo split-bf16 MFMA, split-K, NO LDS.
// ---------------------------------------------------------------------------
__global__ __launch_bounds__(256)
void xproj_hl(const unsigned short* __restrict__ Ah, const unsigned short* __restrict__ Al,
              const unsigned short* __restrict__ Bh, const unsigned short* __restrict__ Bl,
              float* __restrict__ C)
{
    int tid = threadIdx.x;
    int lane = tid & 63, w = tid >> 6;
    int lm = lane & 15, q = lane >> 4;
    int m0 = blockIdx.x * 32;
    int kb = blockIdx.y * 256;

    int wm = (w & 1) * 16;
    int wn = (w >> 1) * 48;

    size_t arow = (size_t)(m0 + wm + lm) * 2048;

    f32x4 acc[3] = {};

    #pragma unroll 2
    for (int kc = 0; kc < 8; ++kc) {
        int k = kb + kc * 32 + q * 8;
        bf16x8 ah = *(const bf16x8*)&Ah[arow + k];
        bf16x8 al = *(const bf16x8*)&Al[arow + k];
        #pragma unroll
        for (int j = 0; j < 3; ++j) {
            size_t brow = (size_t)(wn + j * 16 + lm) * 2048;
            bf16x8 bh = *(const bf16x8*)&Bh[brow + k];
            bf16x8 bl = *(const bf16x8*)&Bl[brow + k];
            acc[j] = __builtin_amdgcn_mfma_f32_16x16x32_bf16(al, bh, acc[j], 0, 0, 0);
            acc[j] = __builtin_amdgcn_mfma_f32_16x16x32_bf16(ah, bl, acc[j], 0, 0, 0);
            acc[j] = __builtin_amdgcn_mfma_f32_16x16x32_bf16(ah, bh, acc[j], 0, 0, 0);
        }
    }

    #pragma unroll
    for (int j = 0; j < 3; ++j) {
        int col = wn + j * 16 + lm;
        #pragma unroll
        for (int r = 0; r < 4; ++r) {
            int row = m0 + wm + q * 4 + r;
            atomicAdd(&C[(size_t)row * 96 + col], acc[j][r]);
        }
    }
}

// ---------------------------------------------------------------------------
// dt_proj via hi/lo split-bf16 MFMA + fused bias+softplus. NO LDS.
// ---------------------------------------------------------------------------
__global__ __launch_bounds__(256)
void dtproj_hl(const float* __restrict__ dbl,
               const unsigned short* __restrict__ Bh, const unsigned short* __restrict__ Bl,
               const float* __restrict__ bias, float* __restrict__ dtb)
{
    int tid = threadIdx.x;
    int lane = tid & 63, w = tid >> 6;
    int lm = lane & 15, q = lane >> 4;
    int n0 = blockIdx.x * 128;
    int m0 = blockIdx.y * 64;

    const float* arow = dbl + (size_t)(m0 + w * 16 + lm) * 96;

    f32x4 acc[8] = {};

    #pragma unroll
    for (int kc = 0; kc < 2; ++kc) {
        int k = kc * 32 + q * 8;
        float4 v0 = *(const float4*)(arow + k);
        float4 v1 = *(const float4*)(arow + k + 4);
        float vv[8] = {v0.x, v0.y, v0.z, v0.w, v1.x, v1.y, v1.z, v1.w};
        bf16x8 ah, al;
        #pragma unroll
        for (int s = 0; s < 8; ++s) {
            unsigned hb = bfbits(vv[s]);
            ah[s] = (short)hb;
            al[s] = (short)bfbits(vv[s] - __uint_as_float(hb << 16));
        }
        #pragma unroll
        for (int j = 0; j < 8; ++j) {
            size_t brow = (size_t)(n0 + j * 16 + lm) * 64;
            bf16x8 bh = *(const bf16x8*)&Bh[brow + k];
            bf16x8 bl = *(const bf16x8*)&Bl[brow + k];
            acc[j] = __builtin_amdgcn_mfma_f32_16x16x32_bf16(al, bh, acc[j], 0, 0, 0);
            acc[j] = __builtin_amdgcn_mfma_f32_16x16x32_bf16(ah, bl, acc[j], 0, 0, 0);
            acc[j] = __builtin_amdgcn_mfma_f32_16x16x32_bf16(ah, bh, acc[j], 0, 0, 0);
        }
    }

    #pragma unroll
    for (int j = 0; j < 8; ++j) {
        int col = n0 + j * 16 + lm;
        float bv = bias[col];
        #pragma unroll
        for (int r = 0; r < 4; ++r) {
            int row = m0 + w * 16 + q * 4 + r;
            float v = acc[j][r] + bv;
            v = (v > 20.f) ? v : log1pf(__expf(v));
            dtb[(size_t)row * D_INNER + col] = v;
        }
    }
}

// ---------------------------------------------------------------------------
// Depthwise causal conv (width 4) + bias + SiLU; also emits hi/lo bf16 split.
// ---------------------------------------------------------------------------
__global__ __launch_bounds__(256)
void conv_silu_kernel(const float* __restrict__ xz, const float* __restrict__ cw,
                      const float* __restrict__ cb, float* __restrict__ xc,
                      unsigned short* __restrict__ xch, unsigned short* __restrict__ xcl)
{
    int idx = blockIdx.x * 256 + threadIdx.x;
    int d  = idx & (D_INNER - 1);
    int t  = (idx >> 11) & (LSEQ - 1);
    int bb = idx >> 21;

    const float* xcol = xz + (size_t)bb * LSEQ * 2 * D_INNER + d;
    float acc = cb[d];
    #pragma unroll
    for (int k = 0; k < D_CONV; ++k) {
        int tt = t + k - (D_CONV - 1);
        if (tt >= 0) acc += xcol[(size_t)tt * 2 * D_INNER] * cw[d * D_CONV + k];
    }
    acc = acc / (1.f + __expf(-acc));
    xc[idx] = acc;
    unsigned hb = bfbits(acc);
    xch[idx] = (unsigned short)hb;
    float hf = __uint_as_float(hb << 16);
    xcl[idx] = (unsigned short)bfbits(acc - hf);
}

// ---------------------------------------------------------------------------
// Chunked selective scan, 3-phase Blelloch (r13-proven).
// ---------------------------------------------------------------------------
#define UNPK4(dst, off, v) { dst[(off)+0]=(v).x; dst[(off)+1]=(v).y; \
                             dst[(off)+2]=(v).z; dst[(off)+3]=(v).w; }

__global__ __launch_bounds__(256)
void scan_pass1(const float* __restrict__ dtb, const float* __restrict__ xc,
                const float* __restrict__ dbl, const float* __restrict__ Alog,
                float* __restrict__ aPbuf, float* __restrict__ bAbuf)
{
    int tid  = threadIdx.x;
    int half = tid & 1;              // states half*8 .. half*8+7
    int blk  = blockIdx.x;           // grid = NB * NCHUNK * 16 = 1024
    int dg   = blk & 15;
    int c    = (blk >> 4) & (NCHUNK - 1);
    int bb   = blk >> 9;
    int d    = dg * 128 + (tid >> 1);

    float A[8];
    {
        const float* pA = Alog + (size_t)d * D_STATE + half * 8;
        float4 v0 = *(const float4*)pA;
        float4 v1 = *(const float4*)(pA + 4);
        A[0] = -__expf(v0.x); A[1] = -__expf(v0.y);
        A[2] = -__expf(v0.z); A[3] = -__expf(v0.w);
        A[4] = -__expf(v1.x); A[5] = -__expf(v1.y);
        A[6] = -__expf(v1.z); A[7] = -__expf(v1.w);
    }

    size_t rowbase = (size_t)bb * LSEQ + (size_t)c * TCH;
    const float* pdt = dtb + rowbase * D_INNER + d;
    const float* pxc = xc  + rowbase * D_INNER + d;
    const float* pbc = dbl + rowbase * 96 + DT_RANK + half * 8;

    float aP[8] = {1.f,1.f,1.f,1.f,1.f,1.f,1.f,1.f};
    float bA[8] = {0.f,0.f,0.f,0.f,0.f,0.f,0.f,0.f};

    // current sets: steps 0 (E), 1 (O)
    float  dtE = pdt[0], xvE = pxc[0];
    float4 BE0 = *(const float4*)pbc;
    float4 BE1 = *(const float4*)(pbc + 4);
    float  dtO = pdt[D_INNER], xvO = pxc[D_INNER];
    float4 BO0 = *(const float4*)(pbc + 96);
    float4 BO1 = *(const float4*)(pbc + 96 + 4);

    // stepped prefetch pointers (point at t+2 / t+3)
    const float* qdtE = pdt + 2 * D_INNER;
    const float* qdtO = pdt + 3 * D_INNER;
    const float* qxcE = pxc + 2 * D_INNER;
    const float* qxcO = pxc + 3 * D_INNER;
    const float* qbcE = pbc + 2 * 96;
    const float* qbcO = pbc + 3 * 96;

#define P1_STEP(DT, XV, B0, B1) { \
        float B[8]; UNPK4(B, 0, B0) UNPK4(B, 4, B1) \
        float dtx = (DT) * (XV); \
        _Pragma("unroll") \
        for (int s = 0; s < 8; ++s) { \
            float a = __expf((DT) * A[s]); \
            aP[s] *= a; \
            bA[s] = bA[s] * a + dtx * B[s]; \
        } }

    for (int t = 0; t < TCH - 4; t += 2) {
        float  dtEn = qdtE[0], xvEn = qxcE[0];
        float4 BE0n = *(const float4*)qbcE;
        float4 BE1n = *(const float4*)(qbcE + 4);
        float  dtOn = qdtO[0], xvOn = qxcO[0];
        float4 BO0n = *(const float4*)qbcO;
        float4 BO1n = *(const float4*)(qbcO + 4);
        qdtE += 2 * D_INNER; qdtO += 2 * D_INNER;
        qxcE += 2 * D_INNER; qxcO += 2 * D_INNER;
        qbcE += 192; qbcO += 192;

        P1_STEP(dtE, xvE, BE0, BE1)
        P1_STEP(dtO, xvO, BO0, BO1)

        dtE = dtEn; xvE = xvEn; BE0 = BE0n; BE1 = BE1n;
        dtO = dtOn; xvO = xvOn; BO0 = BO0n; BO1 = BO1n;
    }
    {   // tail iter A: prefetch last two steps, process TCH-4, TCH-3
        float  dtEn = qdtE[0], xvEn = qxcE[0];
        float4 BE0n = *(const float4*)qbcE;
        float4 BE1n = *(const float4*)(qbcE + 4);
        float  dtOn = qdtO[0], xvOn = qxcO[0];
        float4 BO0n = *(const float4*)qbcO;
        float4 BO1n = *(const float4*)(qbcO + 4);

        P1_STEP(dtE, xvE, BE0, BE1)
        P1_STEP(dtO, xvO, BO0, BO1)

        dtE = dtEn; xvE = xvEn; BE0 = BE0n; BE1 = BE1n;
        dtO = dtOn; xvO = xvOn; BO0 = BO0n; BO1 = BO1n;
    }
    {   // tail iter B: process TCH-2, TCH-1
        P1_STEP(dtE, xvE, BE0, BE1)
        P1_STEP(dtO, xvO, BO0, BO1)
    }
#undef P1_STEP

    float* pa = aPbuf + ((size_t)(bb * NCHUNK + c) * D_INNER + d) * D_STATE + half * 8;
    float* pb = bAbuf + ((size_t)(bb * NCHUNK + c) * D_INNER + d) * D_STATE + half * 8;
    *(float4*)(pa + 0) = make_float4(aP[0], aP[1], aP[2], aP[3]);
    *(float4*)(pa + 4) = make_float4(aP[4], aP[5], aP[6], aP[7]);
    *(float4*)(pb + 0) = make_float4(bA[0], bA[1], bA[2], bA[3]);
    *(float4*)(pb + 4) = make_float4(bA[4], bA[5], bA[6], bA[7]);
}

// Exclusive prefix over chunks, in-place: bAbuf[c] <- h0 entering chunk c.
__global__ __launch_bounds__(256)
void scan_prefix(const float* __restrict__ aPbuf, float* __restrict__ bAbuf)
{
    int idx = blockIdx.x * 256 + threadIdx.x;
    int sp = idx & 7;
    int d  = (idx >> 3) & (D_INNER - 1);
    int bb = idx >> 14;

    size_t o = ((size_t)(bb * NCHUNK) * D_INNER + d) * D_STATE + sp * 2;
    const size_t stride = (size_t)D_INNER * D_STATE;
    float h0 = 0.f, h1 = 0.f;
    #pragma unroll 4
    for (int c = 0; c < NCHUNK; ++c) {
        float2 a2 = *(const float2*)(aPbuf + o);
        float2 b2 = *(const float2*)(bAbuf + o);
        *(float2*)(bAbuf + o) = make_float2(h0, h1);
        h0 = h0 * a2.x + b2.x;
        h1 = h1 * a2.y + b2.y;
        o += stride;
    }
}

__global__ __launch_bounds__(256)
void scan_pass2(const float* __restrict__ dtb, const float* __restrict__ xc,
                const float* __restrict__ dbl, const float* __restrict__ xz,
                const float* __restrict__ Alog, const float* __restrict__ Dp,
                const float* __restrict__ bAbuf,
                unsigned short* __restrict__ y)
{
    int tid  = threadIdx.x;
    int half = tid & 1;
    int blk  = blockIdx.x;
    int dg   = blk & 15;
    int c    = (blk >> 4) & (NCHUNK - 1);
    int bb   = blk >> 9;
    int d    = dg * 128 + (tid >> 1);

    float A[8];
    {
        const float* pA = Alog + (size_t)d * D_STATE + half * 8;
        float4 v0 = *(const float4*)pA;
        float4 v1 = *(const float4*)(pA + 4);
        A[0] = -__expf(v0.x); A[1] = -__expf(v0.y);
        A[2] = -__expf(v0.z); A[3] = -__expf(v0.w);
        A[4] = -__expf(v1.x); A[5] = -__expf(v1.y);
        A[6] = -__expf(v1.z); A[7] = -__expf(v1.w);
    }
    float Dd = Dp[d];

    // initial state: exclusive-prefix h0 for this chunk (from scan_prefix)
    float h[8];
    {
        const float* ph = bAbuf + ((size_t)(bb * NCHUNK + c) * D_INNER + d) * D_STATE + half * 8;
        float4 h0v = *(const float4*)(ph + 0);
        float4 h1v = *(const float4*)(ph + 4);
        UNPK4(h, 0, h0v) UNPK4(h, 4, h1v)
    }

    size_t rowbase = (size_t)bb * LSEQ + (size_t)c * TCH;
    const float* pdt = dtb + rowbase * D_INNER + d;
    const float* pxc = xc  + rowbase * D_INNER + d;
    const float* pz  = xz  + rowbase * 2 * D_INNER + D_INNER + d;
    const float* pbc = dbl + rowbase * 96 + DT_RANK + half * 8;
    unsigned short* qyE = y + rowbase * D_INNER + d;
    unsigned short* qyO = qyE + D_INNER;

    // current sets: steps 0 (E), 1 (O)
    float  dtE = pdt[0], xvE = pxc[0], zvE = pz[0];
    float4 BE0 = *(const float4*)pbc;
    float4 BE1 = *(const float4*)(pbc + 4);
    float4 CE0 = *(const float4*)(pbc + 16);
    float4 CE1 = *(const float4*)(pbc + 20);
    float  dtO = pdt[D_INNER], xvO = pxc[D_INNER], zvO = pz[2 * D_INNER];
    float4 BO0 = *(const float4*)(pbc + 96);
    float4 BO1 = *(const float4*)(pbc + 96 + 4);
    float4 CO0 = *(const float4*)(pbc + 96 + 16);
    float4 CO1 = *(const float4*)(pbc + 96 + 20);

    // stepped prefetch pointers (point at t+2 / t+3)
    const float* qdtE = pdt + 2 * D_INNER;
    const float* qdtO = pdt + 3 * D_INNER;
    const float* qxcE = pxc + 2 * D_INNER;
    const float* qxcO = pxc + 3 * D_INNER;
    const float* qzE  = pz  + 4 * D_INNER;          // step stride 2*D_INNER
    const float* qzO  = pz  + 6 * D_INNER;
    const float* qbcE = pbc + 2 * 96;
    const float* qbcO = pbc + 3 * 96;

#define P2_STEP(DT, XV, ZV, B0, B1, C0, C1, PY) { \
        float B[8], C[8]; \
        UNPK4(B, 0, B0) UNPK4(B, 4, B1) \
        UNPK4(C, 0, C0) UNPK4(C, 4, C1) \
        float dtx = (DT) * (XV); \
        float p = 0.f; \
        _Pragma("unroll") \
        for (int s = 0; s < 8; ++s) { \
            float a = __expf((DT) * A[s]); \
            h[s] = h[s] * a + dtx * B[s]; \
            p += h[s] * C[s]; \
        } \
        p += __shfl_xor(p, 1, 2); \
        if (half == 0) { \
            float sz = (ZV) / (1.f + __expf(-(ZV))); \
            *(PY) = (unsigned short)bfbits((p + (XV) * Dd) * sz); \
        } }

    for (int t = 0; t < TCH - 4; t += 2) {
        float  dtEn = qdtE[0], xvEn = qxcE[0], zvEn = qzE[0];
        float4 BE0n = *(const float4*)qbcE;
        float4 BE1n = *(const float4*)(qbcE + 4);
        float4 CE0n = *(const float4*)(qbcE + 16);
        float4 CE1n = *(const float4*)(qbcE + 20);
        float  dtOn = qdtO[0], xvOn = qxcO[0], zvOn = qzO[0];
        float4 BO0n = *(const float4*)qbcO;
        float4 BO1n = *(const float4*)(qbcO + 4);
        float4 CO0n = *(const float4*)(qbcO + 16);
        float4 CO1n = *(const float4*)(qbcO + 20);
        qdtE += 2 * D_INNER; qdtO += 2 * D_INNER;
        qxcE += 2 * D_INNER; qxcO += 2 * D_INNER;
        qzE  += 4 * D_INNER; qzO  += 4 * D_INNER;
        qbcE += 192; qbcO += 192;

        P2_STEP(dtE, xvE, zvE, BE0, BE1, CE0, CE1, qyE)
        qyE += 2 * D_INNER;
        P2_STEP(dtO, xvO, zvO, BO0, BO1, CO0, CO1, qyO)
        qyO += 2 * D_INNER;

        dtE = dtEn; xvE = xvEn; zvE = zvEn;
        BE0 = BE0n; BE1 = BE1n; CE0 = CE0n; CE1 = CE1n;
        dtO = dtOn; xvO = xvOn; zvO = zvOn;
        BO0 = BO0n; BO1 = BO1n; CO0 = CO0n; CO1 = CO1n;
    }
    {   // tail iter A: prefetch last two steps, process TCH-4, TCH-3
        float  dtEn = qdtE[0], xvEn = qxcE[0], zvEn = qzE[0];
        float4 BE0n = *(const float4*)qbcE;
        float4 BE1n = *(const float4*)(qbcE + 4);
        float4 CE0n = *(const float4*)(qbcE + 16);
        float4 CE1n = *(const float4*)(qbcE + 20);
        float  dtOn = qdtO[0], xvOn = qxcO[0], zvOn = qzO[0];
        float4 BO0n = *(const float4*)qbcO;
        float4 BO1n = *(const float4*)(qbcO + 4);
        float4 CO0n = *(const float4*)(qbcO + 16);
        float4 CO1n = *(const float4*)(qbcO + 20);

        P2_STEP(dtE, xvE, zvE, BE0, BE1, CE0, CE1, qyE)
        qyE += 2 * D_INNER;
        P2_STEP(dtO, xvO, zvO, BO0, BO1, CO0, CO1, qyO)
        qyO += 2 * D_INNER;

        dtE = dtEn; xvE = xvEn; zvE = zvEn;
        BE0 = BE0n; BE1 = BE1n; CE0 = CE0n; CE1 = CE1n;
        dtO = dtOn; xvO = xvOn; zvO = zvOn;
        BO0 = BO0n; BO1 = BO1n; CO0 = CO0n; CO1 = CO1n;
    }
    {   // tail iter B: process TCH-2, TCH-1
        P2_STEP(dtE, xvE, zvE, BE0, BE1, CE0, CE1, qyE)
        P2_STEP(dtO, xvO, zvO, BO0, BO1, CO0, CO1, qyO)
    }
#undef P2_STEP
}

// ---------------------------------------------------------------------------
extern "C" void kernel_launch(void* const* d_in, const int* in_sizes, int n_in,
                              void* d_out, int out_size, void* d_ws, size_t ws_size,
                              hipStream_t stream)
{
    const float* h_in  = (const float*)d_in[0];
    const float* iw    = (const float*)d_in[1];   // (4, 4096, 1024)
    const float* cw    = (const float*)d_in[2];   // (4, 2048, 4)
    const float* cb    = (const float*)d_in[3];   // (4, 2048)
    const float* xw    = (const float*)d_in[4];   // (4, 96, 2048)
    const float* dw    = (const float*)d_in[5];   // (4, 2048, 64)
    const float* db    = (const float*)d_in[6];   // (4, 2048)
    const float* Alog  = (const float*)d_in[7];   // (4, 2048, 16)
    const float* Dp    = (const float*)d_in[8];   // (4, 2048)
    const float* ow    = (const float*)d_in[9];   // (4, 1024, 2048)
    const float* nw    = (const float*)d_in[10];  // (4, 1024)
    const float* nb    = (const float*)d_in[11];  // (4, 1024)
    const float* nfw   = (const float*)d_in[12];  // (1024,)
    const float* nfb   = (const float*)d_in[13];  // (1024,)

    // workspace layout — identical total (25,362,432 floats)
    float* ws = (float*)d_ws;
    float* residual = ws;                       // 2,097,152
    float* hs       = residual + 2097152;       // 2,097,152
    float* xz       = hs + 2097152;             // 8,388,608  [r][4096]
    float* xc       = xz + 8388608;             // 4,194,304  [r][2048]
    float* dtb      = xc + 4194304;             // 4,194,304  [r][2048]
    float* dbl      = dtb + 4194304;            // 196,608    [r][96]
    float* y        = dbl + 196608;             // 4,194,304

    // aPbuf aliases hs (dead add_ln-consume .. scan); bAbuf = y[2M..4M).
    float* aPbuf = hs;
    float* bAbuf = y + 2097152;

    // bf16 / hi-lo staging, all in dead regions (timeline-disjoint):
    unsigned short* wbuf_in  = (unsigned short*)y;
    unsigned short* hs_bf16  = (unsigned short*)(y + 2097152);
    unsigned short* y_bf16   = (unsigned short*)y;
    unsigned short* xc_hi    = (unsigned short*)y;
    unsigned short* xc_lo    = (unsigned short*)(y + 2097152);
    unsigned short* xwp_hi   = (unsigned short*)hs;
    unsigned short* xwp_lo   = (unsigned short*)(hs + 98304);
    unsigned short* dwp_hi   = (unsigned short*)(hs + 196608);
    unsigned short* dwp_lo   = (unsigned short*)(hs + 262144);
    unsigned short* wbuf_out = (unsigned short*)dtb;

    const float* cur_add = h_in;
    for (int i = 0; i < N_LAYER; ++i) {
        // fused: residual add + LN (bf16) | in_proj w->bf16 | xw/dw hi-lo | zero dbl
        lnprep_kernel<<<6656, 256, 0, stream>>>(
            cur_add, residual, nw + i * D_MODEL, nb + i * D_MODEL, hs_bf16, i == 0,
            iw + (size_t)i * 2 * D_INNER * D_MODEL, wbuf_in,
            xw + (size_t)i * 96 * D_INNER, xwp_hi, xwp_lo,
            dw + (size_t)i * D_INNER * DT_RANK, dwp_hi, dwp_lo,
            dbl);
        // in_proj (bf16 MFMA, dbuf pipeline, 128x64 tiles -> 1024 blocks)
        gemm_bf16_dbuf<128, 64><<<dim3(2 * D_INNER / 64, NROWS / 128), 256, 0, stream>>>(
            hs_bf16, wbuf_in, xz, NROWS, 2 * D_INNER, D_MODEL);
        // conv + silu -> xc fp32 + hi/lo bf16 split (for MFMA x_proj)
        conv_silu_kernel<<<NB * LSEQ * D_INNER / 256, 256, 0, stream>>>(
            xz, cw + (size_t)i * D_INNER * D_CONV, cb + i * D_INNER, xc, xc_hi, xc_lo);
        // x_proj (hi/lo split-bf16 MFMA, split-K z=8): -> dbl [r][96]
        xproj_hl<<<dim3(NROWS / 32, 8), 256, 0, stream>>>(
            xc_hi, xc_lo, xwp_hi, xwp_lo, dbl);
        // dt_proj (reads dbl directly, in-reg hi/lo split + bias + softplus)
        dtproj_hl<<<dim3(D_INNER / 128, NROWS / 64), 256, 0, stream>>>(
            dbl, dwp_hi, dwp_lo, db + i * D_INNER, dtb);
        // chunked selective scan — 3-phase Blelloch
        scan_pass1<<<NB * NCHUNK * (D_INNER / 128), 256, 0, stream>>>(
            dtb, xc, dbl, Alog + (size_t)i * D_INNER * D_STATE, aPbuf, bAbuf);
        scan_prefix<<<(NB * D_INNER * 8) / 256, 256, 0, stream>>>(aPbuf, bAbuf);
        scan_pass2<<<NB * NCHUNK * (D_INNER / 128), 256, 0, stream>>>(
            dtb, xc, dbl, xz, Alog + (size_t)i * D_INNER * D_STATE, Dp + i * D_INNER,
            bAbuf, y_bf16);
        // convert out_proj weights -> bf16 (dead dtb space; must follow scan)
        f32_to_bf16_kernel<<<(D_MODEL * D_INNER) / 1024, 256, 0, stream>>>(
            ow + (size_t)i * D_MODEL * D_INNER, wbuf_out);
        // out_proj (bf16 MFMA, dbuf pipeline, 64x64 tiles -> 512 blocks)
        gemm_bf16_dbuf<64, 64><<<dim3(D_MODEL / 64, NROWS / 64), 256, 0, stream>>>(
            y_bf16, wbuf_out, hs, NROWS, D_MODEL, D_INNER);
        cur_add = hs;
    }
    add_ln_kernel<<<NROWS, 256, 0, stream>>>(hs, residual, nfw, nfb, d_out, 0, 0);
}